// Round 8
// baseline (964.815 us; speedup 1.0000x reference)
//
#include <hip/hip_runtime.h>
#include <math.h>

typedef __attribute__((ext_vector_type(8))) short short8;
typedef __attribute__((ext_vector_type(4))) float f32x4;

// ---------------- bf16 helpers ----------------

__device__ __forceinline__ float bf2f(unsigned short u) {
  union { unsigned int i; float f; } v;
  v.i = ((unsigned int)u) << 16;
  return v.f;
}
__device__ __forceinline__ unsigned short f2bf(float f) {
  union { float f; unsigned int i; } v;
  v.f = f;
  unsigned int x = v.i;
  unsigned int r = x + 0x7fffu + ((x >> 16) & 1u);  // RNE
  return (unsigned short)(r >> 16);
}
__device__ __forceinline__ float lo16f(unsigned int u) {
  union { unsigned int i; float f; } v;
  v.i = u << 16;
  return v.f;
}
__device__ __forceinline__ float hi16f(unsigned int u) {
  union { unsigned int i; float f; } v;
  v.i = u & 0xffff0000u;
  return v.f;
}

// ---------------- CSR build ----------------

__global__ __launch_bounds__(256) void count_deg(const int* __restrict__ dstA,
                                                 int Ee, int Nn,
                                                 int* __restrict__ deg) {
  int e = blockIdx.x * 256 + threadIdx.x;
  if (e >= Ee + Nn) return;
  int d = (e < Ee) ? dstA[e] : (e - Ee);
  atomicAdd(&deg[d], 1);
}

__global__ __launch_bounds__(256) void scan_blk(const int* __restrict__ deg,
                                                int* __restrict__ exc,
                                                int* __restrict__ bsum, int Nn) {
  __shared__ int sd[256];
  int t = threadIdx.x;
  int i = blockIdx.x * 256 + t;
  int v = (i < Nn) ? deg[i] : 0;
  sd[t] = v;
  __syncthreads();
  #pragma unroll
  for (int s = 1; s < 256; s <<= 1) {
    int u = (t >= s) ? sd[t - s] : 0;
    __syncthreads();
    sd[t] += u;
    __syncthreads();
  }
  if (i < Nn) exc[i] = sd[t] - v;
  if (t == 255) bsum[blockIdx.x] = sd[255];
}

__global__ void scan_top(const int* __restrict__ bsum, int* __restrict__ boff,
                         int NB, int* __restrict__ off, int Nn) {
  __shared__ int sd[256];
  int t = threadIdx.x;
  int v = (t < NB) ? bsum[t] : 0;
  sd[t] = v;
  __syncthreads();
  #pragma unroll
  for (int s = 1; s < 256; s <<= 1) {
    int u = (t >= s) ? sd[t - s] : 0;
    __syncthreads();
    sd[t] += u;
    __syncthreads();
  }
  if (t < NB) boff[t] = sd[t] - v;
  if (t == 255) off[Nn] = sd[255];
}

__global__ __launch_bounds__(256) void scan_add(const int* __restrict__ exc,
                                                const int* __restrict__ boff,
                                                int* __restrict__ off,
                                                int* __restrict__ cursor, int Nn) {
  int i = blockIdx.x * 256 + threadIdx.x;
  if (i >= Nn) return;
  int o = exc[i] + boff[blockIdx.x];
  off[i] = o;
  cursor[i] = o;
}

__global__ __launch_bounds__(256) void fill_csr(const int* __restrict__ srcA,
                                                const int* __restrict__ dstA,
                                                int Ee, int Nn,
                                                int* __restrict__ cursor,
                                                int* __restrict__ col) {
  int e = blockIdx.x * 256 + threadIdx.x;
  if (e >= Ee + Nn) return;
  int s, d;
  if (e < Ee) { s = srcA[e]; d = dstA[e]; }
  else        { s = e - Ee;  d = s; }
  int slot = atomicAdd(&cursor[d], 1);
  col[slot] = s;
}

// ---------------- operand prep ----------------

__global__ __launch_bounds__(256) void cast_f32_bf16(const float* __restrict__ in,
                                                     unsigned short* __restrict__ out,
                                                     size_t n4) {
  for (size_t i = blockIdx.x * (size_t)256 + threadIdx.x; i < n4;
       i += (size_t)gridDim.x * 256) {
    float4 v = *(const float4*)&in[i * 4];
    ushort4 o;
    o.x = f2bf(v.x); o.y = f2bf(v.y); o.z = f2bf(v.z); o.w = f2bf(v.w);
    *(ushort4*)&out[i * 4] = o;
  }
}

// Wt[n][k] = bf16(W[k][n])
__global__ __launch_bounds__(256) void transpose_cast(const float* __restrict__ W,
                                                      unsigned short* __restrict__ Wt,
                                                      int K, int N) {
  int t = blockIdx.x * 256 + threadIdx.x;
  if (t >= K * N) return;
  int n = t / K, k = t % K;
  Wt[t] = f2bf(W[(size_t)k * N + n]);
}

// ---------------- bf16 MFMA GEMM: C[M,N] = A[M,K] @ Bt[N,K]^T ----------------

template <int BM, int BN, int WM, int WN>
__global__ __launch_bounds__(256) void gemm_mfma_bf16(
    const unsigned short* __restrict__ A,
    const unsigned short* __restrict__ Bt,
    unsigned short* __restrict__ C,
    int M, int N, int K) {
  constexpr int BK = 32;
  constexpr int LDA = BK + 8;
  constexpr int MF = WM / 16, NF = WN / 16;
  constexpr int NWN = BN / WN;
  constexpr int ACH = BM * BK / 8;
  constexpr int BCH = BN * BK / 8;
  constexpr int ACHT = (ACH + 255) / 256;
  constexpr int BCHT = (BCH + 255) / 256;

  __shared__ unsigned short Al[2][BM * LDA];
  __shared__ unsigned short Bl[2][BN * LDA];

  const int tid = threadIdx.x;
  const int wid = tid >> 6, lane = tid & 63;
  const int wr = wid / NWN, wc = wid % NWN;
  const int brow = blockIdx.y * BM;
  const int bcol = blockIdx.x * BN;

  f32x4 acc[MF][NF] = {};
  uint4 ra[ACHT], rb[BCHT];

  auto loadG = [&](int k0) {
    #pragma unroll
    for (int c = 0; c < ACHT; ++c) {
      int i = c * 256 + tid;
      if (ACH % 256 == 0 || i < ACH) {
        int row = i >> 2, blk = i & 3;
        int rg = brow + row;
        rg = rg < M ? rg : M - 1;
        ra[c] = *(const uint4*)&A[(size_t)rg * K + k0 + blk * 8];
      }
    }
    #pragma unroll
    for (int c = 0; c < BCHT; ++c) {
      int i = c * 256 + tid;
      if (BCH % 256 == 0 || i < BCH) {
        int row = i >> 2, blk = i & 3;
        rb[c] = *(const uint4*)&Bt[(size_t)(bcol + row) * K + k0 + blk * 8];
      }
    }
  };
  auto storeL = [&](int buf) {
    #pragma unroll
    for (int c = 0; c < ACHT; ++c) {
      int i = c * 256 + tid;
      if (ACH % 256 == 0 || i < ACH) {
        int row = i >> 2, blk = i & 3;
        *(uint4*)&Al[buf][row * LDA + blk * 8] = ra[c];
      }
    }
    #pragma unroll
    for (int c = 0; c < BCHT; ++c) {
      int i = c * 256 + tid;
      if (BCH % 256 == 0 || i < BCH) {
        int row = i >> 2, blk = i & 3;
        *(uint4*)&Bl[buf][row * LDA + blk * 8] = rb[c];
      }
    }
  };

  const int nt = K / BK;
  loadG(0);
  storeL(0);
  __syncthreads();
  int cur = 0;
  const int arow = wr * WM + (lane & 15);
  const int bro = wc * WN + (lane & 15);
  const int kb = (lane >> 4) * 8;
  for (int t = 0; t < nt; ++t) {
    if (t + 1 < nt) loadG((t + 1) * BK);
    short8 af[MF], bfr[NF];
    #pragma unroll
    for (int m = 0; m < MF; ++m)
      af[m] = *(const short8*)&Al[cur][(arow + m * 16) * LDA + kb];
    #pragma unroll
    for (int n = 0; n < NF; ++n)
      bfr[n] = *(const short8*)&Bl[cur][(bro + n * 16) * LDA + kb];
    #pragma unroll
    for (int m = 0; m < MF; ++m)
      #pragma unroll
      for (int n = 0; n < NF; ++n)
        acc[m][n] = __builtin_amdgcn_mfma_f32_16x16x32_bf16(af[m], bfr[n], acc[m][n], 0, 0, 0);
    if (t + 1 < nt) storeL(cur ^ 1);
    __syncthreads();
    cur ^= 1;
  }

  const int crow0 = brow + wr * WM + (lane >> 4) * 4;
  const int ccol0 = bcol + wc * WN + (lane & 15);
  #pragma unroll
  for (int m = 0; m < MF; ++m) {
    #pragma unroll
    for (int r = 0; r < 4; ++r) {
      int grow = crow0 + m * 16 + r;
      if (grow >= M) continue;
      #pragma unroll
      for (int n = 0; n < NF; ++n)
        C[(size_t)grow * N + ccol0 + n * 16] = f2bf(acc[m][n][r]);
    }
  }
}

// ---------------- per-node attention logits (bf16 h) ----------------

template <int HEADS, int CC>
__global__ __launch_bounds__(256) void attn_logits(const unsigned short* __restrict__ h,
                                                   const float* __restrict__ a_s,
                                                   const float* __restrict__ a_d,
                                                   float* __restrict__ als,
                                                   float* __restrict__ ald,
                                                   int Nn) {
  int wid = (int)((blockIdx.x * (size_t)blockDim.x + threadIdx.x) >> 6);
  int lane = threadIdx.x & 63;
  if (wid >= Nn) return;
  const unsigned short* hn = h + (size_t)wid * HEADS * CC;
  #pragma unroll
  for (int hh = 0; hh < HEADS; ++hh) {
    float vs = 0.f, vd = 0.f;
    if (lane < CC) {
      float v = bf2f(hn[hh * CC + lane]);
      vs = v * a_s[hh * CC + lane];
      vd = v * a_d[hh * CC + lane];
    }
    #pragma unroll
    for (int o = 32; o > 0; o >>= 1) {
      vs += __shfl_xor(vs, o, 64);
      vd += __shfl_xor(vd, o, 64);
    }
    if (lane == 0) {
      als[(size_t)wid * HEADS + hh] = vs;
      ald[(size_t)wid * HEADS + hh] = vd;
    }
  }
}

// ---------------- GAT aggregation ----------------
// One wave per (dst, head): 4x the waves of the old per-dst kernel -> 4x
// outstanding 128B gathers (latency hiding), same total bytes. bf16 out
// (f32 accum) halves the write stream. Max-free softmax as before.

template <int HEADS, int CC>
__global__ __launch_bounds__(256) void gat_aggregate_h(
    const unsigned short* __restrict__ h, const float* __restrict__ als,
    const float* __restrict__ ald, const int* __restrict__ off,
    const int* __restrict__ col, const float* __restrict__ bias,
    unsigned short* __restrict__ out, int Nn) {
  constexpr int HC = HEADS * CC;
  int gw = (int)((blockIdx.x * (size_t)blockDim.x + threadIdx.x) >> 6);
  int lane = threadIdx.x & 63;  // channel within head (CC == 64)
  int node = gw / HEADS;
  int head = gw % HEADS;
  if (node >= Nn) return;
  float my_ald = ald[(size_t)node * HEADS + head];
  int beg = off[node], end = off[node + 1];
  float ssum = 0.f, acc = 0.f;
  const unsigned short* hh = h + head * CC + lane;
  for (int j = beg; j < end; ++j) {
    int s = col[j];
    float l = als[(size_t)s * HEADS + head] + my_ald;
    l = (l > 0.f) ? l : 0.2f * l;  // leaky_relu(0.2)
    float p = __expf(l);
    ssum += p;
    acc += p * bf2f(hh[(size_t)s * HC]);
  }
  out[(size_t)node * HC + head * CC + lane] =
      f2bf(acc / (ssum + 1e-16f) + bias[head * CC + lane]);
}

// HEADS==1, CC==32: two nodes per wave (lo/hi halves, per-lane edge ranges).
template <int CC>
__global__ __launch_bounds__(256) void gat_aggregate_dual(
    const unsigned short* __restrict__ h, const float* __restrict__ als,
    const float* __restrict__ ald, const int* __restrict__ off,
    const int* __restrict__ col, const float* __restrict__ bias,
    unsigned short* __restrict__ out, int Nn) {
  int gw = (int)((blockIdx.x * (size_t)blockDim.x + threadIdx.x) >> 6);
  int lane = threadIdx.x & 63;
  int node = gw * 2 + (lane >> 5);
  if (node >= Nn) return;
  int c = lane & (CC - 1);
  float my_ald = ald[node];
  int beg = off[node], end = off[node + 1];
  float ssum = 0.f, acc = 0.f;
  for (int j = beg; j < end; ++j) {
    int s = col[j];
    float l = als[s] + my_ald;
    l = (l > 0.f) ? l : 0.2f * l;
    float p = __expf(l);
    ssum += p;
    acc += p * bf2f(h[(size_t)s * CC + c]);
  }
  out[(size_t)node * CC + c] = f2bf(acc / (ssum + 1e-16f) + bias[c]);
}

// ---------------- BatchNorm (biased var) — parallel two-stage, bf16 input ----------------

constexpr int BN_NB = 1024;

template <int CH>
__global__ __launch_bounds__(256) void bn_stats_part(const unsigned short* __restrict__ x,
                                                     int Nn, float* __restrict__ pbuf) {
  constexpr int Q8 = CH / 8;  // uint4 (8 bf16) groups per row: 32 or 4; divides 256
  int t = threadIdx.x;
  size_t tot8 = (size_t)Nn * Q8;
  size_t stride = (size_t)gridDim.x * 256;  // multiple of Q8 -> fixed group per thread
  float s[8] = {}, sq[8] = {};
  for (size_t i = blockIdx.x * (size_t)256 + t; i < tot8; i += stride) {
    uint4 u = *(const uint4*)&x[i * 8];
    float v[8] = {lo16f(u.x), hi16f(u.x), lo16f(u.y), hi16f(u.y),
                  lo16f(u.z), hi16f(u.z), lo16f(u.w), hi16f(u.w)};
    #pragma unroll
    for (int k = 0; k < 8; ++k) { s[k] += v[k]; sq[k] += v[k] * v[k]; }
  }
  __shared__ float sS[256][8];
  __shared__ float sQ[256][8];
  #pragma unroll
  for (int k = 0; k < 8; ++k) { sS[t][k] = s[k]; sQ[t][k] = sq[k]; }
  __syncthreads();
  for (int half = 128; half >= Q8; half >>= 1) {  // half % Q8 == 0 -> same group
    if (t < half) {
      #pragma unroll
      for (int k = 0; k < 8; ++k) {
        sS[t][k] += sS[t + half][k];
        sQ[t][k] += sQ[t + half][k];
      }
    }
    __syncthreads();
  }
  if (t < Q8) {
    #pragma unroll
    for (int k = 0; k < 8; ++k) {
      pbuf[(size_t)blockIdx.x * 2 * CH + t * 8 + k] = sS[t][k];
      pbuf[(size_t)blockIdx.x * 2 * CH + CH + t * 8 + k] = sQ[t][k];
    }
  }
}

template <int CH>
__global__ __launch_bounds__(256) void bn_reduce_finalize(const float* __restrict__ pbuf,
                                                          const float* __restrict__ g,
                                                          const float* __restrict__ be,
                                                          float invN,
                                                          float* __restrict__ ss) {
  int c = blockIdx.x;  // one block per channel
  int t = threadIdx.x;
  float s = 0.f, q = 0.f;
  for (int b = t; b < BN_NB; b += 256) {
    s += pbuf[(size_t)b * 2 * CH + c];
    q += pbuf[(size_t)b * 2 * CH + CH + c];
  }
  #pragma unroll
  for (int o = 32; o > 0; o >>= 1) {
    s += __shfl_xor(s, o, 64);
    q += __shfl_xor(q, o, 64);
  }
  __shared__ float rs[4], rq[4];
  int wv = t >> 6, lane = t & 63;
  if (lane == 0) { rs[wv] = s; rq[wv] = q; }
  __syncthreads();
  if (t == 0) {
    float S = rs[0] + rs[1] + rs[2] + rs[3];
    float Qs = rq[0] + rq[1] + rq[2] + rq[3];
    float mu = S * invN;
    float var = Qs * invN - mu * mu;
    float sc = g[c] * rsqrtf(var + 1e-5f);
    ss[c] = sc;
    ss[CH + c] = be[c] - mu * sc;
  }
}

// BN-apply + ELU, bf16 in -> bf16 out (usable in-place when out == x).
template <int CH>
__global__ __launch_bounds__(256) void bn_apply_elu_b2b(const unsigned short* __restrict__ x,
                                                        const float* __restrict__ ss,
                                                        unsigned short* __restrict__ out,
                                                        int Nn) {
  size_t tot8 = (size_t)Nn * (CH / 8);
  for (size_t i = blockIdx.x * (size_t)256 + threadIdx.x; i < tot8;
       i += (size_t)gridDim.x * 256) {
    uint4 u = *(const uint4*)&x[i * 8];
    int c0 = (int)((i % (CH / 8)) * 8);
    float v[8] = {lo16f(u.x), hi16f(u.x), lo16f(u.y), hi16f(u.y),
                  lo16f(u.z), hi16f(u.z), lo16f(u.w), hi16f(u.w)};
    unsigned int o[4];
    #pragma unroll
    for (int k = 0; k < 4; ++k) {
      float y0 = v[2 * k] * ss[c0 + 2 * k] + ss[CH + c0 + 2 * k];
      float y1 = v[2 * k + 1] * ss[c0 + 2 * k + 1] + ss[CH + c0 + 2 * k + 1];
      y0 = (y0 > 0.f) ? y0 : expm1f(y0);
      y1 = (y1 > 0.f) ? y1 : expm1f(y1);
      o[k] = (unsigned int)f2bf(y0) | ((unsigned int)f2bf(y1) << 16);
    }
    *(uint4*)&out[i * 8] = make_uint4(o[0], o[1], o[2], o[3]);
  }
}

// ---------------- classifier: relu(x@Wc1+bc1)@Wc2+bc2 (bf16 x) ----------------

__global__ __launch_bounds__(256) void classifier_k(const unsigned short* __restrict__ x,
                                                    const float* __restrict__ Wc1,
                                                    const float* __restrict__ bc1,
                                                    const float* __restrict__ Wc2,
                                                    const float* __restrict__ bc2,
                                                    float* __restrict__ outp, int Nn) {
  __shared__ unsigned short sx[256][33];
  __shared__ float sw[32 * 32];
  __shared__ float sb1[32];
  __shared__ float sw2[32];
  int t = threadIdx.x;
  int base = blockIdx.x * 256;
  for (int i = t; i < 1024; i += 256) sw[i] = Wc1[i];
  if (t < 32) { sb1[t] = bc1[t]; sw2[t] = Wc2[t]; }
  int cnt = min(256, Nn - base);
  for (int i = t; i < cnt * 32; i += 256) sx[i / 32][i % 32] = x[(size_t)base * 32 + i];
  __syncthreads();
  if (t < cnt) {
    float xa[32];
    #pragma unroll
    for (int c = 0; c < 32; ++c) xa[c] = bf2f(sx[t][c]);
    float o = bc2[0];
    #pragma unroll
    for (int j = 0; j < 32; ++j) {
      float v = sb1[j];
      #pragma unroll
      for (int c = 0; c < 32; ++c) v += xa[c] * sw[c * 32 + j];
      v = fmaxf(v, 0.f);
      o += v * sw2[j];
    }
    outp[base + t] = o;
  }
}

// ---------------- host orchestration ----------------

extern "C" void kernel_launch(void* const* d_in, const int* in_sizes, int n_in,
                              void* d_out, int out_size, void* d_ws, size_t ws_size,
                              hipStream_t stream) {
  const float* x   = (const float*)d_in[0];
  const int*   ei  = (const int*)d_in[1];
  const float* W1  = (const float*)d_in[2];
  const float* as1 = (const float*)d_in[3];
  const float* ad1 = (const float*)d_in[4];
  const float* b1  = (const float*)d_in[5];
  const float* g1  = (const float*)d_in[6];
  const float* be1 = (const float*)d_in[7];
  const float* W2  = (const float*)d_in[8];
  const float* as2 = (const float*)d_in[9];
  const float* ad2 = (const float*)d_in[10];
  const float* b2  = (const float*)d_in[11];
  const float* g2  = (const float*)d_in[12];
  const float* be2 = (const float*)d_in[13];
  const float* W3  = (const float*)d_in[14];
  const float* as3 = (const float*)d_in[15];
  const float* ad3 = (const float*)d_in[16];
  const float* b3  = (const float*)d_in[17];
  const float* g3  = (const float*)d_in[18];
  const float* be3 = (const float*)d_in[19];
  const float* Wc1 = (const float*)d_in[20];
  const float* bc1 = (const float*)d_in[21];
  const float* Wc2 = (const float*)d_in[22];
  const float* bc2 = (const float*)d_in[23];
  float* outp = (float*)d_out;

  const int Nn = in_sizes[0] / 128;
  const int Ee = in_sizes[1] / 2;
  const int TotE = Ee + Nn;
  const int* esrc = ei;
  const int* edst = ei + Ee;

  char* w = (char*)d_ws;
  auto carve = [&](size_t bytes) {
    char* p = w;
    w += (bytes + 255) & ~(size_t)255;
    return p;
  };
  unsigned short* hb  = (unsigned short*)carve((size_t)Nn * 256 * 2);  // GEMM out (bf16)
  unsigned short* xb  = (unsigned short*)carve((size_t)Nn * 256 * 2);  // GEMM A operand (bf16)
  unsigned short* agg = (unsigned short*)carve((size_t)Nn * 256 * 2);  // aggregate out (bf16)
  float* als   = (float*)carve((size_t)Nn * 4 * 4);
  float* ald   = (float*)carve((size_t)Nn * 4 * 4);
  float* pbuf  = (float*)carve((size_t)BN_NB * 512 * 4);
  float* ss    = (float*)carve(512 * 4);
  unsigned short* Wt1 = (unsigned short*)carve(256 * 128 * 2);
  unsigned short* Wt2 = (unsigned short*)carve(256 * 256 * 2);
  unsigned short* Wt3 = (unsigned short*)carve(32 * 256 * 2);
  int* deg     = (int*)carve((size_t)Nn * 4);
  int* off     = (int*)carve((size_t)(Nn + 1) * 4);
  int* cursor  = (int*)carve((size_t)Nn * 4);
  int* col     = (int*)carve((size_t)TotE * 4);
  int* exc     = (int*)carve((size_t)Nn * 4);
  int* bsum    = (int*)carve(256 * 4);
  int* boff    = (int*)carve(256 * 4);

  // --- operand prep ---
  cast_f32_bf16<<<2048, 256, 0, stream>>>(x, xb, (size_t)Nn * 128 / 4);
  transpose_cast<<<(128 * 256 + 255) / 256, 256, 0, stream>>>(W1, Wt1, 128, 256);
  transpose_cast<<<(256 * 256 + 255) / 256, 256, 0, stream>>>(W2, Wt2, 256, 256);
  transpose_cast<<<(256 * 32 + 255) / 256, 256, 0, stream>>>(W3, Wt3, 256, 32);

  // --- CSR build (shared by all 3 layers); hierarchical scan ---
  const int NB = (Nn + 255) / 256;
  hipMemsetAsync(deg, 0, (size_t)Nn * 4, stream);
  count_deg<<<(TotE + 255) / 256, 256, 0, stream>>>(edst, Ee, Nn, deg);
  scan_blk<<<NB, 256, 0, stream>>>(deg, exc, bsum, Nn);
  scan_top<<<1, 256, 0, stream>>>(bsum, boff, NB, off, Nn);
  scan_add<<<NB, 256, 0, stream>>>(exc, boff, off, cursor, Nn);
  fill_csr<<<(TotE + 255) / 256, 256, 0, stream>>>(esrc, edst, Ee, Nn, cursor, col);

  int waveBlocks = (Nn + 3) / 4;
  int aggBlocksH = (Nn * 4 + 3) / 4;          // one wave per (node, head)
  int aggBlocksD = ((Nn + 1) / 2 + 3) / 4;    // two nodes per wave
  int gy = (Nn + 127) / 128;
  float invN = 1.0f / (float)Nn;

  // --- Layer 1: 128 -> 4x64 concat ---
  gemm_mfma_bf16<128, 128, 64, 64><<<dim3(2, gy), 256, 0, stream>>>(xb, Wt1, hb, Nn, 256, 128);
  attn_logits<4, 64><<<waveBlocks, 256, 0, stream>>>(hb, as1, ad1, als, ald, Nn);
  gat_aggregate_h<4, 64><<<aggBlocksH, 256, 0, stream>>>(hb, als, ald, off, col, b1, agg, Nn);
  bn_stats_part<256><<<BN_NB, 256, 0, stream>>>(agg, Nn, pbuf);
  bn_reduce_finalize<256><<<256, 256, 0, stream>>>(pbuf, g1, be1, invN, ss);
  bn_apply_elu_b2b<256><<<2048, 256, 0, stream>>>(agg, ss, xb, Nn);

  // --- Layer 2: 256 -> 4x64 concat ---
  gemm_mfma_bf16<128, 128, 64, 64><<<dim3(2, gy), 256, 0, stream>>>(xb, Wt2, hb, Nn, 256, 256);
  attn_logits<4, 64><<<waveBlocks, 256, 0, stream>>>(hb, as2, ad2, als, ald, Nn);
  gat_aggregate_h<4, 64><<<aggBlocksH, 256, 0, stream>>>(hb, als, ald, off, col, b2, agg, Nn);
  bn_stats_part<256><<<BN_NB, 256, 0, stream>>>(agg, Nn, pbuf);
  bn_reduce_finalize<256><<<256, 256, 0, stream>>>(pbuf, g2, be2, invN, ss);
  bn_apply_elu_b2b<256><<<2048, 256, 0, stream>>>(agg, ss, xb, Nn);

  // --- Layer 3: 256 -> 1x32, no concat ---
  gemm_mfma_bf16<128, 32, 32, 32><<<dim3(1, gy), 256, 0, stream>>>(xb, Wt3, hb, Nn, 32, 256);
  attn_logits<1, 32><<<waveBlocks, 256, 0, stream>>>(hb, as3, ad3, als, ald, Nn);
  gat_aggregate_dual<32><<<aggBlocksD, 256, 0, stream>>>(hb, als, ald, off, col, b3, agg, Nn);
  bn_stats_part<32><<<BN_NB, 256, 0, stream>>>(agg, Nn, pbuf);
  bn_reduce_finalize<32><<<32, 256, 0, stream>>>(pbuf, g3, be3, invN, ss);
  bn_apply_elu_b2b<32><<<512, 256, 0, stream>>>(agg, ss, agg, Nn);  // in-place

  // --- classifier ---
  classifier_k<<<(Nn + 255) / 256, 256, 0, stream>>>(agg, Wc1, bc1, Wc2, bc2, outp, Nn);
}

// Round 10
// 597.935 us; speedup vs baseline: 1.6136x; 1.6136x over previous
//
#include <hip/hip_runtime.h>
#include <math.h>

typedef __attribute__((ext_vector_type(8))) short short8;
typedef __attribute__((ext_vector_type(4))) float f32x4;

// ---------------- bf16 helpers ----------------

__device__ __forceinline__ float bf2f(unsigned short u) {
  union { unsigned int i; float f; } v;
  v.i = ((unsigned int)u) << 16;
  return v.f;
}
__device__ __forceinline__ unsigned short f2bf(float f) {
  union { float f; unsigned int i; } v;
  v.f = f;
  unsigned int x = v.i;
  unsigned int r = x + 0x7fffu + ((x >> 16) & 1u);  // RNE
  return (unsigned short)(r >> 16);
}
__device__ __forceinline__ float lo16f(unsigned int u) {
  union { unsigned int i; float f; } v;
  v.i = u << 16;
  return v.f;
}
__device__ __forceinline__ float hi16f(unsigned int u) {
  union { unsigned int i; float f; } v;
  v.i = u & 0xffff0000u;
  return v.f;
}

// ---------------- CSR build ----------------

__global__ __launch_bounds__(256) void count_deg(const int* __restrict__ dstA,
                                                 int Ee, int Nn,
                                                 int* __restrict__ deg) {
  int e = blockIdx.x * 256 + threadIdx.x;
  if (e >= Ee + Nn) return;
  int d = (e < Ee) ? dstA[e] : (e - Ee);
  atomicAdd(&deg[d], 1);
}

__global__ __launch_bounds__(256) void scan_blk(const int* __restrict__ deg,
                                                int* __restrict__ exc,
                                                int* __restrict__ bsum, int Nn) {
  __shared__ int sd[256];
  int t = threadIdx.x;
  int i = blockIdx.x * 256 + t;
  int v = (i < Nn) ? deg[i] : 0;
  sd[t] = v;
  __syncthreads();
  #pragma unroll
  for (int s = 1; s < 256; s <<= 1) {
    int u = (t >= s) ? sd[t - s] : 0;
    __syncthreads();
    sd[t] += u;
    __syncthreads();
  }
  if (i < Nn) exc[i] = sd[t] - v;
  if (t == 255) bsum[blockIdx.x] = sd[255];
}

__global__ void scan_top(const int* __restrict__ bsum, int* __restrict__ boff,
                         int NB, int* __restrict__ off, int Nn) {
  __shared__ int sd[256];
  int t = threadIdx.x;
  int v = (t < NB) ? bsum[t] : 0;
  sd[t] = v;
  __syncthreads();
  #pragma unroll
  for (int s = 1; s < 256; s <<= 1) {
    int u = (t >= s) ? sd[t - s] : 0;
    __syncthreads();
    sd[t] += u;
    __syncthreads();
  }
  if (t < NB) boff[t] = sd[t] - v;
  if (t == 255) off[Nn] = sd[255];
}

__global__ __launch_bounds__(256) void scan_add(const int* __restrict__ exc,
                                                const int* __restrict__ boff,
                                                int* __restrict__ off,
                                                int* __restrict__ cursor, int Nn) {
  int i = blockIdx.x * 256 + threadIdx.x;
  if (i >= Nn) return;
  int o = exc[i] + boff[blockIdx.x];
  off[i] = o;
  cursor[i] = o;
}

__global__ __launch_bounds__(256) void fill_csr(const int* __restrict__ srcA,
                                                const int* __restrict__ dstA,
                                                int Ee, int Nn,
                                                int* __restrict__ cursor,
                                                int* __restrict__ col) {
  int e = blockIdx.x * 256 + threadIdx.x;
  if (e >= Ee + Nn) return;
  int s, d;
  if (e < Ee) { s = srcA[e]; d = dstA[e]; }
  else        { s = e - Ee;  d = s; }
  int slot = atomicAdd(&cursor[d], 1);
  col[slot] = s;
}

// ---------------- operand prep ----------------

__global__ __launch_bounds__(256) void cast_f32_bf16(const float* __restrict__ in,
                                                     unsigned short* __restrict__ out,
                                                     size_t n4) {
  for (size_t i = blockIdx.x * (size_t)256 + threadIdx.x; i < n4;
       i += (size_t)gridDim.x * 256) {
    float4 v = *(const float4*)&in[i * 4];
    ushort4 o;
    o.x = f2bf(v.x); o.y = f2bf(v.y); o.z = f2bf(v.z); o.w = f2bf(v.w);
    *(ushort4*)&out[i * 4] = o;
  }
}

// Wt[n][k] = bf16(W[k][n])
__global__ __launch_bounds__(256) void transpose_cast(const float* __restrict__ W,
                                                      unsigned short* __restrict__ Wt,
                                                      int K, int N) {
  int t = blockIdx.x * 256 + threadIdx.x;
  if (t >= K * N) return;
  int n = t / K, k = t % K;
  Wt[t] = f2bf(W[(size_t)k * N + n]);
}

// ---------------- bf16 MFMA GEMM: C[M,N] = A[M,K] @ Bt[N,K]^T ----------------

template <int BM, int BN, int WM, int WN>
__global__ __launch_bounds__(256) void gemm_mfma_bf16(
    const unsigned short* __restrict__ A,
    const unsigned short* __restrict__ Bt,
    unsigned short* __restrict__ C,
    int M, int N, int K) {
  constexpr int BK = 32;
  constexpr int LDA = BK + 8;
  constexpr int MF = WM / 16, NF = WN / 16;
  constexpr int NWN = BN / WN;
  constexpr int ACH = BM * BK / 8;
  constexpr int BCH = BN * BK / 8;
  constexpr int ACHT = (ACH + 255) / 256;
  constexpr int BCHT = (BCH + 255) / 256;

  __shared__ unsigned short Al[2][BM * LDA];
  __shared__ unsigned short Bl[2][BN * LDA];

  const int tid = threadIdx.x;
  const int wid = tid >> 6, lane = tid & 63;
  const int wr = wid / NWN, wc = wid % NWN;
  const int brow = blockIdx.y * BM;
  const int bcol = blockIdx.x * BN;

  f32x4 acc[MF][NF] = {};
  uint4 ra[ACHT], rb[BCHT];

  auto loadG = [&](int k0) {
    #pragma unroll
    for (int c = 0; c < ACHT; ++c) {
      int i = c * 256 + tid;
      if (ACH % 256 == 0 || i < ACH) {
        int row = i >> 2, blk = i & 3;
        int rg = brow + row;
        rg = rg < M ? rg : M - 1;
        ra[c] = *(const uint4*)&A[(size_t)rg * K + k0 + blk * 8];
      }
    }
    #pragma unroll
    for (int c = 0; c < BCHT; ++c) {
      int i = c * 256 + tid;
      if (BCH % 256 == 0 || i < BCH) {
        int row = i >> 2, blk = i & 3;
        rb[c] = *(const uint4*)&Bt[(size_t)(bcol + row) * K + k0 + blk * 8];
      }
    }
  };
  auto storeL = [&](int buf) {
    #pragma unroll
    for (int c = 0; c < ACHT; ++c) {
      int i = c * 256 + tid;
      if (ACH % 256 == 0 || i < ACH) {
        int row = i >> 2, blk = i & 3;
        *(uint4*)&Al[buf][row * LDA + blk * 8] = ra[c];
      }
    }
    #pragma unroll
    for (int c = 0; c < BCHT; ++c) {
      int i = c * 256 + tid;
      if (BCH % 256 == 0 || i < BCH) {
        int row = i >> 2, blk = i & 3;
        *(uint4*)&Bl[buf][row * LDA + blk * 8] = rb[c];
      }
    }
  };

  const int nt = K / BK;
  loadG(0);
  storeL(0);
  __syncthreads();
  int cur = 0;
  const int arow = wr * WM + (lane & 15);
  const int bro = wc * WN + (lane & 15);
  const int kb = (lane >> 4) * 8;
  for (int t = 0; t < nt; ++t) {
    if (t + 1 < nt) loadG((t + 1) * BK);
    short8 af[MF], bfr[NF];
    #pragma unroll
    for (int m = 0; m < MF; ++m)
      af[m] = *(const short8*)&Al[cur][(arow + m * 16) * LDA + kb];
    #pragma unroll
    for (int n = 0; n < NF; ++n)
      bfr[n] = *(const short8*)&Bl[cur][(bro + n * 16) * LDA + kb];
    #pragma unroll
    for (int m = 0; m < MF; ++m)
      #pragma unroll
      for (int n = 0; n < NF; ++n)
        acc[m][n] = __builtin_amdgcn_mfma_f32_16x16x32_bf16(af[m], bfr[n], acc[m][n], 0, 0, 0);
    if (t + 1 < nt) storeL(cur ^ 1);
    __syncthreads();
    cur ^= 1;
  }

  const int crow0 = brow + wr * WM + (lane >> 4) * 4;
  const int ccol0 = bcol + wc * WN + (lane & 15);
  #pragma unroll
  for (int m = 0; m < MF; ++m) {
    #pragma unroll
    for (int r = 0; r < 4; ++r) {
      int grow = crow0 + m * 16 + r;
      if (grow >= M) continue;
      #pragma unroll
      for (int n = 0; n < NF; ++n)
        C[(size_t)grow * N + ccol0 + n * 16] = f2bf(acc[m][n][r]);
    }
  }
}

// ---------------- per-node attention logits (bf16 h) ----------------

template <int HEADS, int CC>
__global__ __launch_bounds__(256) void attn_logits(const unsigned short* __restrict__ h,
                                                   const float* __restrict__ a_s,
                                                   const float* __restrict__ a_d,
                                                   float* __restrict__ als,
                                                   float* __restrict__ ald,
                                                   int Nn) {
  int wid = (int)((blockIdx.x * (size_t)blockDim.x + threadIdx.x) >> 6);
  int lane = threadIdx.x & 63;
  if (wid >= Nn) return;
  const unsigned short* hn = h + (size_t)wid * HEADS * CC;
  #pragma unroll
  for (int hh = 0; hh < HEADS; ++hh) {
    float vs = 0.f, vd = 0.f;
    if (lane < CC) {
      float v = bf2f(hn[hh * CC + lane]);
      vs = v * a_s[hh * CC + lane];
      vd = v * a_d[hh * CC + lane];
    }
    #pragma unroll
    for (int o = 32; o > 0; o >>= 1) {
      vs += __shfl_xor(vs, o, 64);
      vd += __shfl_xor(vd, o, 64);
    }
    if (lane == 0) {
      als[(size_t)wid * HEADS + hh] = vs;
      ald[(size_t)wid * HEADS + hh] = vd;
    }
  }
}

// ---------------- GAT aggregation: one wave per dst, V channels/lane ----------------
// REVERTED from per-(node,head) split (r8: 3x regression — gather is
// VMEM-instruction-efficiency-bound, not latency-bound; need wide per-lane
// vectors: ushort4 = 512B per wave instruction). bf16 out kept (halved write).

template <int HEADS, int CC, int V>
__global__ __launch_bounds__(256) void gat_aggregate(const unsigned short* __restrict__ h,
                                                     const float* __restrict__ als,
                                                     const float* __restrict__ ald,
                                                     const int* __restrict__ off,
                                                     const int* __restrict__ col,
                                                     const float* __restrict__ bias,
                                                     unsigned short* __restrict__ out,
                                                     int Nn) {
  constexpr int HC = HEADS * CC;
  int wid = (int)((blockIdx.x * (size_t)blockDim.x + threadIdx.x) >> 6);
  int lane = threadIdx.x & 63;
  if (wid >= Nn) return;
  int c0 = lane * V;
  if (c0 >= HC) return;
  int head = c0 / CC;
  float my_ald = ald[(size_t)wid * HEADS + head];
  float ssum = 0.f;
  float acc[V] = {};
  int beg = off[wid], end = off[wid + 1];
  for (int j = beg; j < end; ++j) {
    int s = col[j];
    float l = als[(size_t)s * HEADS + head] + my_ald;
    l = (l > 0.f) ? l : 0.2f * l;  // leaky_relu(0.2)
    float p = __expf(l);
    ssum += p;
    const unsigned short* hs = h + (size_t)s * HC + c0;
    if constexpr (V == 4) {
      ushort4 hv = *(const ushort4*)hs;
      acc[0] += p * bf2f(hv.x);
      acc[1] += p * bf2f(hv.y);
      acc[2] += p * bf2f(hv.z);
      acc[3] += p * bf2f(hv.w);
    } else {
      #pragma unroll
      for (int k2 = 0; k2 < V; ++k2) acc[k2] += p * bf2f(hs[k2]);
    }
  }
  float inv = 1.f / (ssum + 1e-16f);
  #pragma unroll
  for (int k2 = 0; k2 < V; ++k2)
    out[(size_t)wid * HC + c0 + k2] = f2bf(acc[k2] * inv + bias[c0 + k2]);
}

// ---------------- BatchNorm (biased var) — parallel two-stage, bf16 input ----------------

constexpr int BN_NB = 1024;

template <int CH>
__global__ __launch_bounds__(256) void bn_stats_part(const unsigned short* __restrict__ x,
                                                     int Nn, float* __restrict__ pbuf) {
  constexpr int Q8 = CH / 8;  // uint4 (8 bf16) groups per row: 32 or 4; divides 256
  int t = threadIdx.x;
  size_t tot8 = (size_t)Nn * Q8;
  size_t stride = (size_t)gridDim.x * 256;  // multiple of Q8 -> fixed group per thread
  float s[8] = {}, sq[8] = {};
  for (size_t i = blockIdx.x * (size_t)256 + t; i < tot8; i += stride) {
    uint4 u = *(const uint4*)&x[i * 8];
    float v[8] = {lo16f(u.x), hi16f(u.x), lo16f(u.y), hi16f(u.y),
                  lo16f(u.z), hi16f(u.z), lo16f(u.w), hi16f(u.w)};
    #pragma unroll
    for (int k = 0; k < 8; ++k) { s[k] += v[k]; sq[k] += v[k] * v[k]; }
  }
  __shared__ float sS[256][8];
  __shared__ float sQ[256][8];
  #pragma unroll
  for (int k = 0; k < 8; ++k) { sS[t][k] = s[k]; sQ[t][k] = sq[k]; }
  __syncthreads();
  for (int half = 128; half >= Q8; half >>= 1) {  // half % Q8 == 0 -> same group
    if (t < half) {
      #pragma unroll
      for (int k = 0; k < 8; ++k) {
        sS[t][k] += sS[t + half][k];
        sQ[t][k] += sQ[t + half][k];
      }
    }
    __syncthreads();
  }
  if (t < Q8) {
    #pragma unroll
    for (int k = 0; k < 8; ++k) {
      pbuf[(size_t)blockIdx.x * 2 * CH + t * 8 + k] = sS[t][k];
      pbuf[(size_t)blockIdx.x * 2 * CH + CH + t * 8 + k] = sQ[t][k];
    }
  }
}

template <int CH>
__global__ __launch_bounds__(256) void bn_reduce_finalize(const float* __restrict__ pbuf,
                                                          const float* __restrict__ g,
                                                          const float* __restrict__ be,
                                                          float invN,
                                                          float* __restrict__ ss) {
  int c = blockIdx.x;  // one block per channel
  int t = threadIdx.x;
  float s = 0.f, q = 0.f;
  for (int b = t; b < BN_NB; b += 256) {
    s += pbuf[(size_t)b * 2 * CH + c];
    q += pbuf[(size_t)b * 2 * CH + CH + c];
  }
  #pragma unroll
  for (int o = 32; o > 0; o >>= 1) {
    s += __shfl_xor(s, o, 64);
    q += __shfl_xor(q, o, 64);
  }
  __shared__ float rs[4], rq[4];
  int wv = t >> 6, lane = t & 63;
  if (lane == 0) { rs[wv] = s; rq[wv] = q; }
  __syncthreads();
  if (t == 0) {
    float S = rs[0] + rs[1] + rs[2] + rs[3];
    float Qs = rq[0] + rq[1] + rq[2] + rq[3];
    float mu = S * invN;
    float var = Qs * invN - mu * mu;
    float sc = g[c] * rsqrtf(var + 1e-5f);
    ss[c] = sc;
    ss[CH + c] = be[c] - mu * sc;
  }
}

// BN-apply + ELU, bf16 in -> bf16 out (usable in-place when out == x).
template <int CH>
__global__ __launch_bounds__(256) void bn_apply_elu_b2b(const unsigned short* __restrict__ x,
                                                        const float* __restrict__ ss,
                                                        unsigned short* __restrict__ out,
                                                        int Nn) {
  size_t tot8 = (size_t)Nn * (CH / 8);
  for (size_t i = blockIdx.x * (size_t)256 + threadIdx.x; i < tot8;
       i += (size_t)gridDim.x * 256) {
    uint4 u = *(const uint4*)&x[i * 8];
    int c0 = (int)((i % (CH / 8)) * 8);
    float v[8] = {lo16f(u.x), hi16f(u.x), lo16f(u.y), hi16f(u.y),
                  lo16f(u.z), hi16f(u.z), lo16f(u.w), hi16f(u.w)};
    unsigned int o[4];
    #pragma unroll
    for (int k = 0; k < 4; ++k) {
      float y0 = v[2 * k] * ss[c0 + 2 * k] + ss[CH + c0 + 2 * k];
      float y1 = v[2 * k + 1] * ss[c0 + 2 * k + 1] + ss[CH + c0 + 2 * k + 1];
      y0 = (y0 > 0.f) ? y0 : expm1f(y0);
      y1 = (y1 > 0.f) ? y1 : expm1f(y1);
      o[k] = (unsigned int)f2bf(y0) | ((unsigned int)f2bf(y1) << 16);
    }
    *(uint4*)&out[i * 8] = make_uint4(o[0], o[1], o[2], o[3]);
  }
}

// ---------------- classifier: relu(x@Wc1+bc1)@Wc2+bc2 (bf16 x) ----------------

__global__ __launch_bounds__(256) void classifier_k(const unsigned short* __restrict__ x,
                                                    const float* __restrict__ Wc1,
                                                    const float* __restrict__ bc1,
                                                    const float* __restrict__ Wc2,
                                                    const float* __restrict__ bc2,
                                                    float* __restrict__ outp, int Nn) {
  __shared__ unsigned short sx[256][33];
  __shared__ float sw[32 * 32];
  __shared__ float sb1[32];
  __shared__ float sw2[32];
  int t = threadIdx.x;
  int base = blockIdx.x * 256;
  for (int i = t; i < 1024; i += 256) sw[i] = Wc1[i];
  if (t < 32) { sb1[t] = bc1[t]; sw2[t] = Wc2[t]; }
  int cnt = min(256, Nn - base);
  for (int i = t; i < cnt * 32; i += 256) sx[i / 32][i % 32] = x[(size_t)base * 32 + i];
  __syncthreads();
  if (t < cnt) {
    float xa[32];
    #pragma unroll
    for (int c = 0; c < 32; ++c) xa[c] = bf2f(sx[t][c]);
    float o = bc2[0];
    #pragma unroll
    for (int j = 0; j < 32; ++j) {
      float v = sb1[j];
      #pragma unroll
      for (int c = 0; c < 32; ++c) v += xa[c] * sw[c * 32 + j];
      v = fmaxf(v, 0.f);
      o += v * sw2[j];
    }
    outp[base + t] = o;
  }
}

// ---------------- host orchestration ----------------

extern "C" void kernel_launch(void* const* d_in, const int* in_sizes, int n_in,
                              void* d_out, int out_size, void* d_ws, size_t ws_size,
                              hipStream_t stream) {
  const float* x   = (const float*)d_in[0];
  const int*   ei  = (const int*)d_in[1];
  const float* W1  = (const float*)d_in[2];
  const float* as1 = (const float*)d_in[3];
  const float* ad1 = (const float*)d_in[4];
  const float* b1  = (const float*)d_in[5];
  const float* g1  = (const float*)d_in[6];
  const float* be1 = (const float*)d_in[7];
  const float* W2  = (const float*)d_in[8];
  const float* as2 = (const float*)d_in[9];
  const float* ad2 = (const float*)d_in[10];
  const float* b2  = (const float*)d_in[11];
  const float* g2  = (const float*)d_in[12];
  const float* be2 = (const float*)d_in[13];
  const float* W3  = (const float*)d_in[14];
  const float* as3 = (const float*)d_in[15];
  const float* ad3 = (const float*)d_in[16];
  const float* b3  = (const float*)d_in[17];
  const float* g3  = (const float*)d_in[18];
  const float* be3 = (const float*)d_in[19];
  const float* Wc1 = (const float*)d_in[20];
  const float* bc1 = (const float*)d_in[21];
  const float* Wc2 = (const float*)d_in[22];
  const float* bc2 = (const float*)d_in[23];
  float* outp = (float*)d_out;

  const int Nn = in_sizes[0] / 128;
  const int Ee = in_sizes[1] / 2;
  const int TotE = Ee + Nn;
  const int* esrc = ei;
  const int* edst = ei + Ee;

  char* w = (char*)d_ws;
  auto carve = [&](size_t bytes) {
    char* p = w;
    w += (bytes + 255) & ~(size_t)255;
    return p;
  };
  unsigned short* hb  = (unsigned short*)carve((size_t)Nn * 256 * 2);
  unsigned short* xb  = (unsigned short*)carve((size_t)Nn * 256 * 2);
  unsigned short* agg = (unsigned short*)carve((size_t)Nn * 256 * 2);
  float* als   = (float*)carve((size_t)Nn * 4 * 4);
  float* ald   = (float*)carve((size_t)Nn * 4 * 4);
  float* pbuf  = (float*)carve((size_t)BN_NB * 512 * 4);
  float* ss    = (float*)carve(512 * 4);
  unsigned short* Wt1 = (unsigned short*)carve(256 * 128 * 2);
  unsigned short* Wt2 = (unsigned short*)carve(256 * 256 * 2);
  unsigned short* Wt3 = (unsigned short*)carve(32 * 256 * 2);
  int* deg     = (int*)carve((size_t)Nn * 4);
  int* off     = (int*)carve((size_t)(Nn + 1) * 4);
  int* cursor  = (int*)carve((size_t)Nn * 4);
  int* col     = (int*)carve((size_t)TotE * 4);
  int* exc     = (int*)carve((size_t)Nn * 4);
  int* bsum    = (int*)carve(256 * 4);
  int* boff    = (int*)carve(256 * 4);

  // --- operand prep ---
  cast_f32_bf16<<<2048, 256, 0, stream>>>(x, xb, (size_t)Nn * 128 / 4);
  transpose_cast<<<(128 * 256 + 255) / 256, 256, 0, stream>>>(W1, Wt1, 128, 256);
  transpose_cast<<<(256 * 256 + 255) / 256, 256, 0, stream>>>(W2, Wt2, 256, 256);
  transpose_cast<<<(256 * 32 + 255) / 256, 256, 0, stream>>>(W3, Wt3, 256, 32);

  // --- CSR build (shared by all 3 layers); hierarchical scan ---
  const int NB = (Nn + 255) / 256;
  hipMemsetAsync(deg, 0, (size_t)Nn * 4, stream);
  count_deg<<<(TotE + 255) / 256, 256, 0, stream>>>(edst, Ee, Nn, deg);
  scan_blk<<<NB, 256, 0, stream>>>(deg, exc, bsum, Nn);
  scan_top<<<1, 256, 0, stream>>>(bsum, boff, NB, off, Nn);
  scan_add<<<NB, 256, 0, stream>>>(exc, boff, off, cursor, Nn);
  fill_csr<<<(TotE + 255) / 256, 256, 0, stream>>>(esrc, edst, Ee, Nn, cursor, col);

  int waveBlocks = (Nn + 3) / 4;
  int gy = (Nn + 127) / 128;
  float invN = 1.0f / (float)Nn;

  // --- Layer 1: 128 -> 4x64 concat ---
  gemm_mfma_bf16<128, 128, 64, 64><<<dim3(2, gy), 256, 0, stream>>>(xb, Wt1, hb, Nn, 256, 128);
  attn_logits<4, 64><<<waveBlocks, 256, 0, stream>>>(hb, as1, ad1, als, ald, Nn);
  gat_aggregate<4, 64, 4><<<waveBlocks, 256, 0, stream>>>(hb, als, ald, off, col, b1, agg, Nn);
  bn_stats_part<256><<<BN_NB, 256, 0, stream>>>(agg, Nn, pbuf);
  bn_reduce_finalize<256><<<256, 256, 0, stream>>>(pbuf, g1, be1, invN, ss);
  bn_apply_elu_b2b<256><<<2048, 256, 0, stream>>>(agg, ss, xb, Nn);

  // --- Layer 2: 256 -> 4x64 concat ---
  gemm_mfma_bf16<128, 128, 64, 64><<<dim3(2, gy), 256, 0, stream>>>(xb, Wt2, hb, Nn, 256, 256);
  attn_logits<4, 64><<<waveBlocks, 256, 0, stream>>>(hb, as2, ad2, als, ald, Nn);
  gat_aggregate<4, 64, 4><<<waveBlocks, 256, 0, stream>>>(hb, als, ald, off, col, b2, agg, Nn);
  bn_stats_part<256><<<BN_NB, 256, 0, stream>>>(agg, Nn, pbuf);
  bn_reduce_finalize<256><<<256, 256, 0, stream>>>(pbuf, g2, be2, invN, ss);
  bn_apply_elu_b2b<256><<<2048, 256, 0, stream>>>(agg, ss, xb, Nn);

  // --- Layer 3: 256 -> 1x32, no concat ---
  gemm_mfma_bf16<128, 32, 32, 32><<<dim3(1, gy), 256, 0, stream>>>(xb, Wt3, hb, Nn, 32, 256);
  attn_logits<1, 32><<<waveBlocks, 256, 0, stream>>>(hb, as3, ad3, als, ald, Nn);
  gat_aggregate<1, 32, 1><<<waveBlocks, 256, 0, stream>>>(hb, als, ald, off, col, b3, agg, Nn);
  bn_stats_part<32><<<BN_NB, 256, 0, stream>>>(agg, Nn, pbuf);
  bn_reduce_finalize<32><<<32, 256, 0, stream>>>(pbuf, g3, be3, invN, ss);
  bn_apply_elu_b2b<32><<<512, 256, 0, stream>>>(agg, ss, agg, Nn);  // in-place

  // --- classifier ---
  classifier_k<<<(Nn + 255) / 256, 256, 0, stream>>>(agg, Wc1, bc1, Wc2, bc2, outp, Nn);
}

// Round 12
// 494.991 us; speedup vs baseline: 1.9492x; 1.2080x over previous
//
#include <hip/hip_runtime.h>
#include <math.h>

typedef __attribute__((ext_vector_type(8))) short short8;
typedef __attribute__((ext_vector_type(4))) float f32x4;

// ---------------- bf16 helpers ----------------

__device__ __forceinline__ float bf2f(unsigned short u) {
  union { unsigned int i; float f; } v;
  v.i = ((unsigned int)u) << 16;
  return v.f;
}
__device__ __forceinline__ unsigned short f2bf(float f) {
  union { float f; unsigned int i; } v;
  v.f = f;
  unsigned int x = v.i;
  unsigned int r = x + 0x7fffu + ((x >> 16) & 1u);  // RNE
  return (unsigned short)(r >> 16);
}
__device__ __forceinline__ float lo16f(unsigned int u) {
  union { unsigned int i; float f; } v;
  v.i = u << 16;
  return v.f;
}
__device__ __forceinline__ float hi16f(unsigned int u) {
  union { unsigned int i; float f; } v;
  v.i = u & 0xffff0000u;
  return v.f;
}

// ---------------- CSR build ----------------

__global__ __launch_bounds__(256) void count_deg(const int* __restrict__ dstA,
                                                 int Ee, int Nn,
                                                 int* __restrict__ deg) {
  int e = blockIdx.x * 256 + threadIdx.x;
  if (e >= Ee + Nn) return;
  int d = (e < Ee) ? dstA[e] : (e - Ee);
  atomicAdd(&deg[d], 1);
}

__global__ __launch_bounds__(256) void scan_blk(const int* __restrict__ deg,
                                                int* __restrict__ exc,
                                                int* __restrict__ bsum, int Nn) {
  __shared__ int sd[256];
  int t = threadIdx.x;
  int i = blockIdx.x * 256 + t;
  int v = (i < Nn) ? deg[i] : 0;
  sd[t] = v;
  __syncthreads();
  #pragma unroll
  for (int s = 1; s < 256; s <<= 1) {
    int u = (t >= s) ? sd[t - s] : 0;
    __syncthreads();
    sd[t] += u;
    __syncthreads();
  }
  if (i < Nn) exc[i] = sd[t] - v;
  if (t == 255) bsum[blockIdx.x] = sd[255];
}

__global__ void scan_top(const int* __restrict__ bsum, int* __restrict__ boff,
                         int NB, int* __restrict__ off, int Nn) {
  __shared__ int sd[256];
  int t = threadIdx.x;
  int v = (t < NB) ? bsum[t] : 0;
  sd[t] = v;
  __syncthreads();
  #pragma unroll
  for (int s = 1; s < 256; s <<= 1) {
    int u = (t >= s) ? sd[t - s] : 0;
    __syncthreads();
    sd[t] += u;
    __syncthreads();
  }
  if (t < NB) boff[t] = sd[t] - v;
  if (t == 255) off[Nn] = sd[255];
}

__global__ __launch_bounds__(256) void scan_add(const int* __restrict__ exc,
                                                const int* __restrict__ boff,
                                                int* __restrict__ off,
                                                int* __restrict__ cursor, int Nn) {
  int i = blockIdx.x * 256 + threadIdx.x;
  if (i >= Nn) return;
  int o = exc[i] + boff[blockIdx.x];
  off[i] = o;
  cursor[i] = o;
}

__global__ __launch_bounds__(256) void fill_csr(const int* __restrict__ srcA,
                                                const int* __restrict__ dstA,
                                                int Ee, int Nn,
                                                int* __restrict__ cursor,
                                                int* __restrict__ col) {
  int e = blockIdx.x * 256 + threadIdx.x;
  if (e >= Ee + Nn) return;
  int s, d;
  if (e < Ee) { s = srcA[e]; d = dstA[e]; }
  else        { s = e - Ee;  d = s; }
  int slot = atomicAdd(&cursor[d], 1);
  col[slot] = s;
}

// ---------------- operand prep ----------------

__global__ __launch_bounds__(256) void cast_f32_bf16(const float* __restrict__ in,
                                                     unsigned short* __restrict__ out,
                                                     size_t n4) {
  for (size_t i = blockIdx.x * (size_t)256 + threadIdx.x; i < n4;
       i += (size_t)gridDim.x * 256) {
    float4 v = *(const float4*)&in[i * 4];
    ushort4 o;
    o.x = f2bf(v.x); o.y = f2bf(v.y); o.z = f2bf(v.z); o.w = f2bf(v.w);
    *(ushort4*)&out[i * 4] = o;
  }
}

// Wt[n][k] = bf16(W[k][n])
__global__ __launch_bounds__(256) void transpose_cast(const float* __restrict__ W,
                                                      unsigned short* __restrict__ Wt,
                                                      int K, int N) {
  int t = blockIdx.x * 256 + threadIdx.x;
  if (t >= K * N) return;
  int n = t / K, k = t % K;
  Wt[t] = f2bf(W[(size_t)k * N + n]);
}

// ---------------- bf16 MFMA GEMM: C[M,N] = A[M,K] @ Bt[N,K]^T ----------------

template <int BM, int BN, int WM, int WN>
__global__ __launch_bounds__(256) void gemm_mfma_bf16(
    const unsigned short* __restrict__ A,
    const unsigned short* __restrict__ Bt,
    unsigned short* __restrict__ C,
    int M, int N, int K) {
  constexpr int BK = 32;
  constexpr int LDA = BK + 8;
  constexpr int MF = WM / 16, NF = WN / 16;
  constexpr int NWN = BN / WN;
  constexpr int ACH = BM * BK / 8;
  constexpr int BCH = BN * BK / 8;
  constexpr int ACHT = (ACH + 255) / 256;
  constexpr int BCHT = (BCH + 255) / 256;

  __shared__ unsigned short Al[2][BM * LDA];
  __shared__ unsigned short Bl[2][BN * LDA];

  const int tid = threadIdx.x;
  const int wid = tid >> 6, lane = tid & 63;
  const int wr = wid / NWN, wc = wid % NWN;
  const int brow = blockIdx.y * BM;
  const int bcol = blockIdx.x * BN;

  f32x4 acc[MF][NF] = {};
  uint4 ra[ACHT], rb[BCHT];

  auto loadG = [&](int k0) {
    #pragma unroll
    for (int c = 0; c < ACHT; ++c) {
      int i = c * 256 + tid;
      if (ACH % 256 == 0 || i < ACH) {
        int row = i >> 2, blk = i & 3;
        int rg = brow + row;
        rg = rg < M ? rg : M - 1;
        ra[c] = *(const uint4*)&A[(size_t)rg * K + k0 + blk * 8];
      }
    }
    #pragma unroll
    for (int c = 0; c < BCHT; ++c) {
      int i = c * 256 + tid;
      if (BCH % 256 == 0 || i < BCH) {
        int row = i >> 2, blk = i & 3;
        rb[c] = *(const uint4*)&Bt[(size_t)(bcol + row) * K + k0 + blk * 8];
      }
    }
  };
  auto storeL = [&](int buf) {
    #pragma unroll
    for (int c = 0; c < ACHT; ++c) {
      int i = c * 256 + tid;
      if (ACH % 256 == 0 || i < ACH) {
        int row = i >> 2, blk = i & 3;
        *(uint4*)&Al[buf][row * LDA + blk * 8] = ra[c];
      }
    }
    #pragma unroll
    for (int c = 0; c < BCHT; ++c) {
      int i = c * 256 + tid;
      if (BCH % 256 == 0 || i < BCH) {
        int row = i >> 2, blk = i & 3;
        *(uint4*)&Bl[buf][row * LDA + blk * 8] = rb[c];
      }
    }
  };

  const int nt = K / BK;
  loadG(0);
  storeL(0);
  __syncthreads();
  int cur = 0;
  const int arow = wr * WM + (lane & 15);
  const int bro = wc * WN + (lane & 15);
  const int kb = (lane >> 4) * 8;
  for (int t = 0; t < nt; ++t) {
    if (t + 1 < nt) loadG((t + 1) * BK);
    short8 af[MF], bfr[NF];
    #pragma unroll
    for (int m = 0; m < MF; ++m)
      af[m] = *(const short8*)&Al[cur][(arow + m * 16) * LDA + kb];
    #pragma unroll
    for (int n = 0; n < NF; ++n)
      bfr[n] = *(const short8*)&Bl[cur][(bro + n * 16) * LDA + kb];
    #pragma unroll
    for (int m = 0; m < MF; ++m)
      #pragma unroll
      for (int n = 0; n < NF; ++n)
        acc[m][n] = __builtin_amdgcn_mfma_f32_16x16x32_bf16(af[m], bfr[n], acc[m][n], 0, 0, 0);
    if (t + 1 < nt) storeL(cur ^ 1);
    __syncthreads();
    cur ^= 1;
  }

  const int crow0 = brow + wr * WM + (lane >> 4) * 4;
  const int ccol0 = bcol + wc * WN + (lane & 15);
  #pragma unroll
  for (int m = 0; m < MF; ++m) {
    #pragma unroll
    for (int r = 0; r < 4; ++r) {
      int grow = crow0 + m * 16 + r;
      if (grow >= M) continue;
      #pragma unroll
      for (int n = 0; n < NF; ++n)
        C[(size_t)grow * N + ccol0 + n * 16] = f2bf(acc[m][n][r]);
    }
  }
}

// ---------------- per-node attention logits (bf16 h) ----------------

template <int HEADS, int CC>
__global__ __launch_bounds__(256) void attn_logits(const unsigned short* __restrict__ h,
                                                   const float* __restrict__ a_s,
                                                   const float* __restrict__ a_d,
                                                   float* __restrict__ als,
                                                   float* __restrict__ ald,
                                                   int Nn) {
  int wid = (int)((blockIdx.x * (size_t)blockDim.x + threadIdx.x) >> 6);
  int lane = threadIdx.x & 63;
  if (wid >= Nn) return;
  const unsigned short* hn = h + (size_t)wid * HEADS * CC;
  #pragma unroll
  for (int hh = 0; hh < HEADS; ++hh) {
    float vs = 0.f, vd = 0.f;
    if (lane < CC) {
      float v = bf2f(hn[hh * CC + lane]);
      vs = v * a_s[hh * CC + lane];
      vd = v * a_d[hh * CC + lane];
    }
    #pragma unroll
    for (int o = 32; o > 0; o >>= 1) {
      vs += __shfl_xor(vs, o, 64);
      vd += __shfl_xor(vd, o, 64);
    }
    if (lane == 0) {
      als[(size_t)wid * HEADS + hh] = vs;
      ald[(size_t)wid * HEADS + hh] = vd;
    }
  }
}

// ---------------- GAT aggregation: one wave per dst, 4-edge unroll ----------------
// r10 diagnosis: FETCH = 8 XCD x table = structural floor; 103us at VALUBusy 32%
// and ~5 waves/SIMD => latency-bound with ~1 gather in flight per wave.
// Fix: batch 4 edges — issue 4 independent 512B gathers before any use (4x MLP).

template <int HEADS, int CC, int V>
__global__ __launch_bounds__(256) void gat_aggregate(const unsigned short* __restrict__ h,
                                                     const float* __restrict__ als,
                                                     const float* __restrict__ ald,
                                                     const int* __restrict__ off,
                                                     const int* __restrict__ col,
                                                     const float* __restrict__ bias,
                                                     unsigned short* __restrict__ out,
                                                     int Nn) {
  constexpr int HC = HEADS * CC;
  int wid = (int)((blockIdx.x * (size_t)blockDim.x + threadIdx.x) >> 6);
  int lane = threadIdx.x & 63;
  if (wid >= Nn) return;
  int c0 = lane * V;
  if (c0 >= HC) return;
  int head = c0 / CC;
  float my_ald = ald[(size_t)wid * HEADS + head];
  float ssum = 0.f;
  float acc[V] = {};
  int beg = off[wid], end = off[wid + 1];

  auto lrelu = [](float l) { return (l > 0.f) ? l : 0.2f * l; };

  int j = beg;
  for (; j + 4 <= end; j += 4) {
    int s0 = col[j], s1 = col[j + 1], s2 = col[j + 2], s3 = col[j + 3];
    // issue all 4 gathers up front (independent -> 4 in flight)
    const unsigned short* h0 = h + (size_t)s0 * HC + c0;
    const unsigned short* h1 = h + (size_t)s1 * HC + c0;
    const unsigned short* h2 = h + (size_t)s2 * HC + c0;
    const unsigned short* h3 = h + (size_t)s3 * HC + c0;
    if constexpr (V == 4) {
      ushort4 g0 = *(const ushort4*)h0;
      ushort4 g1 = *(const ushort4*)h1;
      ushort4 g2 = *(const ushort4*)h2;
      ushort4 g3 = *(const ushort4*)h3;
      float p0 = __expf(lrelu(als[(size_t)s0 * HEADS + head] + my_ald));
      float p1 = __expf(lrelu(als[(size_t)s1 * HEADS + head] + my_ald));
      float p2 = __expf(lrelu(als[(size_t)s2 * HEADS + head] + my_ald));
      float p3 = __expf(lrelu(als[(size_t)s3 * HEADS + head] + my_ald));
      ssum += (p0 + p1) + (p2 + p3);
      acc[0] += p0 * bf2f(g0.x) + p1 * bf2f(g1.x) + p2 * bf2f(g2.x) + p3 * bf2f(g3.x);
      acc[1] += p0 * bf2f(g0.y) + p1 * bf2f(g1.y) + p2 * bf2f(g2.y) + p3 * bf2f(g3.y);
      acc[2] += p0 * bf2f(g0.z) + p1 * bf2f(g1.z) + p2 * bf2f(g2.z) + p3 * bf2f(g3.z);
      acc[3] += p0 * bf2f(g0.w) + p1 * bf2f(g1.w) + p2 * bf2f(g2.w) + p3 * bf2f(g3.w);
    } else {
      unsigned short g0 = *h0, g1 = *h1, g2 = *h2, g3 = *h3;
      float p0 = __expf(lrelu(als[(size_t)s0 * HEADS + head] + my_ald));
      float p1 = __expf(lrelu(als[(size_t)s1 * HEADS + head] + my_ald));
      float p2 = __expf(lrelu(als[(size_t)s2 * HEADS + head] + my_ald));
      float p3 = __expf(lrelu(als[(size_t)s3 * HEADS + head] + my_ald));
      ssum += (p0 + p1) + (p2 + p3);
      acc[0] += p0 * bf2f(g0) + p1 * bf2f(g1) + p2 * bf2f(g2) + p3 * bf2f(g3);
    }
  }
  for (; j < end; ++j) {
    int s = col[j];
    float p = __expf(lrelu(als[(size_t)s * HEADS + head] + my_ald));
    ssum += p;
    const unsigned short* hs = h + (size_t)s * HC + c0;
    if constexpr (V == 4) {
      ushort4 hv = *(const ushort4*)hs;
      acc[0] += p * bf2f(hv.x);
      acc[1] += p * bf2f(hv.y);
      acc[2] += p * bf2f(hv.z);
      acc[3] += p * bf2f(hv.w);
    } else {
      acc[0] += p * bf2f(hs[0]);
    }
  }
  float inv = 1.f / (ssum + 1e-16f);
  #pragma unroll
  for (int k2 = 0; k2 < V; ++k2)
    out[(size_t)wid * HC + c0 + k2] = f2bf(acc[k2] * inv + bias[c0 + k2]);
}

// ---------------- BatchNorm (biased var) — parallel two-stage, bf16 input ----------------

constexpr int BN_NB = 1024;

template <int CH>
__global__ __launch_bounds__(256) void bn_stats_part(const unsigned short* __restrict__ x,
                                                     int Nn, float* __restrict__ pbuf) {
  constexpr int Q8 = CH / 8;  // uint4 (8 bf16) groups per row: 32 or 4; divides 256
  int t = threadIdx.x;
  size_t tot8 = (size_t)Nn * Q8;
  size_t stride = (size_t)gridDim.x * 256;  // multiple of Q8 -> fixed group per thread
  float s[8] = {}, sq[8] = {};
  for (size_t i = blockIdx.x * (size_t)256 + t; i < tot8; i += stride) {
    uint4 u = *(const uint4*)&x[i * 8];
    float v[8] = {lo16f(u.x), hi16f(u.x), lo16f(u.y), hi16f(u.y),
                  lo16f(u.z), hi16f(u.z), lo16f(u.w), hi16f(u.w)};
    #pragma unroll
    for (int k = 0; k < 8; ++k) { s[k] += v[k]; sq[k] += v[k] * v[k]; }
  }
  __shared__ float sS[256][8];
  __shared__ float sQ[256][8];
  #pragma unroll
  for (int k = 0; k < 8; ++k) { sS[t][k] = s[k]; sQ[t][k] = sq[k]; }
  __syncthreads();
  for (int half = 128; half >= Q8; half >>= 1) {  // half % Q8 == 0 -> same group
    if (t < half) {
      #pragma unroll
      for (int k = 0; k < 8; ++k) {
        sS[t][k] += sS[t + half][k];
        sQ[t][k] += sQ[t + half][k];
      }
    }
    __syncthreads();
  }
  if (t < Q8) {
    #pragma unroll
    for (int k = 0; k < 8; ++k) {
      pbuf[(size_t)blockIdx.x * 2 * CH + t * 8 + k] = sS[t][k];
      pbuf[(size_t)blockIdx.x * 2 * CH + CH + t * 8 + k] = sQ[t][k];
    }
  }
}

template <int CH>
__global__ __launch_bounds__(256) void bn_reduce_finalize(const float* __restrict__ pbuf,
                                                          const float* __restrict__ g,
                                                          const float* __restrict__ be,
                                                          float invN,
                                                          float* __restrict__ ss) {
  int c = blockIdx.x;  // one block per channel
  int t = threadIdx.x;
  float s = 0.f, q = 0.f;
  for (int b = t; b < BN_NB; b += 256) {
    s += pbuf[(size_t)b * 2 * CH + c];
    q += pbuf[(size_t)b * 2 * CH + CH + c];
  }
  #pragma unroll
  for (int o = 32; o > 0; o >>= 1) {
    s += __shfl_xor(s, o, 64);
    q += __shfl_xor(q, o, 64);
  }
  __shared__ float rs[4], rq[4];
  int wv = t >> 6, lane = t & 63;
  if (lane == 0) { rs[wv] = s; rq[wv] = q; }
  __syncthreads();
  if (t == 0) {
    float S = rs[0] + rs[1] + rs[2] + rs[3];
    float Qs = rq[0] + rq[1] + rq[2] + rq[3];
    float mu = S * invN;
    float var = Qs * invN - mu * mu;
    float sc = g[c] * rsqrtf(var + 1e-5f);
    ss[c] = sc;
    ss[CH + c] = be[c] - mu * sc;
  }
}

// BN-apply + ELU, bf16 in -> bf16 out (usable in-place when out == x).
template <int CH>
__global__ __launch_bounds__(256) void bn_apply_elu_b2b(const unsigned short* __restrict__ x,
                                                        const float* __restrict__ ss,
                                                        unsigned short* __restrict__ out,
                                                        int Nn) {
  size_t tot8 = (size_t)Nn * (CH / 8);
  for (size_t i = blockIdx.x * (size_t)256 + threadIdx.x; i < tot8;
       i += (size_t)gridDim.x * 256) {
    uint4 u = *(const uint4*)&x[i * 8];
    int c0 = (int)((i % (CH / 8)) * 8);
    float v[8] = {lo16f(u.x), hi16f(u.x), lo16f(u.y), hi16f(u.y),
                  lo16f(u.z), hi16f(u.z), lo16f(u.w), hi16f(u.w)};
    unsigned int o[4];
    #pragma unroll
    for (int k = 0; k < 4; ++k) {
      float y0 = v[2 * k] * ss[c0 + 2 * k] + ss[CH + c0 + 2 * k];
      float y1 = v[2 * k + 1] * ss[c0 + 2 * k + 1] + ss[CH + c0 + 2 * k + 1];
      y0 = (y0 > 0.f) ? y0 : expm1f(y0);
      y1 = (y1 > 0.f) ? y1 : expm1f(y1);
      o[k] = (unsigned int)f2bf(y0) | ((unsigned int)f2bf(y1) << 16);
    }
    *(uint4*)&out[i * 8] = make_uint4(o[0], o[1], o[2], o[3]);
  }
}

// ---------------- classifier: relu(x@Wc1+bc1)@Wc2+bc2 (bf16 x) ----------------

__global__ __launch_bounds__(256) void classifier_k(const unsigned short* __restrict__ x,
                                                    const float* __restrict__ Wc1,
                                                    const float* __restrict__ bc1,
                                                    const float* __restrict__ Wc2,
                                                    const float* __restrict__ bc2,
                                                    float* __restrict__ outp, int Nn) {
  __shared__ unsigned short sx[256][33];
  __shared__ float sw[32 * 32];
  __shared__ float sb1[32];
  __shared__ float sw2[32];
  int t = threadIdx.x;
  int base = blockIdx.x * 256;
  for (int i = t; i < 1024; i += 256) sw[i] = Wc1[i];
  if (t < 32) { sb1[t] = bc1[t]; sw2[t] = Wc2[t]; }
  int cnt = min(256, Nn - base);
  for (int i = t; i < cnt * 32; i += 256) sx[i / 32][i % 32] = x[(size_t)base * 32 + i];
  __syncthreads();
  if (t < cnt) {
    float xa[32];
    #pragma unroll
    for (int c = 0; c < 32; ++c) xa[c] = bf2f(sx[t][c]);
    float o = bc2[0];
    #pragma unroll
    for (int j = 0; j < 32; ++j) {
      float v = sb1[j];
      #pragma unroll
      for (int c = 0; c < 32; ++c) v += xa[c] * sw[c * 32 + j];
      v = fmaxf(v, 0.f);
      o += v * sw2[j];
    }
    outp[base + t] = o;
  }
}

// ---------------- host orchestration ----------------

extern "C" void kernel_launch(void* const* d_in, const int* in_sizes, int n_in,
                              void* d_out, int out_size, void* d_ws, size_t ws_size,
                              hipStream_t stream) {
  const float* x   = (const float*)d_in[0];
  const int*   ei  = (const int*)d_in[1];
  const float* W1  = (const float*)d_in[2];
  const float* as1 = (const float*)d_in[3];
  const float* ad1 = (const float*)d_in[4];
  const float* b1  = (const float*)d_in[5];
  const float* g1  = (const float*)d_in[6];
  const float* be1 = (const float*)d_in[7];
  const float* W2  = (const float*)d_in[8];
  const float* as2 = (const float*)d_in[9];
  const float* ad2 = (const float*)d_in[10];
  const float* b2  = (const float*)d_in[11];
  const float* g2  = (const float*)d_in[12];
  const float* be2 = (const float*)d_in[13];
  const float* W3  = (const float*)d_in[14];
  const float* as3 = (const float*)d_in[15];
  const float* ad3 = (const float*)d_in[16];
  const float* b3  = (const float*)d_in[17];
  const float* g3  = (const float*)d_in[18];
  const float* be3 = (const float*)d_in[19];
  const float* Wc1 = (const float*)d_in[20];
  const float* bc1 = (const float*)d_in[21];
  const float* Wc2 = (const float*)d_in[22];
  const float* bc2 = (const float*)d_in[23];
  float* outp = (float*)d_out;

  const int Nn = in_sizes[0] / 128;
  const int Ee = in_sizes[1] / 2;
  const int TotE = Ee + Nn;
  const int* esrc = ei;
  const int* edst = ei + Ee;

  char* w = (char*)d_ws;
  auto carve = [&](size_t bytes) {
    char* p = w;
    w += (bytes + 255) & ~(size_t)255;
    return p;
  };
  unsigned short* hb  = (unsigned short*)carve((size_t)Nn * 256 * 2);
  unsigned short* xb  = (unsigned short*)carve((size_t)Nn * 256 * 2);
  unsigned short* agg = (unsigned short*)carve((size_t)Nn * 256 * 2);
  float* als   = (float*)carve((size_t)Nn * 4 * 4);
  float* ald   = (float*)carve((size_t)Nn * 4 * 4);
  float* pbuf  = (float*)carve((size_t)BN_NB * 512 * 4);
  float* ss    = (float*)carve(512 * 4);
  unsigned short* Wt1 = (unsigned short*)carve(256 * 128 * 2);
  unsigned short* Wt2 = (unsigned short*)carve(256 * 256 * 2);
  unsigned short* Wt3 = (unsigned short*)carve(32 * 256 * 2);
  int* deg     = (int*)carve((size_t)Nn * 4);
  int* off     = (int*)carve((size_t)(Nn + 1) * 4);
  int* cursor  = (int*)carve((size_t)Nn * 4);
  int* col     = (int*)carve((size_t)TotE * 4);
  int* exc     = (int*)carve((size_t)Nn * 4);
  int* bsum    = (int*)carve(256 * 4);
  int* boff    = (int*)carve(256 * 4);

  // --- operand prep ---
  cast_f32_bf16<<<2048, 256, 0, stream>>>(x, xb, (size_t)Nn * 128 / 4);
  transpose_cast<<<(128 * 256 + 255) / 256, 256, 0, stream>>>(W1, Wt1, 128, 256);
  transpose_cast<<<(256 * 256 + 255) / 256, 256, 0, stream>>>(W2, Wt2, 256, 256);
  transpose_cast<<<(256 * 32 + 255) / 256, 256, 0, stream>>>(W3, Wt3, 256, 32);

  // --- CSR build (shared by all 3 layers); hierarchical scan ---
  const int NB = (Nn + 255) / 256;
  hipMemsetAsync(deg, 0, (size_t)Nn * 4, stream);
  count_deg<<<(TotE + 255) / 256, 256, 0, stream>>>(edst, Ee, Nn, deg);
  scan_blk<<<NB, 256, 0, stream>>>(deg, exc, bsum, Nn);
  scan_top<<<1, 256, 0, stream>>>(bsum, boff, NB, off, Nn);
  scan_add<<<NB, 256, 0, stream>>>(exc, boff, off, cursor, Nn);
  fill_csr<<<(TotE + 255) / 256, 256, 0, stream>>>(esrc, edst, Ee, Nn, cursor, col);

  int waveBlocks = (Nn + 3) / 4;
  int gy = (Nn + 127) / 128;
  float invN = 1.0f / (float)Nn;

  // --- Layer 1: 128 -> 4x64 concat ---
  gemm_mfma_bf16<128, 128, 64, 64><<<dim3(2, gy), 256, 0, stream>>>(xb, Wt1, hb, Nn, 256, 128);
  attn_logits<4, 64><<<waveBlocks, 256, 0, stream>>>(hb, as1, ad1, als, ald, Nn);
  gat_aggregate<4, 64, 4><<<waveBlocks, 256, 0, stream>>>(hb, als, ald, off, col, b1, agg, Nn);
  bn_stats_part<256><<<BN_NB, 256, 0, stream>>>(agg, Nn, pbuf);
  bn_reduce_finalize<256><<<256, 256, 0, stream>>>(pbuf, g1, be1, invN, ss);
  bn_apply_elu_b2b<256><<<2048, 256, 0, stream>>>(agg, ss, xb, Nn);

  // --- Layer 2: 256 -> 4x64 concat ---
  gemm_mfma_bf16<128, 128, 64, 64><<<dim3(2, gy), 256, 0, stream>>>(xb, Wt2, hb, Nn, 256, 256);
  attn_logits<4, 64><<<waveBlocks, 256, 0, stream>>>(hb, as2, ad2, als, ald, Nn);
  gat_aggregate<4, 64, 4><<<waveBlocks, 256, 0, stream>>>(hb, als, ald, off, col, b2, agg, Nn);
  bn_stats_part<256><<<BN_NB, 256, 0, stream>>>(agg, Nn, pbuf);
  bn_reduce_finalize<256><<<256, 256, 0, stream>>>(pbuf, g2, be2, invN, ss);
  bn_apply_elu_b2b<256><<<2048, 256, 0, stream>>>(agg, ss, xb, Nn);

  // --- Layer 3: 256 -> 1x32, no concat ---
  gemm_mfma_bf16<128, 32, 32, 32><<<dim3(1, gy), 256, 0, stream>>>(xb, Wt3, hb, Nn, 32, 256);
  attn_logits<1, 32><<<waveBlocks, 256, 0, stream>>>(hb, as3, ad3, als, ald, Nn);
  gat_aggregate<1, 32, 1><<<waveBlocks, 256, 0, stream>>>(hb, als, ald, off, col, b3, agg, Nn);
  bn_stats_part<32><<<BN_NB, 256, 0, stream>>>(agg, Nn, pbuf);
  bn_reduce_finalize<32><<<32, 256, 0, stream>>>(pbuf, g3, be3, invN, ss);
  bn_apply_elu_b2b<32><<<512, 256, 0, stream>>>(agg, ss, agg, Nn);  // in-place

  // --- classifier ---
  classifier_k<<<(Nn + 255) / 256, 256, 0, stream>>>(agg, Wc1, bc1, Wc2, bc2, outp, Nn);
}

// Round 13
// 482.966 us; speedup vs baseline: 1.9977x; 1.0249x over previous
//
#include <hip/hip_runtime.h>
#include <math.h>

typedef __attribute__((ext_vector_type(8))) short short8;
typedef __attribute__((ext_vector_type(4))) float f32x4;

// ---------------- bf16 helpers ----------------

__device__ __forceinline__ float bf2f(unsigned short u) {
  union { unsigned int i; float f; } v;
  v.i = ((unsigned int)u) << 16;
  return v.f;
}
__device__ __forceinline__ unsigned short f2bf(float f) {
  union { float f; unsigned int i; } v;
  v.f = f;
  unsigned int x = v.i;
  unsigned int r = x + 0x7fffu + ((x >> 16) & 1u);  // RNE
  return (unsigned short)(r >> 16);
}
__device__ __forceinline__ float lo16f(unsigned int u) {
  union { unsigned int i; float f; } v;
  v.i = u << 16;
  return v.f;
}
__device__ __forceinline__ float hi16f(unsigned int u) {
  union { unsigned int i; float f; } v;
  v.i = u & 0xffff0000u;
  return v.f;
}

// ---------------- CSR build ----------------

__global__ __launch_bounds__(256) void count_deg(const int* __restrict__ dstA,
                                                 int Ee, int Nn,
                                                 int* __restrict__ deg) {
  int e = blockIdx.x * 256 + threadIdx.x;
  if (e >= Ee + Nn) return;
  int d = (e < Ee) ? dstA[e] : (e - Ee);
  atomicAdd(&deg[d], 1);
}

__global__ __launch_bounds__(256) void scan_blk(const int* __restrict__ deg,
                                                int* __restrict__ exc,
                                                int* __restrict__ bsum, int Nn) {
  __shared__ int sd[256];
  int t = threadIdx.x;
  int i = blockIdx.x * 256 + t;
  int v = (i < Nn) ? deg[i] : 0;
  sd[t] = v;
  __syncthreads();
  #pragma unroll
  for (int s = 1; s < 256; s <<= 1) {
    int u = (t >= s) ? sd[t - s] : 0;
    __syncthreads();
    sd[t] += u;
    __syncthreads();
  }
  if (i < Nn) exc[i] = sd[t] - v;
  if (t == 255) bsum[blockIdx.x] = sd[255];
}

__global__ void scan_top(const int* __restrict__ bsum, int* __restrict__ boff,
                         int NB, int* __restrict__ off, int Nn) {
  __shared__ int sd[256];
  int t = threadIdx.x;
  int v = (t < NB) ? bsum[t] : 0;
  sd[t] = v;
  __syncthreads();
  #pragma unroll
  for (int s = 1; s < 256; s <<= 1) {
    int u = (t >= s) ? sd[t - s] : 0;
    __syncthreads();
    sd[t] += u;
    __syncthreads();
  }
  if (t < NB) boff[t] = sd[t] - v;
  if (t == 255) off[Nn] = sd[255];
}

__global__ __launch_bounds__(256) void scan_add(const int* __restrict__ exc,
                                                const int* __restrict__ boff,
                                                int* __restrict__ off,
                                                int* __restrict__ cursor, int Nn) {
  int i = blockIdx.x * 256 + threadIdx.x;
  if (i >= Nn) return;
  int o = exc[i] + boff[blockIdx.x];
  off[i] = o;
  cursor[i] = o;
}

__global__ __launch_bounds__(256) void fill_csr(const int* __restrict__ srcA,
                                                const int* __restrict__ dstA,
                                                int Ee, int Nn,
                                                int* __restrict__ cursor,
                                                int* __restrict__ col) {
  int e = blockIdx.x * 256 + threadIdx.x;
  if (e >= Ee + Nn) return;
  int s, d;
  if (e < Ee) { s = srcA[e]; d = dstA[e]; }
  else        { s = e - Ee;  d = s; }
  int slot = atomicAdd(&cursor[d], 1);
  col[slot] = s;
}

// ---------------- operand prep ----------------

__global__ __launch_bounds__(256) void cast_f32_bf16(const float* __restrict__ in,
                                                     unsigned short* __restrict__ out,
                                                     size_t n4) {
  for (size_t i = blockIdx.x * (size_t)256 + threadIdx.x; i < n4;
       i += (size_t)gridDim.x * 256) {
    float4 v = *(const float4*)&in[i * 4];
    ushort4 o;
    o.x = f2bf(v.x); o.y = f2bf(v.y); o.z = f2bf(v.z); o.w = f2bf(v.w);
    *(ushort4*)&out[i * 4] = o;
  }
}

// Wt[n][k] = bf16(W[k][n])
__global__ __launch_bounds__(256) void transpose_cast(const float* __restrict__ W,
                                                      unsigned short* __restrict__ Wt,
                                                      int K, int N) {
  int t = blockIdx.x * 256 + threadIdx.x;
  if (t >= K * N) return;
  int n = t / K, k = t % K;
  Wt[t] = f2bf(W[(size_t)k * N + n]);
}

// ---------------- bf16 MFMA GEMM: C[M,N] = A[M,K] @ Bt[N,K]^T ----------------

template <int BM, int BN, int WM, int WN>
__global__ __launch_bounds__(256) void gemm_mfma_bf16(
    const unsigned short* __restrict__ A,
    const unsigned short* __restrict__ Bt,
    unsigned short* __restrict__ C,
    int M, int N, int K) {
  constexpr int BK = 32;
  constexpr int LDA = BK + 8;
  constexpr int MF = WM / 16, NF = WN / 16;
  constexpr int NWN = BN / WN;
  constexpr int ACH = BM * BK / 8;
  constexpr int BCH = BN * BK / 8;
  constexpr int ACHT = (ACH + 255) / 256;
  constexpr int BCHT = (BCH + 255) / 256;

  __shared__ unsigned short Al[2][BM * LDA];
  __shared__ unsigned short Bl[2][BN * LDA];

  const int tid = threadIdx.x;
  const int wid = tid >> 6, lane = tid & 63;
  const int wr = wid / NWN, wc = wid % NWN;
  const int brow = blockIdx.y * BM;
  const int bcol = blockIdx.x * BN;

  f32x4 acc[MF][NF] = {};
  uint4 ra[ACHT], rb[BCHT];

  auto loadG = [&](int k0) {
    #pragma unroll
    for (int c = 0; c < ACHT; ++c) {
      int i = c * 256 + tid;
      if (ACH % 256 == 0 || i < ACH) {
        int row = i >> 2, blk = i & 3;
        int rg = brow + row;
        rg = rg < M ? rg : M - 1;
        ra[c] = *(const uint4*)&A[(size_t)rg * K + k0 + blk * 8];
      }
    }
    #pragma unroll
    for (int c = 0; c < BCHT; ++c) {
      int i = c * 256 + tid;
      if (BCH % 256 == 0 || i < BCH) {
        int row = i >> 2, blk = i & 3;
        rb[c] = *(const uint4*)&Bt[(size_t)(bcol + row) * K + k0 + blk * 8];
      }
    }
  };
  auto storeL = [&](int buf) {
    #pragma unroll
    for (int c = 0; c < ACHT; ++c) {
      int i = c * 256 + tid;
      if (ACH % 256 == 0 || i < ACH) {
        int row = i >> 2, blk = i & 3;
        *(uint4*)&Al[buf][row * LDA + blk * 8] = ra[c];
      }
    }
    #pragma unroll
    for (int c = 0; c < BCHT; ++c) {
      int i = c * 256 + tid;
      if (BCH % 256 == 0 || i < BCH) {
        int row = i >> 2, blk = i & 3;
        *(uint4*)&Bl[buf][row * LDA + blk * 8] = rb[c];
      }
    }
  };

  const int nt = K / BK;
  loadG(0);
  storeL(0);
  __syncthreads();
  int cur = 0;
  const int arow = wr * WM + (lane & 15);
  const int bro = wc * WN + (lane & 15);
  const int kb = (lane >> 4) * 8;
  for (int t = 0; t < nt; ++t) {
    if (t + 1 < nt) loadG((t + 1) * BK);
    short8 af[MF], bfr[NF];
    #pragma unroll
    for (int m = 0; m < MF; ++m)
      af[m] = *(const short8*)&Al[cur][(arow + m * 16) * LDA + kb];
    #pragma unroll
    for (int n = 0; n < NF; ++n)
      bfr[n] = *(const short8*)&Bl[cur][(bro + n * 16) * LDA + kb];
    #pragma unroll
    for (int m = 0; m < MF; ++m)
      #pragma unroll
      for (int n = 0; n < NF; ++n)
        acc[m][n] = __builtin_amdgcn_mfma_f32_16x16x32_bf16(af[m], bfr[n], acc[m][n], 0, 0, 0);
    if (t + 1 < nt) storeL(cur ^ 1);
    __syncthreads();
    cur ^= 1;
  }

  const int crow0 = brow + wr * WM + (lane >> 4) * 4;
  const int ccol0 = bcol + wc * WN + (lane & 15);
  #pragma unroll
  for (int m = 0; m < MF; ++m) {
    #pragma unroll
    for (int r = 0; r < 4; ++r) {
      int grow = crow0 + m * 16 + r;
      if (grow >= M) continue;
      #pragma unroll
      for (int n = 0; n < NF; ++n)
        C[(size_t)grow * N + ccol0 + n * 16] = f2bf(acc[m][n][r]);
    }
  }
}

// ---------------- per-node attention logits (bf16 h) ----------------

template <int HEADS, int CC>
__global__ __launch_bounds__(256) void attn_logits(const unsigned short* __restrict__ h,
                                                   const float* __restrict__ a_s,
                                                   const float* __restrict__ a_d,
                                                   float* __restrict__ als,
                                                   float* __restrict__ ald,
                                                   int Nn) {
  int wid = (int)((blockIdx.x * (size_t)blockDim.x + threadIdx.x) >> 6);
  int lane = threadIdx.x & 63;
  if (wid >= Nn) return;
  const unsigned short* hn = h + (size_t)wid * HEADS * CC;
  #pragma unroll
  for (int hh = 0; hh < HEADS; ++hh) {
    float vs = 0.f, vd = 0.f;
    if (lane < CC) {
      float v = bf2f(hn[hh * CC + lane]);
      vs = v * a_s[hh * CC + lane];
      vd = v * a_d[hh * CC + lane];
    }
    #pragma unroll
    for (int o = 32; o > 0; o >>= 1) {
      vs += __shfl_xor(vs, o, 64);
      vd += __shfl_xor(vd, o, 64);
    }
    if (lane == 0) {
      als[(size_t)wid * HEADS + hh] = vs;
      ald[(size_t)wid * HEADS + hh] = vd;
    }
  }
}

// ---------------- GAT aggregation: one wave per dst, 8-edge unroll ----------------
// r12: 4-edge unroll proved latency theory (103->67us, BW 2.3->3.6 TB/s).
// Push MLP to 8 gathers in flight; arrays fully unrolled -> registers.

template <int HEADS, int CC>
__global__ __launch_bounds__(256) void gat_aggregate(const unsigned short* __restrict__ h,
                                                     const float* __restrict__ als,
                                                     const float* __restrict__ ald,
                                                     const int* __restrict__ off,
                                                     const int* __restrict__ col,
                                                     const float* __restrict__ bias,
                                                     unsigned short* __restrict__ out,
                                                     int Nn) {
  constexpr int HC = HEADS * CC;  // 256; V = 4 channels/lane
  int wid = (int)((blockIdx.x * (size_t)blockDim.x + threadIdx.x) >> 6);
  int lane = threadIdx.x & 63;
  if (wid >= Nn) return;
  int c0 = lane * 4;
  int head = c0 / CC;
  float my_ald = ald[(size_t)wid * HEADS + head];
  float ssum = 0.f;
  float acc[4] = {};
  int beg = off[wid], end = off[wid + 1];

  auto lrelu = [](float l) { return (l > 0.f) ? l : 0.2f * l; };

  int j = beg;
  for (; j + 8 <= end; j += 8) {
    int sI[8];
    ushort4 g[8];
    float p[8];
    #pragma unroll
    for (int k = 0; k < 8; ++k) sI[k] = col[j + k];
    #pragma unroll
    for (int k = 0; k < 8; ++k)
      g[k] = *(const ushort4*)(h + (size_t)sI[k] * HC + c0);
    #pragma unroll
    for (int k = 0; k < 8; ++k)
      p[k] = __expf(lrelu(als[(size_t)sI[k] * HEADS + head] + my_ald));
    #pragma unroll
    for (int k = 0; k < 8; ++k) {
      ssum += p[k];
      acc[0] += p[k] * bf2f(g[k].x);
      acc[1] += p[k] * bf2f(g[k].y);
      acc[2] += p[k] * bf2f(g[k].z);
      acc[3] += p[k] * bf2f(g[k].w);
    }
  }
  for (; j + 4 <= end; j += 4) {
    int sI[4];
    ushort4 g[4];
    float p[4];
    #pragma unroll
    for (int k = 0; k < 4; ++k) sI[k] = col[j + k];
    #pragma unroll
    for (int k = 0; k < 4; ++k)
      g[k] = *(const ushort4*)(h + (size_t)sI[k] * HC + c0);
    #pragma unroll
    for (int k = 0; k < 4; ++k)
      p[k] = __expf(lrelu(als[(size_t)sI[k] * HEADS + head] + my_ald));
    #pragma unroll
    for (int k = 0; k < 4; ++k) {
      ssum += p[k];
      acc[0] += p[k] * bf2f(g[k].x);
      acc[1] += p[k] * bf2f(g[k].y);
      acc[2] += p[k] * bf2f(g[k].z);
      acc[3] += p[k] * bf2f(g[k].w);
    }
  }
  for (; j < end; ++j) {
    int s = col[j];
    float p = __expf(lrelu(als[(size_t)s * HEADS + head] + my_ald));
    ssum += p;
    ushort4 hv = *(const ushort4*)(h + (size_t)s * HC + c0);
    acc[0] += p * bf2f(hv.x);
    acc[1] += p * bf2f(hv.y);
    acc[2] += p * bf2f(hv.z);
    acc[3] += p * bf2f(hv.w);
  }
  float inv = 1.f / (ssum + 1e-16f);
  #pragma unroll
  for (int k2 = 0; k2 < 4; ++k2)
    out[(size_t)wid * HC + c0 + k2] = f2bf(acc[k2] * inv + bias[c0 + k2]);
}

// HEADS=1, CC=32 layer: split-K wave — lanes 0-31 take first half of the edge
// list, lanes 32-63 the second half (same node, channel = lane&31). Full lane
// utilization (old V=1 kernel idled lanes 32-63) + 4-edge unroll per half
// (8 gathers in flight per wave). Combine via shfl_xor(32).

template <int CC>
__global__ __launch_bounds__(256) void gat_aggregate_splitk(
    const unsigned short* __restrict__ h, const float* __restrict__ als,
    const float* __restrict__ ald, const int* __restrict__ off,
    const int* __restrict__ col, const float* __restrict__ bias,
    unsigned short* __restrict__ out, int Nn) {
  int wid = (int)((blockIdx.x * (size_t)blockDim.x + threadIdx.x) >> 6);
  int lane = threadIdx.x & 63;
  if (wid >= Nn) return;
  int c = lane & (CC - 1);
  int half = lane >> 5;
  float my_ald = ald[wid];
  int beg0 = off[wid], end0 = off[wid + 1];
  int mid = beg0 + ((end0 - beg0) >> 1);
  int beg = half ? mid : beg0;
  int end = half ? end0 : mid;

  auto lrelu = [](float l) { return (l > 0.f) ? l : 0.2f * l; };

  float ssum = 0.f, acc = 0.f;
  int j = beg;
  for (; j + 4 <= end; j += 4) {
    int s0 = col[j], s1 = col[j + 1], s2 = col[j + 2], s3 = col[j + 3];
    unsigned short g0 = h[(size_t)s0 * CC + c];
    unsigned short g1 = h[(size_t)s1 * CC + c];
    unsigned short g2 = h[(size_t)s2 * CC + c];
    unsigned short g3 = h[(size_t)s3 * CC + c];
    float p0 = __expf(lrelu(als[s0] + my_ald));
    float p1 = __expf(lrelu(als[s1] + my_ald));
    float p2 = __expf(lrelu(als[s2] + my_ald));
    float p3 = __expf(lrelu(als[s3] + my_ald));
    ssum += (p0 + p1) + (p2 + p3);
    acc += p0 * bf2f(g0) + p1 * bf2f(g1) + p2 * bf2f(g2) + p3 * bf2f(g3);
  }
  for (; j < end; ++j) {
    int s = col[j];
    float p = __expf(lrelu(als[s] + my_ald));
    ssum += p;
    acc += p * bf2f(h[(size_t)s * CC + c]);
  }
  // combine halves (same channel c in both halves)
  ssum += __shfl_xor(ssum, 32, 64);
  acc += __shfl_xor(acc, 32, 64);
  if (half == 0)
    out[(size_t)wid * CC + c] = f2bf(acc / (ssum + 1e-16f) + bias[c]);
}

// ---------------- BatchNorm (biased var) — parallel two-stage, bf16 input ----------------

constexpr int BN_NB = 1024;

template <int CH>
__global__ __launch_bounds__(256) void bn_stats_part(const unsigned short* __restrict__ x,
                                                     int Nn, float* __restrict__ pbuf) {
  constexpr int Q8 = CH / 8;  // uint4 (8 bf16) groups per row: 32 or 4; divides 256
  int t = threadIdx.x;
  size_t tot8 = (size_t)Nn * Q8;
  size_t stride = (size_t)gridDim.x * 256;  // multiple of Q8 -> fixed group per thread
  float s[8] = {}, sq[8] = {};
  for (size_t i = blockIdx.x * (size_t)256 + t; i < tot8; i += stride) {
    uint4 u = *(const uint4*)&x[i * 8];
    float v[8] = {lo16f(u.x), hi16f(u.x), lo16f(u.y), hi16f(u.y),
                  lo16f(u.z), hi16f(u.z), lo16f(u.w), hi16f(u.w)};
    #pragma unroll
    for (int k = 0; k < 8; ++k) { s[k] += v[k]; sq[k] += v[k] * v[k]; }
  }
  __shared__ float sS[256][8];
  __shared__ float sQ[256][8];
  #pragma unroll
  for (int k = 0; k < 8; ++k) { sS[t][k] = s[k]; sQ[t][k] = sq[k]; }
  __syncthreads();
  for (int half = 128; half >= Q8; half >>= 1) {  // half % Q8 == 0 -> same group
    if (t < half) {
      #pragma unroll
      for (int k = 0; k < 8; ++k) {
        sS[t][k] += sS[t + half][k];
        sQ[t][k] += sQ[t + half][k];
      }
    }
    __syncthreads();
  }
  if (t < Q8) {
    #pragma unroll
    for (int k = 0; k < 8; ++k) {
      pbuf[(size_t)blockIdx.x * 2 * CH + t * 8 + k] = sS[t][k];
      pbuf[(size_t)blockIdx.x * 2 * CH + CH + t * 8 + k] = sQ[t][k];
    }
  }
}

template <int CH>
__global__ __launch_bounds__(256) void bn_reduce_finalize(const float* __restrict__ pbuf,
                                                          const float* __restrict__ g,
                                                          const float* __restrict__ be,
                                                          float invN,
                                                          float* __restrict__ ss) {
  int c = blockIdx.x;  // one block per channel
  int t = threadIdx.x;
  float s = 0.f, q = 0.f;
  for (int b = t; b < BN_NB; b += 256) {
    s += pbuf[(size_t)b * 2 * CH + c];
    q += pbuf[(size_t)b * 2 * CH + CH + c];
  }
  #pragma unroll
  for (int o = 32; o > 0; o >>= 1) {
    s += __shfl_xor(s, o, 64);
    q += __shfl_xor(q, o, 64);
  }
  __shared__ float rs[4], rq[4];
  int wv = t >> 6, lane = t & 63;
  if (lane == 0) { rs[wv] = s; rq[wv] = q; }
  __syncthreads();
  if (t == 0) {
    float S = rs[0] + rs[1] + rs[2] + rs[3];
    float Qs = rq[0] + rq[1] + rq[2] + rq[3];
    float mu = S * invN;
    float var = Qs * invN - mu * mu;
    float sc = g[c] * rsqrtf(var + 1e-5f);
    ss[c] = sc;
    ss[CH + c] = be[c] - mu * sc;
  }
}

// BN-apply + ELU, bf16 in -> bf16 out (usable in-place when out == x).
template <int CH>
__global__ __launch_bounds__(256) void bn_apply_elu_b2b(const unsigned short* __restrict__ x,
                                                        const float* __restrict__ ss,
                                                        unsigned short* __restrict__ out,
                                                        int Nn) {
  size_t tot8 = (size_t)Nn * (CH / 8);
  for (size_t i = blockIdx.x * (size_t)256 + threadIdx.x; i < tot8;
       i += (size_t)gridDim.x * 256) {
    uint4 u = *(const uint4*)&x[i * 8];
    int c0 = (int)((i % (CH / 8)) * 8);
    float v[8] = {lo16f(u.x), hi16f(u.x), lo16f(u.y), hi16f(u.y),
                  lo16f(u.z), hi16f(u.z), lo16f(u.w), hi16f(u.w)};
    unsigned int o[4];
    #pragma unroll
    for (int k = 0; k < 4; ++k) {
      float y0 = v[2 * k] * ss[c0 + 2 * k] + ss[CH + c0 + 2 * k];
      float y1 = v[2 * k + 1] * ss[c0 + 2 * k + 1] + ss[CH + c0 + 2 * k + 1];
      y0 = (y0 > 0.f) ? y0 : expm1f(y0);
      y1 = (y1 > 0.f) ? y1 : expm1f(y1);
      o[k] = (unsigned int)f2bf(y0) | ((unsigned int)f2bf(y1) << 16);
    }
    *(uint4*)&out[i * 8] = make_uint4(o[0], o[1], o[2], o[3]);
  }
}

// ---------------- classifier: relu(x@Wc1+bc1)@Wc2+bc2 (bf16 x) ----------------

__global__ __launch_bounds__(256) void classifier_k(const unsigned short* __restrict__ x,
                                                    const float* __restrict__ Wc1,
                                                    const float* __restrict__ bc1,
                                                    const float* __restrict__ Wc2,
                                                    const float* __restrict__ bc2,
                                                    float* __restrict__ outp, int Nn) {
  __shared__ unsigned short sx[256][33];
  __shared__ float sw[32 * 32];
  __shared__ float sb1[32];
  __shared__ float sw2[32];
  int t = threadIdx.x;
  int base = blockIdx.x * 256;
  for (int i = t; i < 1024; i += 256) sw[i] = Wc1[i];
  if (t < 32) { sb1[t] = bc1[t]; sw2[t] = Wc2[t]; }
  int cnt = min(256, Nn - base);
  for (int i = t; i < cnt * 32; i += 256) sx[i / 32][i % 32] = x[(size_t)base * 32 + i];
  __syncthreads();
  if (t < cnt) {
    float xa[32];
    #pragma unroll
    for (int c = 0; c < 32; ++c) xa[c] = bf2f(sx[t][c]);
    float o = bc2[0];
    #pragma unroll
    for (int j = 0; j < 32; ++j) {
      float v = sb1[j];
      #pragma unroll
      for (int c = 0; c < 32; ++c) v += xa[c] * sw[c * 32 + j];
      v = fmaxf(v, 0.f);
      o += v * sw2[j];
    }
    outp[base + t] = o;
  }
}

// ---------------- host orchestration ----------------

extern "C" void kernel_launch(void* const* d_in, const int* in_sizes, int n_in,
                              void* d_out, int out_size, void* d_ws, size_t ws_size,
                              hipStream_t stream) {
  const float* x   = (const float*)d_in[0];
  const int*   ei  = (const int*)d_in[1];
  const float* W1  = (const float*)d_in[2];
  const float* as1 = (const float*)d_in[3];
  const float* ad1 = (const float*)d_in[4];
  const float* b1  = (const float*)d_in[5];
  const float* g1  = (const float*)d_in[6];
  const float* be1 = (const float*)d_in[7];
  const float* W2  = (const float*)d_in[8];
  const float* as2 = (const float*)d_in[9];
  const float* ad2 = (const float*)d_in[10];
  const float* b2  = (const float*)d_in[11];
  const float* g2  = (const float*)d_in[12];
  const float* be2 = (const float*)d_in[13];
  const float* W3  = (const float*)d_in[14];
  const float* as3 = (const float*)d_in[15];
  const float* ad3 = (const float*)d_in[16];
  const float* b3  = (const float*)d_in[17];
  const float* g3  = (const float*)d_in[18];
  const float* be3 = (const float*)d_in[19];
  const float* Wc1 = (const float*)d_in[20];
  const float* bc1 = (const float*)d_in[21];
  const float* Wc2 = (const float*)d_in[22];
  const float* bc2 = (const float*)d_in[23];
  float* outp = (float*)d_out;

  const int Nn = in_sizes[0] / 128;
  const int Ee = in_sizes[1] / 2;
  const int TotE = Ee + Nn;
  const int* esrc = ei;
  const int* edst = ei + Ee;

  char* w = (char*)d_ws;
  auto carve = [&](size_t bytes) {
    char* p = w;
    w += (bytes + 255) & ~(size_t)255;
    return p;
  };
  unsigned short* hb  = (unsigned short*)carve((size_t)Nn * 256 * 2);
  unsigned short* xb  = (unsigned short*)carve((size_t)Nn * 256 * 2);
  unsigned short* agg = (unsigned short*)carve((size_t)Nn * 256 * 2);
  float* als   = (float*)carve((size_t)Nn * 4 * 4);
  float* ald   = (float*)carve((size_t)Nn * 4 * 4);
  float* pbuf  = (float*)carve((size_t)BN_NB * 512 * 4);
  float* ss    = (float*)carve(512 * 4);
  unsigned short* Wt1 = (unsigned short*)carve(256 * 128 * 2);
  unsigned short* Wt2 = (unsigned short*)carve(256 * 256 * 2);
  unsigned short* Wt3 = (unsigned short*)carve(32 * 256 * 2);
  int* deg     = (int*)carve((size_t)Nn * 4);
  int* off     = (int*)carve((size_t)(Nn + 1) * 4);
  int* cursor  = (int*)carve((size_t)Nn * 4);
  int* col     = (int*)carve((size_t)TotE * 4);
  int* exc     = (int*)carve((size_t)Nn * 4);
  int* bsum    = (int*)carve(256 * 4);
  int* boff    = (int*)carve(256 * 4);

  // --- operand prep ---
  cast_f32_bf16<<<2048, 256, 0, stream>>>(x, xb, (size_t)Nn * 128 / 4);
  transpose_cast<<<(128 * 256 + 255) / 256, 256, 0, stream>>>(W1, Wt1, 128, 256);
  transpose_cast<<<(256 * 256 + 255) / 256, 256, 0, stream>>>(W2, Wt2, 256, 256);
  transpose_cast<<<(256 * 32 + 255) / 256, 256, 0, stream>>>(W3, Wt3, 256, 32);

  // --- CSR build (shared by all 3 layers); hierarchical scan ---
  const int NB = (Nn + 255) / 256;
  hipMemsetAsync(deg, 0, (size_t)Nn * 4, stream);
  count_deg<<<(TotE + 255) / 256, 256, 0, stream>>>(edst, Ee, Nn, deg);
  scan_blk<<<NB, 256, 0, stream>>>(deg, exc, bsum, Nn);
  scan_top<<<1, 256, 0, stream>>>(bsum, boff, NB, off, Nn);
  scan_add<<<NB, 256, 0, stream>>>(exc, boff, off, cursor, Nn);
  fill_csr<<<(TotE + 255) / 256, 256, 0, stream>>>(esrc, edst, Ee, Nn, cursor, col);

  int waveBlocks = (Nn + 3) / 4;
  int gy = (Nn + 127) / 128;
  float invN = 1.0f / (float)Nn;

  // --- Layer 1: 128 -> 4x64 concat ---
  gemm_mfma_bf16<128, 128, 64, 64><<<dim3(2, gy), 256, 0, stream>>>(xb, Wt1, hb, Nn, 256, 128);
  attn_logits<4, 64><<<waveBlocks, 256, 0, stream>>>(hb, as1, ad1, als, ald, Nn);
  gat_aggregate<4, 64><<<waveBlocks, 256, 0, stream>>>(hb, als, ald, off, col, b1, agg, Nn);
  bn_stats_part<256><<<BN_NB, 256, 0, stream>>>(agg, Nn, pbuf);
  bn_reduce_finalize<256><<<256, 256, 0, stream>>>(pbuf, g1, be1, invN, ss);
  bn_apply_elu_b2b<256><<<2048, 256, 0, stream>>>(agg, ss, xb, Nn);

  // --- Layer 2: 256 -> 4x64 concat ---
  gemm_mfma_bf16<128, 128, 64, 64><<<dim3(2, gy), 256, 0, stream>>>(xb, Wt2, hb, Nn, 256, 256);
  attn_logits<4, 64><<<waveBlocks, 256, 0, stream>>>(hb, as2, ad2, als, ald, Nn);
  gat_aggregate<4, 64><<<waveBlocks, 256, 0, stream>>>(hb, als, ald, off, col, b2, agg, Nn);
  bn_stats_part<256><<<BN_NB, 256, 0, stream>>>(agg, Nn, pbuf);
  bn_reduce_finalize<256><<<256, 256, 0, stream>>>(pbuf, g2, be2, invN, ss);
  bn_apply_elu_b2b<256><<<2048, 256, 0, stream>>>(agg, ss, xb, Nn);

  // --- Layer 3: 256 -> 1x32, no concat ---
  gemm_mfma_bf16<128, 32, 32, 32><<<dim3(1, gy), 256, 0, stream>>>(xb, Wt3, hb, Nn, 32, 256);
  attn_logits<1, 32><<<waveBlocks, 256, 0, stream>>>(hb, as3, ad3, als, ald, Nn);
  gat_aggregate_splitk<32><<<waveBlocks, 256, 0, stream>>>(hb, als, ald, off, col, b3, agg, Nn);
  bn_stats_part<32><<<BN_NB, 256, 0, stream>>>(agg, Nn, pbuf);
  bn_reduce_finalize<32><<<32, 256, 0, stream>>>(pbuf, g3, be3, invN, ss);
  bn_apply_elu_b2b<32><<<512, 256, 0, stream>>>(agg, ss, agg, Nn);  // in-place

  // --- classifier ---
  classifier_k<<<(Nn + 255) / 256, 256, 0, stream>>>(agg, Wc1, bc1, Wc2, bc2, outp, Nn);
}

// Round 15
// 435.570 us; speedup vs baseline: 2.2151x; 1.1088x over previous
//
#include <hip/hip_runtime.h>
#include <math.h>

typedef __attribute__((ext_vector_type(8))) short short8;
typedef __attribute__((ext_vector_type(4))) float f32x4;

// ---------------- bf16 helpers ----------------

__device__ __forceinline__ float bf2f(unsigned short u) {
  union { unsigned int i; float f; } v;
  v.i = ((unsigned int)u) << 16;
  return v.f;
}
__device__ __forceinline__ unsigned short f2bf(float f) {
  union { float f; unsigned int i; } v;
  v.f = f;
  unsigned int x = v.i;
  unsigned int r = x + 0x7fffu + ((x >> 16) & 1u);  // RNE
  return (unsigned short)(r >> 16);
}
__device__ __forceinline__ float lo16f(unsigned int u) {
  union { unsigned int i; float f; } v;
  v.i = u << 16;
  return v.f;
}
__device__ __forceinline__ float hi16f(unsigned int u) {
  union { unsigned int i; float f; } v;
  v.i = u & 0xffff0000u;
  return v.f;
}

// ---------------- CSR build ----------------

__global__ __launch_bounds__(256) void count_deg(const int* __restrict__ dstA,
                                                 int Ee, int Nn,
                                                 int* __restrict__ deg) {
  int e = blockIdx.x * 256 + threadIdx.x;
  if (e >= Ee + Nn) return;
  int d = (e < Ee) ? dstA[e] : (e - Ee);
  atomicAdd(&deg[d], 1);
}

__global__ __launch_bounds__(256) void scan_blk(const int* __restrict__ deg,
                                                int* __restrict__ exc,
                                                int* __restrict__ bsum, int Nn) {
  __shared__ int sd[256];
  int t = threadIdx.x;
  int i = blockIdx.x * 256 + t;
  int v = (i < Nn) ? deg[i] : 0;
  sd[t] = v;
  __syncthreads();
  #pragma unroll
  for (int s = 1; s < 256; s <<= 1) {
    int u = (t >= s) ? sd[t - s] : 0;
    __syncthreads();
    sd[t] += u;
    __syncthreads();
  }
  if (i < Nn) exc[i] = sd[t] - v;
  if (t == 255) bsum[blockIdx.x] = sd[255];
}

__global__ void scan_top(const int* __restrict__ bsum, int* __restrict__ boff,
                         int NB, int* __restrict__ off, int Nn) {
  __shared__ int sd[256];
  int t = threadIdx.x;
  int v = (t < NB) ? bsum[t] : 0;
  sd[t] = v;
  __syncthreads();
  #pragma unroll
  for (int s = 1; s < 256; s <<= 1) {
    int u = (t >= s) ? sd[t - s] : 0;
    __syncthreads();
    sd[t] += u;
    __syncthreads();
  }
  if (t < NB) boff[t] = sd[t] - v;
  if (t == 255) off[Nn] = sd[255];
}

__global__ __launch_bounds__(256) void scan_add(const int* __restrict__ exc,
                                                const int* __restrict__ boff,
                                                int* __restrict__ off,
                                                int* __restrict__ cursor, int Nn) {
  int i = blockIdx.x * 256 + threadIdx.x;
  if (i >= Nn) return;
  int o = exc[i] + boff[blockIdx.x];
  off[i] = o;
  cursor[i] = o;
}

__global__ __launch_bounds__(256) void fill_csr(const int* __restrict__ srcA,
                                                const int* __restrict__ dstA,
                                                int Ee, int Nn,
                                                int* __restrict__ cursor,
                                                int* __restrict__ col) {
  int e = blockIdx.x * 256 + threadIdx.x;
  if (e >= Ee + Nn) return;
  int s, d;
  if (e < Ee) { s = srcA[e]; d = dstA[e]; }
  else        { s = e - Ee;  d = s; }
  int slot = atomicAdd(&cursor[d], 1);
  col[slot] = s;
}

// ---------------- operand prep ----------------

__global__ __launch_bounds__(256) void cast_f32_bf16(const float* __restrict__ in,
                                                     unsigned short* __restrict__ out,
                                                     size_t n4) {
  for (size_t i = blockIdx.x * (size_t)256 + threadIdx.x; i < n4;
       i += (size_t)gridDim.x * 256) {
    float4 v = *(const float4*)&in[i * 4];
    ushort4 o;
    o.x = f2bf(v.x); o.y = f2bf(v.y); o.z = f2bf(v.z); o.w = f2bf(v.w);
    *(ushort4*)&out[i * 4] = o;
  }
}

// Wt[n][k] = bf16(W[k][n])
__global__ __launch_bounds__(256) void transpose_cast(const float* __restrict__ W,
                                                      unsigned short* __restrict__ Wt,
                                                      int K, int N) {
  int t = blockIdx.x * 256 + threadIdx.x;
  if (t >= K * N) return;
  int n = t / K, k = t % K;
  Wt[t] = f2bf(W[(size_t)k * N + n]);
}

// ---------------- bf16 MFMA GEMM + fused attention logits ----------------
// C[M,N] = A[M,K] @ Bt[N,K]^T, bf16 out. Epilogue additionally computes
// als[row][head] = sum_c C[row, head*CC+c]*a_s[head][c] (and ald) from the f32
// accumulators: wave col-range WN == CC, so a 16-lane shfl_xor reduce over the
// col groups covers exactly one head. (ONLY change vs r13-passing kernel.)

template <int BM, int BN, int WM, int WN, int HEADS, int CC>
__global__ __launch_bounds__(256) void gemm_mfma_logits(
    const unsigned short* __restrict__ A,
    const unsigned short* __restrict__ Bt,
    unsigned short* __restrict__ C,
    const float* __restrict__ a_s, const float* __restrict__ a_d,
    float* __restrict__ als, float* __restrict__ ald,
    int M, int N, int K) {
  static_assert(WN == CC, "wave col-range must equal head width");
  constexpr int BK = 32;
  constexpr int LDA = BK + 8;
  constexpr int MF = WM / 16, NF = WN / 16;
  constexpr int NWN = BN / WN;
  constexpr int ACH = BM * BK / 8;
  constexpr int BCH = BN * BK / 8;
  constexpr int ACHT = (ACH + 255) / 256;
  constexpr int BCHT = (BCH + 255) / 256;

  __shared__ unsigned short Al[2][BM * LDA];
  __shared__ unsigned short Bl[2][BN * LDA];

  const int tid = threadIdx.x;
  const int wid = tid >> 6, lane = tid & 63;
  const int wr = wid / NWN, wc = wid % NWN;
  const int brow = blockIdx.y * BM;
  const int bcol = blockIdx.x * BN;

  f32x4 acc[MF][NF] = {};
  uint4 ra[ACHT], rb[BCHT];

  auto loadG = [&](int k0) {
    #pragma unroll
    for (int c = 0; c < ACHT; ++c) {
      int i = c * 256 + tid;
      if (ACH % 256 == 0 || i < ACH) {
        int row = i >> 2, blk = i & 3;
        int rg = brow + row;
        rg = rg < M ? rg : M - 1;
        ra[c] = *(const uint4*)&A[(size_t)rg * K + k0 + blk * 8];
      }
    }
    #pragma unroll
    for (int c = 0; c < BCHT; ++c) {
      int i = c * 256 + tid;
      if (BCH % 256 == 0 || i < BCH) {
        int row = i >> 2, blk = i & 3;
        rb[c] = *(const uint4*)&Bt[(size_t)(bcol + row) * K + k0 + blk * 8];
      }
    }
  };
  auto storeL = [&](int buf) {
    #pragma unroll
    for (int c = 0; c < ACHT; ++c) {
      int i = c * 256 + tid;
      if (ACH % 256 == 0 || i < ACH) {
        int row = i >> 2, blk = i & 3;
        *(uint4*)&Al[buf][row * LDA + blk * 8] = ra[c];
      }
    }
    #pragma unroll
    for (int c = 0; c < BCHT; ++c) {
      int i = c * 256 + tid;
      if (BCH % 256 == 0 || i < BCH) {
        int row = i >> 2, blk = i & 3;
        *(uint4*)&Bl[buf][row * LDA + blk * 8] = rb[c];
      }
    }
  };

  const int nt = K / BK;
  loadG(0);
  storeL(0);
  __syncthreads();
  int cur = 0;
  const int arow = wr * WM + (lane & 15);
  const int bro = wc * WN + (lane & 15);
  const int kb = (lane >> 4) * 8;
  for (int t = 0; t < nt; ++t) {
    if (t + 1 < nt) loadG((t + 1) * BK);
    short8 af[MF], bfr[NF];
    #pragma unroll
    for (int m = 0; m < MF; ++m)
      af[m] = *(const short8*)&Al[cur][(arow + m * 16) * LDA + kb];
    #pragma unroll
    for (int n = 0; n < NF; ++n)
      bfr[n] = *(const short8*)&Bl[cur][(bro + n * 16) * LDA + kb];
    #pragma unroll
    for (int m = 0; m < MF; ++m)
      #pragma unroll
      for (int n = 0; n < NF; ++n)
        acc[m][n] = __builtin_amdgcn_mfma_f32_16x16x32_bf16(af[m], bfr[n], acc[m][n], 0, 0, 0);
    if (t + 1 < nt) storeL(cur ^ 1);
    __syncthreads();
    cur ^= 1;
  }

  const int crow0 = brow + wr * WM + (lane >> 4) * 4;
  const int ccol0 = bcol + wc * WN + (lane & 15);
  #pragma unroll
  for (int m = 0; m < MF; ++m) {
    #pragma unroll
    for (int r = 0; r < 4; ++r) {
      int grow = crow0 + m * 16 + r;
      if (grow >= M) continue;
      #pragma unroll
      for (int n = 0; n < NF; ++n)
        C[(size_t)grow * N + ccol0 + n * 16] = f2bf(acc[m][n][r]);
    }
  }

  // ---- fused logits epilogue ----
  // For fixed (m,r), the 16 lanes of each (lane>>4)-group hold the SAME row
  // (crow0+m*16+r) and 16 distinct cols per fragment n; asv/adv pick the
  // matching a-vector entries; xor-reduce over masks 1,2,4,8 sums the head.
  const int hidx = (bcol + wc * WN) / CC;
  float asv[NF], adv[NF];
  #pragma unroll
  for (int n = 0; n < NF; ++n) {
    int ch = (lane & 15) + n * 16;  // channel within head
    asv[n] = a_s[hidx * CC + ch];
    adv[n] = a_d[hidx * CC + ch];
  }
  #pragma unroll
  for (int m = 0; m < MF; ++m) {
    #pragma unroll
    for (int r = 0; r < 4; ++r) {
      float ps = 0.f, pd = 0.f;
      #pragma unroll
      for (int n = 0; n < NF; ++n) {
        float v = acc[m][n][r];
        ps += v * asv[n];
        pd += v * adv[n];
      }
      #pragma unroll
      for (int o = 1; o < 16; o <<= 1) {
        ps += __shfl_xor(ps, o, 64);
        pd += __shfl_xor(pd, o, 64);
      }
      int grow = crow0 + m * 16 + r;
      if ((lane & 15) == 0 && grow < M) {
        als[(size_t)grow * HEADS + hidx] = ps;
        ald[(size_t)grow * HEADS + hidx] = pd;
      }
    }
  }
}

// ---------------- GAT aggregation: one wave per dst, 8-edge unroll (r13) ----------------

template <int HEADS, int CC>
__global__ __launch_bounds__(256) void gat_aggregate(const unsigned short* __restrict__ h,
                                                     const float* __restrict__ als,
                                                     const float* __restrict__ ald,
                                                     const int* __restrict__ off,
                                                     const int* __restrict__ col,
                                                     const float* __restrict__ bias,
                                                     unsigned short* __restrict__ out,
                                                     int Nn) {
  constexpr int HC = HEADS * CC;  // 256; 4 ch/lane
  int wid = (int)((blockIdx.x * (size_t)blockDim.x + threadIdx.x) >> 6);
  int lane = threadIdx.x & 63;
  if (wid >= Nn) return;
  int c0 = lane * 4;
  int head = c0 / CC;
  float my_ald = ald[(size_t)wid * HEADS + head];
  float ssum = 0.f;
  float acc[4] = {};
  int beg = off[wid], end = off[wid + 1];

  auto lrelu = [](float l) { return (l > 0.f) ? l : 0.2f * l; };

  int j = beg;
  for (; j + 8 <= end; j += 8) {
    int sI[8];
    ushort4 g[8];
    float p[8];
    #pragma unroll
    for (int k = 0; k < 8; ++k) sI[k] = col[j + k];
    #pragma unroll
    for (int k = 0; k < 8; ++k)
      g[k] = *(const ushort4*)(h + (size_t)sI[k] * HC + c0);
    #pragma unroll
    for (int k = 0; k < 8; ++k)
      p[k] = __expf(lrelu(als[(size_t)sI[k] * HEADS + head] + my_ald));
    #pragma unroll
    for (int k = 0; k < 8; ++k) {
      ssum += p[k];
      acc[0] += p[k] * bf2f(g[k].x);
      acc[1] += p[k] * bf2f(g[k].y);
      acc[2] += p[k] * bf2f(g[k].z);
      acc[3] += p[k] * bf2f(g[k].w);
    }
  }
  for (; j + 4 <= end; j += 4) {
    int sI[4];
    ushort4 g[4];
    float p[4];
    #pragma unroll
    for (int k = 0; k < 4; ++k) sI[k] = col[j + k];
    #pragma unroll
    for (int k = 0; k < 4; ++k)
      g[k] = *(const ushort4*)(h + (size_t)sI[k] * HC + c0);
    #pragma unroll
    for (int k = 0; k < 4; ++k)
      p[k] = __expf(lrelu(als[(size_t)sI[k] * HEADS + head] + my_ald));
    #pragma unroll
    for (int k = 0; k < 4; ++k) {
      ssum += p[k];
      acc[0] += p[k] * bf2f(g[k].x);
      acc[1] += p[k] * bf2f(g[k].y);
      acc[2] += p[k] * bf2f(g[k].z);
      acc[3] += p[k] * bf2f(g[k].w);
    }
  }
  for (; j < end; ++j) {
    int s = col[j];
    float p = __expf(lrelu(als[(size_t)s * HEADS + head] + my_ald));
    ssum += p;
    ushort4 hv = *(const ushort4*)(h + (size_t)s * HC + c0);
    acc[0] += p * bf2f(hv.x);
    acc[1] += p * bf2f(hv.y);
    acc[2] += p * bf2f(hv.z);
    acc[3] += p * bf2f(hv.w);
  }
  float inv = 1.f / (ssum + 1e-16f);
  #pragma unroll
  for (int k2 = 0; k2 < 4; ++k2)
    out[(size_t)wid * HC + c0 + k2] = f2bf(acc[k2] * inv + bias[c0 + k2]);
}

// HEADS=1, CC=32: split-K within a wave (r13).

template <int CC>
__global__ __launch_bounds__(256) void gat_aggregate_splitk(
    const unsigned short* __restrict__ h, const float* __restrict__ als,
    const float* __restrict__ ald, const int* __restrict__ off,
    const int* __restrict__ col, const float* __restrict__ bias,
    unsigned short* __restrict__ out, int Nn) {
  int wid = (int)((blockIdx.x * (size_t)blockDim.x + threadIdx.x) >> 6);
  int lane = threadIdx.x & 63;
  if (wid >= Nn) return;
  int c = lane & (CC - 1);
  int half = lane >> 5;
  float my_ald = ald[wid];
  int beg0 = off[wid], end0 = off[wid + 1];
  int mid = beg0 + ((end0 - beg0) >> 1);
  int beg = half ? mid : beg0;
  int end = half ? end0 : mid;

  auto lrelu = [](float l) { return (l > 0.f) ? l : 0.2f * l; };

  float ssum = 0.f, acc = 0.f;
  int j = beg;
  for (; j + 4 <= end; j += 4) {
    int s0 = col[j], s1 = col[j + 1], s2 = col[j + 2], s3 = col[j + 3];
    unsigned short g0 = h[(size_t)s0 * CC + c];
    unsigned short g1 = h[(size_t)s1 * CC + c];
    unsigned short g2 = h[(size_t)s2 * CC + c];
    unsigned short g3 = h[(size_t)s3 * CC + c];
    float p0 = __expf(lrelu(als[s0] + my_ald));
    float p1 = __expf(lrelu(als[s1] + my_ald));
    float p2 = __expf(lrelu(als[s2] + my_ald));
    float p3 = __expf(lrelu(als[s3] + my_ald));
    ssum += (p0 + p1) + (p2 + p3);
    acc += p0 * bf2f(g0) + p1 * bf2f(g1) + p2 * bf2f(g2) + p3 * bf2f(g3);
  }
  for (; j < end; ++j) {
    int s = col[j];
    float p = __expf(lrelu(als[s] + my_ald));
    ssum += p;
    acc += p * bf2f(h[(size_t)s * CC + c]);
  }
  ssum += __shfl_xor(ssum, 32, 64);
  acc += __shfl_xor(acc, 32, 64);
  if (half == 0)
    out[(size_t)wid * CC + c] = f2bf(acc / (ssum + 1e-16f) + bias[c]);
}

// ---------------- BatchNorm (biased var) — parallel two-stage, bf16 input ----------------

constexpr int BN_NB = 1024;

template <int CH>
__global__ __launch_bounds__(256) void bn_stats_part(const unsigned short* __restrict__ x,
                                                     int Nn, float* __restrict__ pbuf) {
  constexpr int Q8 = CH / 8;
  int t = threadIdx.x;
  size_t tot8 = (size_t)Nn * Q8;
  size_t stride = (size_t)gridDim.x * 256;
  float s[8] = {}, sq[8] = {};
  for (size_t i = blockIdx.x * (size_t)256 + t; i < tot8; i += stride) {
    uint4 u = *(const uint4*)&x[i * 8];
    float v[8] = {lo16f(u.x), hi16f(u.x), lo16f(u.y), hi16f(u.y),
                  lo16f(u.z), hi16f(u.z), lo16f(u.w), hi16f(u.w)};
    #pragma unroll
    for (int k = 0; k < 8; ++k) { s[k] += v[k]; sq[k] += v[k] * v[k]; }
  }
  __shared__ float sS[256][8];
  __shared__ float sQ[256][8];
  #pragma unroll
  for (int k = 0; k < 8; ++k) { sS[t][k] = s[k]; sQ[t][k] = sq[k]; }
  __syncthreads();
  for (int half = 128; half >= Q8; half >>= 1) {
    if (t < half) {
      #pragma unroll
      for (int k = 0; k < 8; ++k) {
        sS[t][k] += sS[t + half][k];
        sQ[t][k] += sQ[t + half][k];
      }
    }
    __syncthreads();
  }
  if (t < Q8) {
    #pragma unroll
    for (int k = 0; k < 8; ++k) {
      pbuf[(size_t)blockIdx.x * 2 * CH + t * 8 + k] = sS[t][k];
      pbuf[(size_t)blockIdx.x * 2 * CH + CH + t * 8 + k] = sQ[t][k];
    }
  }
}

template <int CH>
__global__ __launch_bounds__(256) void bn_reduce_finalize(const float* __restrict__ pbuf,
                                                          const float* __restrict__ g,
                                                          const float* __restrict__ be,
                                                          float invN,
                                                          float* __restrict__ ss) {
  int c = blockIdx.x;
  int t = threadIdx.x;
  float s = 0.f, q = 0.f;
  for (int b = t; b < BN_NB; b += 256) {
    s += pbuf[(size_t)b * 2 * CH + c];
    q += pbuf[(size_t)b * 2 * CH + CH + c];
  }
  #pragma unroll
  for (int o = 32; o > 0; o >>= 1) {
    s += __shfl_xor(s, o, 64);
    q += __shfl_xor(q, o, 64);
  }
  __shared__ float rs[4], rq[4];
  int wv = t >> 6, lane = t & 63;
  if (lane == 0) { rs[wv] = s; rq[wv] = q; }
  __syncthreads();
  if (t == 0) {
    float S = rs[0] + rs[1] + rs[2] + rs[3];
    float Qs = rq[0] + rq[1] + rq[2] + rq[3];
    float mu = S * invN;
    float var = Qs * invN - mu * mu;
    float sc = g[c] * rsqrtf(var + 1e-5f);
    ss[c] = sc;
    ss[CH + c] = be[c] - mu * sc;
  }
}

template <int CH>
__global__ __launch_bounds__(256) void bn_apply_elu_b2b(const unsigned short* __restrict__ x,
                                                        const float* __restrict__ ss,
                                                        unsigned short* __restrict__ out,
                                                        int Nn) {
  size_t tot8 = (size_t)Nn * (CH / 8);
  for (size_t i = blockIdx.x * (size_t)256 + threadIdx.x; i < tot8;
       i += (size_t)gridDim.x * 256) {
    uint4 u = *(const uint4*)&x[i * 8];
    int c0 = (int)((i % (CH / 8)) * 8);
    float v[8] = {lo16f(u.x), hi16f(u.x), lo16f(u.y), hi16f(u.y),
                  lo16f(u.z), hi16f(u.z), lo16f(u.w), hi16f(u.w)};
    unsigned int o[4];
    #pragma unroll
    for (int k = 0; k < 4; ++k) {
      float y0 = v[2 * k] * ss[c0 + 2 * k] + ss[CH + c0 + 2 * k];
      float y1 = v[2 * k + 1] * ss[c0 + 2 * k + 1] + ss[CH + c0 + 2 * k + 1];
      y0 = (y0 > 0.f) ? y0 : expm1f(y0);
      y1 = (y1 > 0.f) ? y1 : expm1f(y1);
      o[k] = (unsigned int)f2bf(y0) | ((unsigned int)f2bf(y1) << 16);
    }
    *(uint4*)&out[i * 8] = make_uint4(o[0], o[1], o[2], o[3]);
  }
}

// ---------------- classifier: relu(x@Wc1+bc1)@Wc2+bc2 (bf16 x) ----------------

__global__ __launch_bounds__(256) void classifier_k(const unsigned short* __restrict__ x,
                                                    const float* __restrict__ Wc1,
                                                    const float* __restrict__ bc1,
                                                    const float* __restrict__ Wc2,
                                                    const float* __restrict__ bc2,
                                                    float* __restrict__ outp, int Nn) {
  __shared__ unsigned short sx[256][33];
  __shared__ float sw[32 * 32];
  __shared__ float sb1[32];
  __shared__ float sw2[32];
  int t = threadIdx.x;
  int base = blockIdx.x * 256;
  for (int i = t; i < 1024; i += 256) sw[i] = Wc1[i];
  if (t < 32) { sb1[t] = bc1[t]; sw2[t] = Wc2[t]; }
  int cnt = min(256, Nn - base);
  for (int i = t; i < cnt * 32; i += 256) sx[i / 32][i % 32] = x[(size_t)base * 32 + i];
  __syncthreads();
  if (t < cnt) {
    float xa[32];
    #pragma unroll
    for (int c = 0; c < 32; ++c) xa[c] = bf2f(sx[t][c]);
    float o = bc2[0];
    #pragma unroll
    for (int j = 0; j < 32; ++j) {
      float v = sb1[j];
      #pragma unroll
      for (int c = 0; c < 32; ++c) v += xa[c] * sw[c * 32 + j];
      v = fmaxf(v, 0.f);
      o += v * sw2[j];
    }
    outp[base + t] = o;
  }
}

// ---------------- host orchestration ----------------

extern "C" void kernel_launch(void* const* d_in, const int* in_sizes, int n_in,
                              void* d_out, int out_size, void* d_ws, size_t ws_size,
                              hipStream_t stream) {
  const float* x   = (const float*)d_in[0];
  const int*   ei  = (const int*)d_in[1];
  const float* W1  = (const float*)d_in[2];
  const float* as1 = (const float*)d_in[3];
  const float* ad1 = (const float*)d_in[4];
  const float* b1  = (const float*)d_in[5];
  const float* g1  = (const float*)d_in[6];
  const float* be1 = (const float*)d_in[7];
  const float* W2  = (const float*)d_in[8];
  const float* as2 = (const float*)d_in[9];
  const float* ad2 = (const float*)d_in[10];
  const float* b2  = (const float*)d_in[11];
  const float* g2  = (const float*)d_in[12];
  const float* be2 = (const float*)d_in[13];
  const float* W3  = (const float*)d_in[14];
  const float* as3 = (const float*)d_in[15];
  const float* ad3 = (const float*)d_in[16];
  const float* b3  = (const float*)d_in[17];
  const float* g3  = (const float*)d_in[18];
  const float* be3 = (const float*)d_in[19];
  const float* Wc1 = (const float*)d_in[20];
  const float* bc1 = (const float*)d_in[21];
  const float* Wc2 = (const float*)d_in[22];
  const float* bc2 = (const float*)d_in[23];
  float* outp = (float*)d_out;

  const int Nn = in_sizes[0] / 128;
  const int Ee = in_sizes[1] / 2;
  const int TotE = Ee + Nn;
  const int* esrc = ei;
  const int* edst = ei + Ee;

  char* w = (char*)d_ws;
  auto carve = [&](size_t bytes) {
    char* p = w;
    w += (bytes + 255) & ~(size_t)255;
    return p;
  };
  unsigned short* hb  = (unsigned short*)carve((size_t)Nn * 256 * 2);
  unsigned short* xb  = (unsigned short*)carve((size_t)Nn * 256 * 2);
  unsigned short* agg = (unsigned short*)carve((size_t)Nn * 256 * 2);
  float* als   = (float*)carve((size_t)Nn * 4 * 4);
  float* ald   = (float*)carve((size_t)Nn * 4 * 4);
  float* pbuf  = (float*)carve((size_t)BN_NB * 512 * 4);
  float* ss    = (float*)carve(512 * 4);
  unsigned short* Wt1 = (unsigned short*)carve(256 * 128 * 2);
  unsigned short* Wt2 = (unsigned short*)carve(256 * 256 * 2);
  unsigned short* Wt3 = (unsigned short*)carve(32 * 256 * 2);
  int* deg     = (int*)carve((size_t)Nn * 4);
  int* off     = (int*)carve((size_t)(Nn + 1) * 4);
  int* cursor  = (int*)carve((size_t)Nn * 4);
  int* col     = (int*)carve((size_t)TotE * 4);
  int* exc     = (int*)carve((size_t)Nn * 4);
  int* bsum    = (int*)carve(256 * 4);
  int* boff    = (int*)carve(256 * 4);

  // --- operand prep ---
  cast_f32_bf16<<<2048, 256, 0, stream>>>(x, xb, (size_t)Nn * 128 / 4);
  transpose_cast<<<(128 * 256 + 255) / 256, 256, 0, stream>>>(W1, Wt1, 128, 256);
  transpose_cast<<<(256 * 256 + 255) / 256, 256, 0, stream>>>(W2, Wt2, 256, 256);
  transpose_cast<<<(256 * 32 + 255) / 256, 256, 0, stream>>>(W3, Wt3, 256, 32);

  // --- CSR build (shared by all 3 layers); hierarchical scan ---
  const int NB = (Nn + 255) / 256;
  hipMemsetAsync(deg, 0, (size_t)Nn * 4, stream);
  count_deg<<<(TotE + 255) / 256, 256, 0, stream>>>(edst, Ee, Nn, deg);
  scan_blk<<<NB, 256, 0, stream>>>(deg, exc, bsum, Nn);
  scan_top<<<1, 256, 0, stream>>>(bsum, boff, NB, off, Nn);
  scan_add<<<NB, 256, 0, stream>>>(exc, boff, off, cursor, Nn);
  fill_csr<<<(TotE + 255) / 256, 256, 0, stream>>>(esrc, edst, Ee, Nn, cursor, col);

  int waveBlocks = (Nn + 3) / 4;
  int gy = (Nn + 127) / 128;
  float invN = 1.0f / (float)Nn;

  // --- Layer 1: 128 -> 4x64 concat ---
  gemm_mfma_logits<128, 128, 64, 64, 4, 64><<<dim3(2, gy), 256, 0, stream>>>(
      xb, Wt1, hb, as1, ad1, als, ald, Nn, 256, 128);
  gat_aggregate<4, 64><<<waveBlocks, 256, 0, stream>>>(hb, als, ald, off, col, b1, agg, Nn);
  bn_stats_part<256><<<BN_NB, 256, 0, stream>>>(agg, Nn, pbuf);
  bn_reduce_finalize<256><<<256, 256, 0, stream>>>(pbuf, g1, be1, invN, ss);
  bn_apply_elu_b2b<256><<<2048, 256, 0, stream>>>(agg, ss, xb, Nn);

  // --- Layer 2: 256 -> 4x64 concat ---
  gemm_mfma_logits<128, 128, 64, 64, 4, 64><<<dim3(2, gy), 256, 0, stream>>>(
      xb, Wt2, hb, as2, ad2, als, ald, Nn, 256, 256);
  gat_aggregate<4, 64><<<waveBlocks, 256, 0, stream>>>(hb, als, ald, off, col, b2, agg, Nn);
  bn_stats_part<256><<<BN_NB, 256, 0, stream>>>(agg, Nn, pbuf);
  bn_reduce_finalize<256><<<256, 256, 0, stream>>>(pbuf, g2, be2, invN, ss);
  bn_apply_elu_b2b<256><<<2048, 256, 0, stream>>>(agg, ss, xb, Nn);

  // --- Layer 3: 256 -> 1x32, no concat ---
  gemm_mfma_logits<128, 32, 32, 32, 1, 32><<<dim3(1, gy), 256, 0, stream>>>(
      xb, Wt3, hb, as3, ad3, als, ald, Nn, 32, 256);
  gat_aggregate_splitk<32><<<waveBlocks, 256, 0, stream>>>(hb, als, ald, off, col, b3, agg, Nn);
  bn_stats_part<32><<<BN_NB, 256, 0, stream>>>(agg, Nn, pbuf);
  bn_reduce_finalize<32><<<32, 256, 0, stream>>>(pbuf, g3, be3, invN, ss);
  bn_apply_elu_b2b<32><<<512, 256, 0, stream>>>(agg, ss, agg, Nn);  // in-place

  // --- classifier ---
  classifier_k<<<(Nn + 255) / 256, 256, 0, stream>>>(agg, Wc1, bc1, Wc2, bc2, outp, Nn);
}

// Round 16
// 360.722 us; speedup vs baseline: 2.6747x; 1.2075x over previous
//
#include <hip/hip_runtime.h>
#include <math.h>

typedef __attribute__((ext_vector_type(8))) short short8;
typedef __attribute__((ext_vector_type(4))) float f32x4;

// ---------------- bf16 helpers ----------------

__device__ __forceinline__ float bf2f(unsigned short u) {
  union { unsigned int i; float f; } v;
  v.i = ((unsigned int)u) << 16;
  return v.f;
}
__device__ __forceinline__ unsigned short f2bf(float f) {
  union { float f; unsigned int i; } v;
  v.f = f;
  unsigned int x = v.i;
  unsigned int r = x + 0x7fffu + ((x >> 16) & 1u);  // RNE
  return (unsigned short)(r >> 16);
}
__device__ __forceinline__ float lo16f(unsigned int u) {
  union { unsigned int i; float f; } v;
  v.i = u << 16;
  return v.f;
}
__device__ __forceinline__ float hi16f(unsigned int u) {
  union { unsigned int i; float f; } v;
  v.i = u & 0xffff0000u;
  return v.f;
}

// ---------------- CSR build: atomic-free two-level counting sort ----------------
// Old path (count_deg + scans + fill_csr) was L2-atomic-serialization-bound:
// 2x 850K scattered global atomicAdd (~55us each) + 64B-line writes for 4B
// scatters. New path: 128-node buckets, per-(bucket,block) LDS histograms,
// block-contiguous scatter into bucket-sorted ebuf, then per-bucket fine fill
// with LDS-only atomics. Zero global atomics.

constexpr int CSR_HB = 256;     // hist blocks (contiguous edge chunks)
constexpr int BUK_SH = 7;       // 128 nodes per bucket
constexpr int MAXBUK = 512;     // Nn <= 65536

// Pass A1: per-(block, bucket) histogram. bhist[bucket * CSR_HB + blk].
__global__ __launch_bounds__(256) void bucket_hist(const int* __restrict__ dstA,
                                                   int Ee, int Nn, int nbuk,
                                                   int* __restrict__ bhist) {
  __shared__ int hist[MAXBUK];
  int t = threadIdx.x;
  for (int i = t; i < nbuk; i += 256) hist[i] = 0;
  __syncthreads();
  int TotE = Ee + Nn;
  int chunk = (TotE + CSR_HB - 1) / CSR_HB;
  int base = blockIdx.x * chunk;
  int lim = min(base + chunk, TotE);
  for (int e = base + t; e < lim; e += 256) {
    int d = (e < Ee) ? dstA[e] : (e - Ee);
    atomicAdd(&hist[d >> BUK_SH], 1);
  }
  __syncthreads();
  for (int i = t; i < nbuk; i += 256)
    bhist[(size_t)i * CSR_HB + blockIdx.x] = hist[i];
}

// Pass A2: per-bucket exclusive scan over the CSR_HB block counts.
__global__ __launch_bounds__(256) void bucket_scan(int* __restrict__ bhist,
                                                   int* __restrict__ btot) {
  __shared__ int sd[256];
  int b = blockIdx.x, t = threadIdx.x;
  int v = bhist[(size_t)b * CSR_HB + t];
  sd[t] = v;
  __syncthreads();
  #pragma unroll
  for (int s = 1; s < 256; s <<= 1) {
    int u = (t >= s) ? sd[t - s] : 0;
    __syncthreads();
    sd[t] += u;
    __syncthreads();
  }
  bhist[(size_t)b * CSR_HB + t] = sd[t] - v;  // exclusive within bucket
  if (t == 255) btot[b] = sd[255];
}

// Pass A3: exclusive scan of bucket totals -> bucketBase[nbuk+1].
__global__ __launch_bounds__(MAXBUK) void bucket_base(const int* __restrict__ btot,
                                                      int* __restrict__ bucketBase,
                                                      int nbuk) {
  __shared__ int sd[MAXBUK];
  int t = threadIdx.x;
  int v = (t < nbuk) ? btot[t] : 0;
  sd[t] = v;
  __syncthreads();
  #pragma unroll
  for (int s = 1; s < MAXBUK; s <<= 1) {
    int u = (t >= s) ? sd[t - s] : 0;
    __syncthreads();
    sd[t] += u;
    __syncthreads();
  }
  if (t < nbuk) bucketBase[t] = sd[t] - v;
  if (t == nbuk - 1) bucketBase[nbuk] = sd[t];
}

// Pass B: scatter edges into bucket-sorted ebuf (same chunking as A1).
__global__ __launch_bounds__(256) void bucket_scatter(const int* __restrict__ srcA,
                                                      const int* __restrict__ dstA,
                                                      int Ee, int Nn, int nbuk,
                                                      const int* __restrict__ bhist,
                                                      const int* __restrict__ bucketBase,
                                                      int2* __restrict__ ebuf) {
  __shared__ int cursor[MAXBUK];
  int t = threadIdx.x;
  for (int i = t; i < nbuk; i += 256)
    cursor[i] = bhist[(size_t)i * CSR_HB + blockIdx.x] + bucketBase[i];
  __syncthreads();
  int TotE = Ee + Nn;
  int chunk = (TotE + CSR_HB - 1) / CSR_HB;
  int base = blockIdx.x * chunk;
  int lim = min(base + chunk, TotE);
  for (int e = base + t; e < lim; e += 256) {
    int s, d;
    if (e < Ee) { s = srcA[e]; d = dstA[e]; }
    else        { s = e - Ee;  d = s; }
    int slot = atomicAdd(&cursor[d >> BUK_SH], 1);
    ebuf[slot] = make_int2(s, d);
  }
}

// Pass C: per-bucket fine fill — LDS degree count, LDS scan -> off[], then
// place col[] via LDS cursors. Writes land in a ~9KB-local col region.
__global__ __launch_bounds__(256) void fine_fill(const int2* __restrict__ ebuf,
                                                 const int* __restrict__ bucketBase,
                                                 int Nn, int TotE,
                                                 int* __restrict__ off,
                                                 int* __restrict__ col) {
  __shared__ int ndeg[128];
  __shared__ int ncur[128];
  __shared__ int sd[128];
  int b = blockIdx.x, t = threadIdx.x;
  int n0 = b << BUK_SH;
  int ncnt = min(128, Nn - n0);
  int ebeg = bucketBase[b], eend = bucketBase[b + 1];
  if (t < 128) ndeg[t] = 0;
  __syncthreads();
  for (int e = ebeg + t; e < eend; e += 256)
    atomicAdd(&ndeg[ebuf[e].y - n0], 1);
  __syncthreads();
  if (t < 128) sd[t] = ndeg[t];
  __syncthreads();
  #pragma unroll
  for (int s = 1; s < 128; s <<= 1) {
    int u = 0;
    if (t < 128 && t >= s) u = sd[t - s];
    __syncthreads();
    if (t < 128) sd[t] += u;
    __syncthreads();
  }
  if (t < 128) {
    int base = ebeg + sd[t] - ndeg[t];  // exclusive
    ncur[t] = base;
    if (t < ncnt) off[n0 + t] = base;
  }
  if (b == 0 && t == 0) off[Nn] = TotE;
  __syncthreads();
  for (int e = ebeg + t; e < eend; e += 256) {
    int2 ed = ebuf[e];
    int slot = atomicAdd(&ncur[ed.y - n0], 1);
    col[slot] = ed.x;
  }
}

// ---------------- operand prep ----------------

__global__ __launch_bounds__(256) void cast_f32_bf16(const float* __restrict__ in,
                                                     unsigned short* __restrict__ out,
                                                     size_t n4) {
  for (size_t i = blockIdx.x * (size_t)256 + threadIdx.x; i < n4;
       i += (size_t)gridDim.x * 256) {
    float4 v = *(const float4*)&in[i * 4];
    ushort4 o;
    o.x = f2bf(v.x); o.y = f2bf(v.y); o.z = f2bf(v.z); o.w = f2bf(v.w);
    *(ushort4*)&out[i * 4] = o;
  }
}

// Wt[n][k] = bf16(W[k][n])
__global__ __launch_bounds__(256) void transpose_cast(const float* __restrict__ W,
                                                      unsigned short* __restrict__ Wt,
                                                      int K, int N) {
  int t = blockIdx.x * 256 + threadIdx.x;
  if (t >= K * N) return;
  int n = t / K, k = t % K;
  Wt[t] = f2bf(W[(size_t)k * N + n]);
}

// ---------------- bf16 MFMA GEMM + fused attention logits (r15, passing) ----------------

template <int BM, int BN, int WM, int WN, int HEADS, int CC>
__global__ __launch_bounds__(256) void gemm_mfma_logits(
    const unsigned short* __restrict__ A,
    const unsigned short* __restrict__ Bt,
    unsigned short* __restrict__ C,
    const float* __restrict__ a_s, const float* __restrict__ a_d,
    float* __restrict__ als, float* __restrict__ ald,
    int M, int N, int K) {
  static_assert(WN == CC, "wave col-range must equal head width");
  constexpr int BK = 32;
  constexpr int LDA = BK + 8;
  constexpr int MF = WM / 16, NF = WN / 16;
  constexpr int NWN = BN / WN;
  constexpr int ACH = BM * BK / 8;
  constexpr int BCH = BN * BK / 8;
  constexpr int ACHT = (ACH + 255) / 256;
  constexpr int BCHT = (BCH + 255) / 256;

  __shared__ unsigned short Al[2][BM * LDA];
  __shared__ unsigned short Bl[2][BN * LDA];

  const int tid = threadIdx.x;
  const int wid = tid >> 6, lane = tid & 63;
  const int wr = wid / NWN, wc = wid % NWN;
  const int brow = blockIdx.y * BM;
  const int bcol = blockIdx.x * BN;

  f32x4 acc[MF][NF] = {};
  uint4 ra[ACHT], rb[BCHT];

  auto loadG = [&](int k0) {
    #pragma unroll
    for (int c = 0; c < ACHT; ++c) {
      int i = c * 256 + tid;
      if (ACH % 256 == 0 || i < ACH) {
        int row = i >> 2, blk = i & 3;
        int rg = brow + row;
        rg = rg < M ? rg : M - 1;
        ra[c] = *(const uint4*)&A[(size_t)rg * K + k0 + blk * 8];
      }
    }
    #pragma unroll
    for (int c = 0; c < BCHT; ++c) {
      int i = c * 256 + tid;
      if (BCH % 256 == 0 || i < BCH) {
        int row = i >> 2, blk = i & 3;
        rb[c] = *(const uint4*)&Bt[(size_t)(bcol + row) * K + k0 + blk * 8];
      }
    }
  };
  auto storeL = [&](int buf) {
    #pragma unroll
    for (int c = 0; c < ACHT; ++c) {
      int i = c * 256 + tid;
      if (ACH % 256 == 0 || i < ACH) {
        int row = i >> 2, blk = i & 3;
        *(uint4*)&Al[buf][row * LDA + blk * 8] = ra[c];
      }
    }
    #pragma unroll
    for (int c = 0; c < BCHT; ++c) {
      int i = c * 256 + tid;
      if (BCH % 256 == 0 || i < BCH) {
        int row = i >> 2, blk = i & 3;
        *(uint4*)&Bl[buf][row * LDA + blk * 8] = rb[c];
      }
    }
  };

  const int nt = K / BK;
  loadG(0);
  storeL(0);
  __syncthreads();
  int cur = 0;
  const int arow = wr * WM + (lane & 15);
  const int bro = wc * WN + (lane & 15);
  const int kb = (lane >> 4) * 8;
  for (int t = 0; t < nt; ++t) {
    if (t + 1 < nt) loadG((t + 1) * BK);
    short8 af[MF], bfr[NF];
    #pragma unroll
    for (int m = 0; m < MF; ++m)
      af[m] = *(const short8*)&Al[cur][(arow + m * 16) * LDA + kb];
    #pragma unroll
    for (int n = 0; n < NF; ++n)
      bfr[n] = *(const short8*)&Bl[cur][(bro + n * 16) * LDA + kb];
    #pragma unroll
    for (int m = 0; m < MF; ++m)
      #pragma unroll
      for (int n = 0; n < NF; ++n)
        acc[m][n] = __builtin_amdgcn_mfma_f32_16x16x32_bf16(af[m], bfr[n], acc[m][n], 0, 0, 0);
    if (t + 1 < nt) storeL(cur ^ 1);
    __syncthreads();
    cur ^= 1;
  }

  const int crow0 = brow + wr * WM + (lane >> 4) * 4;
  const int ccol0 = bcol + wc * WN + (lane & 15);
  #pragma unroll
  for (int m = 0; m < MF; ++m) {
    #pragma unroll
    for (int r = 0; r < 4; ++r) {
      int grow = crow0 + m * 16 + r;
      if (grow >= M) continue;
      #pragma unroll
      for (int n = 0; n < NF; ++n)
        C[(size_t)grow * N + ccol0 + n * 16] = f2bf(acc[m][n][r]);
    }
  }

  // ---- fused logits epilogue ----
  const int hidx = (bcol + wc * WN) / CC;
  float asv[NF], adv[NF];
  #pragma unroll
  for (int n = 0; n < NF; ++n) {
    int ch = (lane & 15) + n * 16;
    asv[n] = a_s[hidx * CC + ch];
    adv[n] = a_d[hidx * CC + ch];
  }
  #pragma unroll
  for (int m = 0; m < MF; ++m) {
    #pragma unroll
    for (int r = 0; r < 4; ++r) {
      float ps = 0.f, pd = 0.f;
      #pragma unroll
      for (int n = 0; n < NF; ++n) {
        float v = acc[m][n][r];
        ps += v * asv[n];
        pd += v * adv[n];
      }
      #pragma unroll
      for (int o = 1; o < 16; o <<= 1) {
        ps += __shfl_xor(ps, o, 64);
        pd += __shfl_xor(pd, o, 64);
      }
      int grow = crow0 + m * 16 + r;
      if ((lane & 15) == 0 && grow < M) {
        als[(size_t)grow * HEADS + hidx] = ps;
        ald[(size_t)grow * HEADS + hidx] = pd;
      }
    }
  }
}

// ---------------- GAT aggregation: one wave per dst, 8-edge unroll (r13) ----------------

template <int HEADS, int CC>
__global__ __launch_bounds__(256) void gat_aggregate(const unsigned short* __restrict__ h,
                                                     const float* __restrict__ als,
                                                     const float* __restrict__ ald,
                                                     const int* __restrict__ off,
                                                     const int* __restrict__ col,
                                                     const float* __restrict__ bias,
                                                     unsigned short* __restrict__ out,
                                                     int Nn) {
  constexpr int HC = HEADS * CC;
  int wid = (int)((blockIdx.x * (size_t)blockDim.x + threadIdx.x) >> 6);
  int lane = threadIdx.x & 63;
  if (wid >= Nn) return;
  int c0 = lane * 4;
  int head = c0 / CC;
  float my_ald = ald[(size_t)wid * HEADS + head];
  float ssum = 0.f;
  float acc[4] = {};
  int beg = off[wid], end = off[wid + 1];

  auto lrelu = [](float l) { return (l > 0.f) ? l : 0.2f * l; };

  int j = beg;
  for (; j + 8 <= end; j += 8) {
    int sI[8];
    ushort4 g[8];
    float p[8];
    #pragma unroll
    for (int k = 0; k < 8; ++k) sI[k] = col[j + k];
    #pragma unroll
    for (int k = 0; k < 8; ++k)
      g[k] = *(const ushort4*)(h + (size_t)sI[k] * HC + c0);
    #pragma unroll
    for (int k = 0; k < 8; ++k)
      p[k] = __expf(lrelu(als[(size_t)sI[k] * HEADS + head] + my_ald));
    #pragma unroll
    for (int k = 0; k < 8; ++k) {
      ssum += p[k];
      acc[0] += p[k] * bf2f(g[k].x);
      acc[1] += p[k] * bf2f(g[k].y);
      acc[2] += p[k] * bf2f(g[k].z);
      acc[3] += p[k] * bf2f(g[k].w);
    }
  }
  for (; j + 4 <= end; j += 4) {
    int sI[4];
    ushort4 g[4];
    float p[4];
    #pragma unroll
    for (int k = 0; k < 4; ++k) sI[k] = col[j + k];
    #pragma unroll
    for (int k = 0; k < 4; ++k)
      g[k] = *(const ushort4*)(h + (size_t)sI[k] * HC + c0);
    #pragma unroll
    for (int k = 0; k < 4; ++k)
      p[k] = __expf(lrelu(als[(size_t)sI[k] * HEADS + head] + my_ald));
    #pragma unroll
    for (int k = 0; k < 4; ++k) {
      ssum += p[k];
      acc[0] += p[k] * bf2f(g[k].x);
      acc[1] += p[k] * bf2f(g[k].y);
      acc[2] += p[k] * bf2f(g[k].z);
      acc[3] += p[k] * bf2f(g[k].w);
    }
  }
  for (; j < end; ++j) {
    int s = col[j];
    float p = __expf(lrelu(als[(size_t)s * HEADS + head] + my_ald));
    ssum += p;
    ushort4 hv = *(const ushort4*)(h + (size_t)s * HC + c0);
    acc[0] += p * bf2f(hv.x);
    acc[1] += p * bf2f(hv.y);
    acc[2] += p * bf2f(hv.z);
    acc[3] += p * bf2f(hv.w);
  }
  float inv = 1.f / (ssum + 1e-16f);
  #pragma unroll
  for (int k2 = 0; k2 < 4; ++k2)
    out[(size_t)wid * HC + c0 + k2] = f2bf(acc[k2] * inv + bias[c0 + k2]);
}

// HEADS=1, CC=32: split-K within a wave (r13).

template <int CC>
__global__ __launch_bounds__(256) void gat_aggregate_splitk(
    const unsigned short* __restrict__ h, const float* __restrict__ als,
    const float* __restrict__ ald, const int* __restrict__ off,
    const int* __restrict__ col, const float* __restrict__ bias,
    unsigned short* __restrict__ out, int Nn) {
  int wid = (int)((blockIdx.x * (size_t)blockDim.x + threadIdx.x) >> 6);
  int lane = threadIdx.x & 63;
  if (wid >= Nn) return;
  int c = lane & (CC - 1);
  int half = lane >> 5;
  float my_ald = ald[wid];
  int beg0 = off[wid], end0 = off[wid + 1];
  int mid = beg0 + ((end0 - beg0) >> 1);
  int beg = half ? mid : beg0;
  int end = half ? end0 : mid;

  auto lrelu = [](float l) { return (l > 0.f) ? l : 0.2f * l; };

  float ssum = 0.f, acc = 0.f;
  int j = beg;
  for (; j + 4 <= end; j += 4) {
    int s0 = col[j], s1 = col[j + 1], s2 = col[j + 2], s3 = col[j + 3];
    unsigned short g0 = h[(size_t)s0 * CC + c];
    unsigned short g1 = h[(size_t)s1 * CC + c];
    unsigned short g2 = h[(size_t)s2 * CC + c];
    unsigned short g3 = h[(size_t)s3 * CC + c];
    float p0 = __expf(lrelu(als[s0] + my_ald));
    float p1 = __expf(lrelu(als[s1] + my_ald));
    float p2 = __expf(lrelu(als[s2] + my_ald));
    float p3 = __expf(lrelu(als[s3] + my_ald));
    ssum += (p0 + p1) + (p2 + p3);
    acc += p0 * bf2f(g0) + p1 * bf2f(g1) + p2 * bf2f(g2) + p3 * bf2f(g3);
  }
  for (; j < end; ++j) {
    int s = col[j];
    float p = __expf(lrelu(als[s] + my_ald));
    ssum += p;
    acc += p * bf2f(h[(size_t)s * CC + c]);
  }
  ssum += __shfl_xor(ssum, 32, 64);
  acc += __shfl_xor(acc, 32, 64);
  if (half == 0)
    out[(size_t)wid * CC + c] = f2bf(acc / (ssum + 1e-16f) + bias[c]);
}

// ---------------- BatchNorm (biased var) — parallel two-stage, bf16 input ----------------

constexpr int BN_NB = 1024;

template <int CH>
__global__ __launch_bounds__(256) void bn_stats_part(const unsigned short* __restrict__ x,
                                                     int Nn, float* __restrict__ pbuf) {
  constexpr int Q8 = CH / 8;
  int t = threadIdx.x;
  size_t tot8 = (size_t)Nn * Q8;
  size_t stride = (size_t)gridDim.x * 256;
  float s[8] = {}, sq[8] = {};
  for (size_t i = blockIdx.x * (size_t)256 + t; i < tot8; i += stride) {
    uint4 u = *(const uint4*)&x[i * 8];
    float v[8] = {lo16f(u.x), hi16f(u.x), lo16f(u.y), hi16f(u.y),
                  lo16f(u.z), hi16f(u.z), lo16f(u.w), hi16f(u.w)};
    #pragma unroll
    for (int k = 0; k < 8; ++k) { s[k] += v[k]; sq[k] += v[k] * v[k]; }
  }
  __shared__ float sS[256][8];
  __shared__ float sQ[256][8];
  #pragma unroll
  for (int k = 0; k < 8; ++k) { sS[t][k] = s[k]; sQ[t][k] = sq[k]; }
  __syncthreads();
  for (int half = 128; half >= Q8; half >>= 1) {
    if (t < half) {
      #pragma unroll
      for (int k = 0; k < 8; ++k) {
        sS[t][k] += sS[t + half][k];
        sQ[t][k] += sQ[t + half][k];
      }
    }
    __syncthreads();
  }
  if (t < Q8) {
    #pragma unroll
    for (int k = 0; k < 8; ++k) {
      pbuf[(size_t)blockIdx.x * 2 * CH + t * 8 + k] = sS[t][k];
      pbuf[(size_t)blockIdx.x * 2 * CH + CH + t * 8 + k] = sQ[t][k];
    }
  }
}

template <int CH>
__global__ __launch_bounds__(256) void bn_reduce_finalize(const float* __restrict__ pbuf,
                                                          const float* __restrict__ g,
                                                          const float* __restrict__ be,
                                                          float invN,
                                                          float* __restrict__ ss) {
  int c = blockIdx.x;
  int t = threadIdx.x;
  float s = 0.f, q = 0.f;
  for (int b = t; b < BN_NB; b += 256) {
    s += pbuf[(size_t)b * 2 * CH + c];
    q += pbuf[(size_t)b * 2 * CH + CH + c];
  }
  #pragma unroll
  for (int o = 32; o > 0; o >>= 1) {
    s += __shfl_xor(s, o, 64);
    q += __shfl_xor(q, o, 64);
  }
  __shared__ float rs[4], rq[4];
  int wv = t >> 6, lane = t & 63;
  if (lane == 0) { rs[wv] = s; rq[wv] = q; }
  __syncthreads();
  if (t == 0) {
    float S = rs[0] + rs[1] + rs[2] + rs[3];
    float Qs = rq[0] + rq[1] + rq[2] + rq[3];
    float mu = S * invN;
    float var = Qs * invN - mu * mu;
    float sc = g[c] * rsqrtf(var + 1e-5f);
    ss[c] = sc;
    ss[CH + c] = be[c] - mu * sc;
  }
}

template <int CH>
__global__ __launch_bounds__(256) void bn_apply_elu_b2b(const unsigned short* __restrict__ x,
                                                        const float* __restrict__ ss,
                                                        unsigned short* __restrict__ out,
                                                        int Nn) {
  size_t tot8 = (size_t)Nn * (CH / 8);
  for (size_t i = blockIdx.x * (size_t)256 + threadIdx.x; i < tot8;
       i += (size_t)gridDim.x * 256) {
    uint4 u = *(const uint4*)&x[i * 8];
    int c0 = (int)((i % (CH / 8)) * 8);
    float v[8] = {lo16f(u.x), hi16f(u.x), lo16f(u.y), hi16f(u.y),
                  lo16f(u.z), hi16f(u.z), lo16f(u.w), hi16f(u.w)};
    unsigned int o[4];
    #pragma unroll
    for (int k = 0; k < 4; ++k) {
      float y0 = v[2 * k] * ss[c0 + 2 * k] + ss[CH + c0 + 2 * k];
      float y1 = v[2 * k + 1] * ss[c0 + 2 * k + 1] + ss[CH + c0 + 2 * k + 1];
      y0 = (y0 > 0.f) ? y0 : expm1f(y0);
      y1 = (y1 > 0.f) ? y1 : expm1f(y1);
      o[k] = (unsigned int)f2bf(y0) | ((unsigned int)f2bf(y1) << 16);
    }
    *(uint4*)&out[i * 8] = make_uint4(o[0], o[1], o[2], o[3]);
  }
}

// ---------------- classifier: relu(x@Wc1+bc1)@Wc2+bc2 (bf16 x) ----------------

__global__ __launch_bounds__(256) void classifier_k(const unsigned short* __restrict__ x,
                                                    const float* __restrict__ Wc1,
                                                    const float* __restrict__ bc1,
                                                    const float* __restrict__ Wc2,
                                                    const float* __restrict__ bc2,
                                                    float* __restrict__ outp, int Nn) {
  __shared__ unsigned short sx[256][33];
  __shared__ float sw[32 * 32];
  __shared__ float sb1[32];
  __shared__ float sw2[32];
  int t = threadIdx.x;
  int base = blockIdx.x * 256;
  for (int i = t; i < 1024; i += 256) sw[i] = Wc1[i];
  if (t < 32) { sb1[t] = bc1[t]; sw2[t] = Wc2[t]; }
  int cnt = min(256, Nn - base);
  for (int i = t; i < cnt * 32; i += 256) sx[i / 32][i % 32] = x[(size_t)base * 32 + i];
  __syncthreads();
  if (t < cnt) {
    float xa[32];
    #pragma unroll
    for (int c = 0; c < 32; ++c) xa[c] = bf2f(sx[t][c]);
    float o = bc2[0];
    #pragma unroll
    for (int j = 0; j < 32; ++j) {
      float v = sb1[j];
      #pragma unroll
      for (int c = 0; c < 32; ++c) v += xa[c] * sw[c * 32 + j];
      v = fmaxf(v, 0.f);
      o += v * sw2[j];
    }
    outp[base + t] = o;
  }
}

// ---------------- host orchestration ----------------

extern "C" void kernel_launch(void* const* d_in, const int* in_sizes, int n_in,
                              void* d_out, int out_size, void* d_ws, size_t ws_size,
                              hipStream_t stream) {
  const float* x   = (const float*)d_in[0];
  const int*   ei  = (const int*)d_in[1];
  const float* W1  = (const float*)d_in[2];
  const float* as1 = (const float*)d_in[3];
  const float* ad1 = (const float*)d_in[4];
  const float* b1  = (const float*)d_in[5];
  const float* g1  = (const float*)d_in[6];
  const float* be1 = (const float*)d_in[7];
  const float* W2  = (const float*)d_in[8];
  const float* as2 = (const float*)d_in[9];
  const float* ad2 = (const float*)d_in[10];
  const float* b2  = (const float*)d_in[11];
  const float* g2  = (const float*)d_in[12];
  const float* be2 = (const float*)d_in[13];
  const float* W3  = (const float*)d_in[14];
  const float* as3 = (const float*)d_in[15];
  const float* ad3 = (const float*)d_in[16];
  const float* b3  = (const float*)d_in[17];
  const float* g3  = (const float*)d_in[18];
  const float* be3 = (const float*)d_in[19];
  const float* Wc1 = (const float*)d_in[20];
  const float* bc1 = (const float*)d_in[21];
  const float* Wc2 = (const float*)d_in[22];
  const float* bc2 = (const float*)d_in[23];
  float* outp = (float*)d_out;

  const int Nn = in_sizes[0] / 128;
  const int Ee = in_sizes[1] / 2;
  const int TotE = Ee + Nn;
  const int* esrc = ei;
  const int* edst = ei + Ee;

  char* w = (char*)d_ws;
  auto carve = [&](size_t bytes) {
    char* p = w;
    w += (bytes + 255) & ~(size_t)255;
    return p;
  };
  unsigned short* hb  = (unsigned short*)carve((size_t)Nn * 256 * 2);
  unsigned short* xb  = (unsigned short*)carve((size_t)Nn * 256 * 2);
  unsigned short* agg = (unsigned short*)carve((size_t)Nn * 256 * 2);
  float* als   = (float*)carve((size_t)Nn * 4 * 4);
  float* ald   = (float*)carve((size_t)Nn * 4 * 4);
  float* pbuf  = (float*)carve((size_t)BN_NB * 512 * 4);
  float* ss    = (float*)carve(512 * 4);
  unsigned short* Wt1 = (unsigned short*)carve(256 * 128 * 2);
  unsigned short* Wt2 = (unsigned short*)carve(256 * 256 * 2);
  unsigned short* Wt3 = (unsigned short*)carve(32 * 256 * 2);
  int* off     = (int*)carve((size_t)(Nn + 1) * 4);
  int* col     = (int*)carve((size_t)TotE * 4);
  int2* ebuf   = (int2*)carve((size_t)TotE * 8);
  int* bhist   = (int*)carve((size_t)MAXBUK * CSR_HB * 4);
  int* btot    = (int*)carve(MAXBUK * 4);
  int* bucketBase = (int*)carve((MAXBUK + 1) * 4);

  // --- operand prep ---
  cast_f32_bf16<<<2048, 256, 0, stream>>>(x, xb, (size_t)Nn * 128 / 4);
  transpose_cast<<<(128 * 256 + 255) / 256, 256, 0, stream>>>(W1, Wt1, 128, 256);
  transpose_cast<<<(256 * 256 + 255) / 256, 256, 0, stream>>>(W2, Wt2, 256, 256);
  transpose_cast<<<(256 * 32 + 255) / 256, 256, 0, stream>>>(W3, Wt3, 256, 32);

  // --- CSR build: atomic-free bucketed counting sort ---
  const int nbuk = (Nn + 127) >> BUK_SH;
  bucket_hist<<<CSR_HB, 256, 0, stream>>>(edst, Ee, Nn, nbuk, bhist);
  bucket_scan<<<nbuk, 256, 0, stream>>>(bhist, btot);
  bucket_base<<<1, MAXBUK, 0, stream>>>(btot, bucketBase, nbuk);
  bucket_scatter<<<CSR_HB, 256, 0, stream>>>(esrc, edst, Ee, Nn, nbuk, bhist, bucketBase, ebuf);
  fine_fill<<<nbuk, 256, 0, stream>>>(ebuf, bucketBase, Nn, TotE, off, col);

  int waveBlocks = (Nn + 3) / 4;
  int gy = (Nn + 127) / 128;
  float invN = 1.0f / (float)Nn;

  // --- Layer 1: 128 -> 4x64 concat ---
  gemm_mfma_logits<128, 128, 64, 64, 4, 64><<<dim3(2, gy), 256, 0, stream>>>(
      xb, Wt1, hb, as1, ad1, als, ald, Nn, 256, 128);
  gat_aggregate<4, 64><<<waveBlocks, 256, 0, stream>>>(hb, als, ald, off, col, b1, agg, Nn);
  bn_stats_part<256><<<BN_NB, 256, 0, stream>>>(agg, Nn, pbuf);
  bn_reduce_finalize<256><<<256, 256, 0, stream>>>(pbuf, g1, be1, invN, ss);
  bn_apply_elu_b2b<256><<<2048, 256, 0, stream>>>(agg, ss, xb, Nn);

  // --- Layer 2: 256 -> 4x64 concat ---
  gemm_mfma_logits<128, 128, 64, 64, 4, 64><<<dim3(2, gy), 256, 0, stream>>>(
      xb, Wt2, hb, as2, ad2, als, ald, Nn, 256, 256);
  gat_aggregate<4, 64><<<waveBlocks, 256, 0, stream>>>(hb, als, ald, off, col, b2, agg, Nn);
  bn_stats_part<256><<<BN_NB, 256, 0, stream>>>(agg, Nn, pbuf);
  bn_reduce_finalize<256><<<256, 256, 0, stream>>>(pbuf, g2, be2, invN, ss);
  bn_apply_elu_b2b<256><<<2048, 256, 0, stream>>>(agg, ss, xb, Nn);

  // --- Layer 3: 256 -> 1x32, no concat ---
  gemm_mfma_logits<128, 32, 32, 32, 1, 32><<<dim3(1, gy), 256, 0, stream>>>(
      xb, Wt3, hb, as3, ad3, als, ald, Nn, 32, 256);
  gat_aggregate_splitk<32><<<waveBlocks, 256, 0, stream>>>(hb, als, ald, off, col, b3, agg, Nn);
  bn_stats_part<32><<<BN_NB, 256, 0, stream>>>(agg, Nn, pbuf);
  bn_reduce_finalize<32><<<32, 256, 0, stream>>>(pbuf, g3, be3, invN, ss);
  bn_apply_elu_b2b<32><<<512, 256, 0, stream>>>(agg, ss, agg, Nn);  // in-place

  // --- classifier ---
  classifier_k<<<(Nn + 255) / 256, 256, 0, stream>>>(agg, Wc1, bc1, Wc2, bc2, outp, Nn);
}

// Round 17
// 359.353 us; speedup vs baseline: 2.6849x; 1.0038x over previous
//
#include <hip/hip_runtime.h>
#include <math.h>

typedef __attribute__((ext_vector_type(8))) short short8;
typedef __attribute__((ext_vector_type(4))) float f32x4;

// ---------------- bf16 helpers ----------------

__device__ __forceinline__ float bf2f(unsigned short u) {
  union { unsigned int i; float f; } v;
  v.i = ((unsigned int)u) << 16;
  return v.f;
}
__device__ __forceinline__ unsigned short f2bf(float f) {
  union { float f; unsigned int i; } v;
  v.f = f;
  unsigned int x = v.i;
  unsigned int r = x + 0x7fffu + ((x >> 16) & 1u);  // RNE
  return (unsigned short)(r >> 16);
}
__device__ __forceinline__ float lo16f(unsigned int u) {
  union { unsigned int i; float f; } v;
  v.i = u << 16;
  return v.f;
}
__device__ __forceinline__ float hi16f(unsigned int u) {
  union { unsigned int i; float f; } v;
  v.i = u & 0xffff0000u;
  return v.f;
}

// ---------------- CSR build: atomic-free two-level counting sort (r16) ----------------

constexpr int CSR_HB = 256;
constexpr int BUK_SH = 7;
constexpr int MAXBUK = 512;

__global__ __launch_bounds__(256) void bucket_hist(const int* __restrict__ dstA,
                                                   int Ee, int Nn, int nbuk,
                                                   int* __restrict__ bhist) {
  __shared__ int hist[MAXBUK];
  int t = threadIdx.x;
  for (int i = t; i < nbuk; i += 256) hist[i] = 0;
  __syncthreads();
  int TotE = Ee + Nn;
  int chunk = (TotE + CSR_HB - 1) / CSR_HB;
  int base = blockIdx.x * chunk;
  int lim = min(base + chunk, TotE);
  for (int e = base + t; e < lim; e += 256) {
    int d = (e < Ee) ? dstA[e] : (e - Ee);
    atomicAdd(&hist[d >> BUK_SH], 1);
  }
  __syncthreads();
  for (int i = t; i < nbuk; i += 256)
    bhist[(size_t)i * CSR_HB + blockIdx.x] = hist[i];
}

__global__ __launch_bounds__(256) void bucket_scan(int* __restrict__ bhist,
                                                   int* __restrict__ btot) {
  __shared__ int sd[256];
  int b = blockIdx.x, t = threadIdx.x;
  int v = bhist[(size_t)b * CSR_HB + t];
  sd[t] = v;
  __syncthreads();
  #pragma unroll
  for (int s = 1; s < 256; s <<= 1) {
    int u = (t >= s) ? sd[t - s] : 0;
    __syncthreads();
    sd[t] += u;
    __syncthreads();
  }
  bhist[(size_t)b * CSR_HB + t] = sd[t] - v;
  if (t == 255) btot[b] = sd[255];
}

__global__ __launch_bounds__(MAXBUK) void bucket_base(const int* __restrict__ btot,
                                                      int* __restrict__ bucketBase,
                                                      int nbuk) {
  __shared__ int sd[MAXBUK];
  int t = threadIdx.x;
  int v = (t < nbuk) ? btot[t] : 0;
  sd[t] = v;
  __syncthreads();
  #pragma unroll
  for (int s = 1; s < MAXBUK; s <<= 1) {
    int u = (t >= s) ? sd[t - s] : 0;
    __syncthreads();
    sd[t] += u;
    __syncthreads();
  }
  if (t < nbuk) bucketBase[t] = sd[t] - v;
  if (t == nbuk - 1) bucketBase[nbuk] = sd[t];
}

__global__ __launch_bounds__(256) void bucket_scatter(const int* __restrict__ srcA,
                                                      const int* __restrict__ dstA,
                                                      int Ee, int Nn, int nbuk,
                                                      const int* __restrict__ bhist,
                                                      const int* __restrict__ bucketBase,
                                                      int2* __restrict__ ebuf) {
  __shared__ int cursor[MAXBUK];
  int t = threadIdx.x;
  for (int i = t; i < nbuk; i += 256)
    cursor[i] = bhist[(size_t)i * CSR_HB + blockIdx.x] + bucketBase[i];
  __syncthreads();
  int TotE = Ee + Nn;
  int chunk = (TotE + CSR_HB - 1) / CSR_HB;
  int base = blockIdx.x * chunk;
  int lim = min(base + chunk, TotE);
  for (int e = base + t; e < lim; e += 256) {
    int s, d;
    if (e < Ee) { s = srcA[e]; d = dstA[e]; }
    else        { s = e - Ee;  d = s; }
    int slot = atomicAdd(&cursor[d >> BUK_SH], 1);
    ebuf[slot] = make_int2(s, d);
  }
}

__global__ __launch_bounds__(256) void fine_fill(const int2* __restrict__ ebuf,
                                                 const int* __restrict__ bucketBase,
                                                 int Nn, int TotE,
                                                 int* __restrict__ off,
                                                 int* __restrict__ col) {
  __shared__ int ndeg[128];
  __shared__ int ncur[128];
  __shared__ int sd[128];
  int b = blockIdx.x, t = threadIdx.x;
  int n0 = b << BUK_SH;
  int ncnt = min(128, Nn - n0);
  int ebeg = bucketBase[b], eend = bucketBase[b + 1];
  if (t < 128) ndeg[t] = 0;
  __syncthreads();
  for (int e = ebeg + t; e < eend; e += 256)
    atomicAdd(&ndeg[ebuf[e].y - n0], 1);
  __syncthreads();
  if (t < 128) sd[t] = ndeg[t];
  __syncthreads();
  #pragma unroll
  for (int s = 1; s < 128; s <<= 1) {
    int u = 0;
    if (t < 128 && t >= s) u = sd[t - s];
    __syncthreads();
    if (t < 128) sd[t] += u;
    __syncthreads();
  }
  if (t < 128) {
    int base = ebeg + sd[t] - ndeg[t];
    ncur[t] = base;
    if (t < ncnt) off[n0 + t] = base;
  }
  if (b == 0 && t == 0) off[Nn] = TotE;
  __syncthreads();
  for (int e = ebeg + t; e < eend; e += 256) {
    int2 ed = ebuf[e];
    int slot = atomicAdd(&ncur[ed.y - n0], 1);
    col[slot] = ed.x;
  }
}

// ---------------- operand prep ----------------

__global__ __launch_bounds__(256) void cast_f32_bf16(const float* __restrict__ in,
                                                     unsigned short* __restrict__ out,
                                                     size_t n4) {
  for (size_t i = blockIdx.x * (size_t)256 + threadIdx.x; i < n4;
       i += (size_t)gridDim.x * 256) {
    float4 v = *(const float4*)&in[i * 4];
    ushort4 o;
    o.x = f2bf(v.x); o.y = f2bf(v.y); o.z = f2bf(v.z); o.w = f2bf(v.w);
    *(ushort4*)&out[i * 4] = o;
  }
}

// All three weight transposes in one launch. Wt[n][k] = bf16(W[k][n]).
__global__ __launch_bounds__(256) void transpose_cast_all(
    const float* __restrict__ W1, const float* __restrict__ W2,
    const float* __restrict__ W3, unsigned short* __restrict__ Wt1,
    unsigned short* __restrict__ Wt2, unsigned short* __restrict__ Wt3) {
  int t = blockIdx.x * 256 + threadIdx.x;
  if (t < 128 * 256) {
    int n = t / 128, k = t % 128;               // Wt1[256][128]
    Wt1[t] = f2bf(W1[(size_t)k * 256 + n]);     // W1[128][256]
  } else if (t < 128 * 256 + 256 * 256) {
    int i = t - 128 * 256;
    int n = i / 256, k = i % 256;               // Wt2[256][256]
    Wt2[i] = f2bf(W2[(size_t)k * 256 + n]);
  } else if (t < 128 * 256 + 256 * 256 + 256 * 32) {
    int i = t - 128 * 256 - 256 * 256;
    int n = i / 256, k = i % 256;               // Wt3[32][256]
    Wt3[i] = f2bf(W3[(size_t)k * 32 + n]);      // W3[256][32]
  }
}

// ---------------- bf16 MFMA GEMM + fused attention logits (r15, passing) ----------------

template <int BM, int BN, int WM, int WN, int HEADS, int CC>
__global__ __launch_bounds__(256) void gemm_mfma_logits(
    const unsigned short* __restrict__ A,
    const unsigned short* __restrict__ Bt,
    unsigned short* __restrict__ C,
    const float* __restrict__ a_s, const float* __restrict__ a_d,
    float* __restrict__ als, float* __restrict__ ald,
    int M, int N, int K) {
  static_assert(WN == CC, "wave col-range must equal head width");
  constexpr int BK = 32;
  constexpr int LDA = BK + 8;
  constexpr int MF = WM / 16, NF = WN / 16;
  constexpr int NWN = BN / WN;
  constexpr int ACH = BM * BK / 8;
  constexpr int BCH = BN * BK / 8;
  constexpr int ACHT = (ACH + 255) / 256;
  constexpr int BCHT = (BCH + 255) / 256;

  __shared__ unsigned short Al[2][BM * LDA];
  __shared__ unsigned short Bl[2][BN * LDA];

  const int tid = threadIdx.x;
  const int wid = tid >> 6, lane = tid & 63;
  const int wr = wid / NWN, wc = wid % NWN;
  const int brow = blockIdx.y * BM;
  const int bcol = blockIdx.x * BN;

  f32x4 acc[MF][NF] = {};
  uint4 ra[ACHT], rb[BCHT];

  auto loadG = [&](int k0) {
    #pragma unroll
    for (int c = 0; c < ACHT; ++c) {
      int i = c * 256 + tid;
      if (ACH % 256 == 0 || i < ACH) {
        int row = i >> 2, blk = i & 3;
        int rg = brow + row;
        rg = rg < M ? rg : M - 1;
        ra[c] = *(const uint4*)&A[(size_t)rg * K + k0 + blk * 8];
      }
    }
    #pragma unroll
    for (int c = 0; c < BCHT; ++c) {
      int i = c * 256 + tid;
      if (BCH % 256 == 0 || i < BCH) {
        int row = i >> 2, blk = i & 3;
        rb[c] = *(const uint4*)&Bt[(size_t)(bcol + row) * K + k0 + blk * 8];
      }
    }
  };
  auto storeL = [&](int buf) {
    #pragma unroll
    for (int c = 0; c < ACHT; ++c) {
      int i = c * 256 + tid;
      if (ACH % 256 == 0 || i < ACH) {
        int row = i >> 2, blk = i & 3;
        *(uint4*)&Al[buf][row * LDA + blk * 8] = ra[c];
      }
    }
    #pragma unroll
    for (int c = 0; c < BCHT; ++c) {
      int i = c * 256 + tid;
      if (BCH % 256 == 0 || i < BCH) {
        int row = i >> 2, blk = i & 3;
        *(uint4*)&Bl[buf][row * LDA + blk * 8] = rb[c];
      }
    }
  };

  const int nt = K / BK;
  loadG(0);
  storeL(0);
  __syncthreads();
  int cur = 0;
  const int arow = wr * WM + (lane & 15);
  const int bro = wc * WN + (lane & 15);
  const int kb = (lane >> 4) * 8;
  for (int t = 0; t < nt; ++t) {
    if (t + 1 < nt) loadG((t + 1) * BK);
    short8 af[MF], bfr[NF];
    #pragma unroll
    for (int m = 0; m < MF; ++m)
      af[m] = *(const short8*)&Al[cur][(arow + m * 16) * LDA + kb];
    #pragma unroll
    for (int n = 0; n < NF; ++n)
      bfr[n] = *(const short8*)&Bl[cur][(bro + n * 16) * LDA + kb];
    #pragma unroll
    for (int m = 0; m < MF; ++m)
      #pragma unroll
      for (int n = 0; n < NF; ++n)
        acc[m][n] = __builtin_amdgcn_mfma_f32_16x16x32_bf16(af[m], bfr[n], acc[m][n], 0, 0, 0);
    if (t + 1 < nt) storeL(cur ^ 1);
    __syncthreads();
    cur ^= 1;
  }

  const int crow0 = brow + wr * WM + (lane >> 4) * 4;
  const int ccol0 = bcol + wc * WN + (lane & 15);
  #pragma unroll
  for (int m = 0; m < MF; ++m) {
    #pragma unroll
    for (int r = 0; r < 4; ++r) {
      int grow = crow0 + m * 16 + r;
      if (grow >= M) continue;
      #pragma unroll
      for (int n = 0; n < NF; ++n)
        C[(size_t)grow * N + ccol0 + n * 16] = f2bf(acc[m][n][r]);
    }
  }

  // ---- fused logits epilogue ----
  const int hidx = (bcol + wc * WN) / CC;
  float asv[NF], adv[NF];
  #pragma unroll
  for (int n = 0; n < NF; ++n) {
    int ch = (lane & 15) + n * 16;
    asv[n] = a_s[hidx * CC + ch];
    adv[n] = a_d[hidx * CC + ch];
  }
  #pragma unroll
  for (int m = 0; m < MF; ++m) {
    #pragma unroll
    for (int r = 0; r < 4; ++r) {
      float ps = 0.f, pd = 0.f;
      #pragma unroll
      for (int n = 0; n < NF; ++n) {
        float v = acc[m][n][r];
        ps += v * asv[n];
        pd += v * adv[n];
      }
      #pragma unroll
      for (int o = 1; o < 16; o <<= 1) {
        ps += __shfl_xor(ps, o, 64);
        pd += __shfl_xor(pd, o, 64);
      }
      int grow = crow0 + m * 16 + r;
      if ((lane & 15) == 0 && grow < M) {
        als[(size_t)grow * HEADS + hidx] = ps;
        ald[(size_t)grow * HEADS + hidx] = pd;
      }
    }
  }
}

// ---------------- GAT aggregation: one wave per dst, 8-edge unroll (r13) ----------------

template <int HEADS, int CC>
__global__ __launch_bounds__(256) void gat_aggregate(const unsigned short* __restrict__ h,
                                                     const float* __restrict__ als,
                                                     const float* __restrict__ ald,
                                                     const int* __restrict__ off,
                                                     const int* __restrict__ col,
                                                     const float* __restrict__ bias,
                                                     unsigned short* __restrict__ out,
                                                     int Nn) {
  constexpr int HC = HEADS * CC;
  int wid = (int)((blockIdx.x * (size_t)blockDim.x + threadIdx.x) >> 6);
  int lane = threadIdx.x & 63;
  if (wid >= Nn) return;
  int c0 = lane * 4;
  int head = c0 / CC;
  float my_ald = ald[(size_t)wid * HEADS + head];
  float ssum = 0.f;
  float acc[4] = {};
  int beg = off[wid], end = off[wid + 1];

  auto lrelu = [](float l) { return (l > 0.f) ? l : 0.2f * l; };

  int j = beg;
  for (; j + 8 <= end; j += 8) {
    int sI[8];
    ushort4 g[8];
    float p[8];
    #pragma unroll
    for (int k = 0; k < 8; ++k) sI[k] = col[j + k];
    #pragma unroll
    for (int k = 0; k < 8; ++k)
      g[k] = *(const ushort4*)(h + (size_t)sI[k] * HC + c0);
    #pragma unroll
    for (int k = 0; k < 8; ++k)
      p[k] = __expf(lrelu(als[(size_t)sI[k] * HEADS + head] + my_ald));
    #pragma unroll
    for (int k = 0; k < 8; ++k) {
      ssum += p[k];
      acc[0] += p[k] * bf2f(g[k].x);
      acc[1] += p[k] * bf2f(g[k].y);
      acc[2] += p[k] * bf2f(g[k].z);
      acc[3] += p[k] * bf2f(g[k].w);
    }
  }
  for (; j + 4 <= end; j += 4) {
    int sI[4];
    ushort4 g[4];
    float p[4];
    #pragma unroll
    for (int k = 0; k < 4; ++k) sI[k] = col[j + k];
    #pragma unroll
    for (int k = 0; k < 4; ++k)
      g[k] = *(const ushort4*)(h + (size_t)sI[k] * HC + c0);
    #pragma unroll
    for (int k = 0; k < 4; ++k)
      p[k] = __expf(lrelu(als[(size_t)sI[k] * HEADS + head] + my_ald));
    #pragma unroll
    for (int k = 0; k < 4; ++k) {
      ssum += p[k];
      acc[0] += p[k] * bf2f(g[k].x);
      acc[1] += p[k] * bf2f(g[k].y);
      acc[2] += p[k] * bf2f(g[k].z);
      acc[3] += p[k] * bf2f(g[k].w);
    }
  }
  for (; j < end; ++j) {
    int s = col[j];
    float p = __expf(lrelu(als[(size_t)s * HEADS + head] + my_ald));
    ssum += p;
    ushort4 hv = *(const ushort4*)(h + (size_t)s * HC + c0);
    acc[0] += p * bf2f(hv.x);
    acc[1] += p * bf2f(hv.y);
    acc[2] += p * bf2f(hv.z);
    acc[3] += p * bf2f(hv.w);
  }
  float inv = 1.f / (ssum + 1e-16f);
  #pragma unroll
  for (int k2 = 0; k2 < 4; ++k2)
    out[(size_t)wid * HC + c0 + k2] = f2bf(acc[k2] * inv + bias[c0 + k2]);
}

// HEADS=1, CC=32: split-K within a wave (r13).

template <int CC>
__global__ __launch_bounds__(256) void gat_aggregate_splitk(
    const unsigned short* __restrict__ h, const float* __restrict__ als,
    const float* __restrict__ ald, const int* __restrict__ off,
    const int* __restrict__ col, const float* __restrict__ bias,
    unsigned short* __restrict__ out, int Nn) {
  int wid = (int)((blockIdx.x * (size_t)blockDim.x + threadIdx.x) >> 6);
  int lane = threadIdx.x & 63;
  if (wid >= Nn) return;
  int c = lane & (CC - 1);
  int half = lane >> 5;
  float my_ald = ald[wid];
  int beg0 = off[wid], end0 = off[wid + 1];
  int mid = beg0 + ((end0 - beg0) >> 1);
  int beg = half ? mid : beg0;
  int end = half ? end0 : mid;

  auto lrelu = [](float l) { return (l > 0.f) ? l : 0.2f * l; };

  float ssum = 0.f, acc = 0.f;
  int j = beg;
  for (; j + 4 <= end; j += 4) {
    int s0 = col[j], s1 = col[j + 1], s2 = col[j + 2], s3 = col[j + 3];
    unsigned short g0 = h[(size_t)s0 * CC + c];
    unsigned short g1 = h[(size_t)s1 * CC + c];
    unsigned short g2 = h[(size_t)s2 * CC + c];
    unsigned short g3 = h[(size_t)s3 * CC + c];
    float p0 = __expf(lrelu(als[s0] + my_ald));
    float p1 = __expf(lrelu(als[s1] + my_ald));
    float p2 = __expf(lrelu(als[s2] + my_ald));
    float p3 = __expf(lrelu(als[s3] + my_ald));
    ssum += (p0 + p1) + (p2 + p3);
    acc += p0 * bf2f(g0) + p1 * bf2f(g1) + p2 * bf2f(g2) + p3 * bf2f(g3);
  }
  for (; j < end; ++j) {
    int s = col[j];
    float p = __expf(lrelu(als[s] + my_ald));
    ssum += p;
    acc += p * bf2f(h[(size_t)s * CC + c]);
  }
  ssum += __shfl_xor(ssum, 32, 64);
  acc += __shfl_xor(acc, 32, 64);
  if (half == 0)
    out[(size_t)wid * CC + c] = f2bf(acc / (ssum + 1e-16f) + bias[c]);
}

// ---------------- BatchNorm (biased var) — parallel two-stage, bf16 input ----------------

constexpr int BN_NB = 1024;

template <int CH>
__global__ __launch_bounds__(256) void bn_stats_part(const unsigned short* __restrict__ x,
                                                     int Nn, float* __restrict__ pbuf) {
  constexpr int Q8 = CH / 8;
  int t = threadIdx.x;
  size_t tot8 = (size_t)Nn * Q8;
  size_t stride = (size_t)gridDim.x * 256;
  float s[8] = {}, sq[8] = {};
  for (size_t i = blockIdx.x * (size_t)256 + t; i < tot8; i += stride) {
    uint4 u = *(const uint4*)&x[i * 8];
    float v[8] = {lo16f(u.x), hi16f(u.x), lo16f(u.y), hi16f(u.y),
                  lo16f(u.z), hi16f(u.z), lo16f(u.w), hi16f(u.w)};
    #pragma unroll
    for (int k = 0; k < 8; ++k) { s[k] += v[k]; sq[k] += v[k] * v[k]; }
  }
  __shared__ float sS[256][8];
  __shared__ float sQ[256][8];
  #pragma unroll
  for (int k = 0; k < 8; ++k) { sS[t][k] = s[k]; sQ[t][k] = sq[k]; }
  __syncthreads();
  for (int half = 128; half >= Q8; half >>= 1) {
    if (t < half) {
      #pragma unroll
      for (int k = 0; k < 8; ++k) {
        sS[t][k] += sS[t + half][k];
        sQ[t][k] += sQ[t + half][k];
      }
    }
    __syncthreads();
  }
  if (t < Q8) {
    #pragma unroll
    for (int k = 0; k < 8; ++k) {
      pbuf[(size_t)blockIdx.x * 2 * CH + t * 8 + k] = sS[t][k];
      pbuf[(size_t)blockIdx.x * 2 * CH + CH + t * 8 + k] = sQ[t][k];
    }
  }
}

template <int CH>
__global__ __launch_bounds__(256) void bn_reduce_finalize(const float* __restrict__ pbuf,
                                                          const float* __restrict__ g,
                                                          const float* __restrict__ be,
                                                          float invN,
                                                          float* __restrict__ ss) {
  int c = blockIdx.x;
  int t = threadIdx.x;
  float s = 0.f, q = 0.f;
  for (int b = t; b < BN_NB; b += 256) {
    s += pbuf[(size_t)b * 2 * CH + c];
    q += pbuf[(size_t)b * 2 * CH + CH + c];
  }
  #pragma unroll
  for (int o = 32; o > 0; o >>= 1) {
    s += __shfl_xor(s, o, 64);
    q += __shfl_xor(q, o, 64);
  }
  __shared__ float rs[4], rq[4];
  int wv = t >> 6, lane = t & 63;
  if (lane == 0) { rs[wv] = s; rq[wv] = q; }
  __syncthreads();
  if (t == 0) {
    float S = rs[0] + rs[1] + rs[2] + rs[3];
    float Qs = rq[0] + rq[1] + rq[2] + rq[3];
    float mu = S * invN;
    float var = Qs * invN - mu * mu;
    float sc = g[c] * rsqrtf(var + 1e-5f);
    ss[c] = sc;
    ss[CH + c] = be[c] - mu * sc;
  }
}

template <int CH>
__global__ __launch_bounds__(256) void bn_apply_elu_b2b(const unsigned short* __restrict__ x,
                                                        const float* __restrict__ ss,
                                                        unsigned short* __restrict__ out,
                                                        int Nn) {
  size_t tot8 = (size_t)Nn * (CH / 8);
  for (size_t i = blockIdx.x * (size_t)256 + threadIdx.x; i < tot8;
       i += (size_t)gridDim.x * 256) {
    uint4 u = *(const uint4*)&x[i * 8];
    int c0 = (int)((i % (CH / 8)) * 8);
    float v[8] = {lo16f(u.x), hi16f(u.x), lo16f(u.y), hi16f(u.y),
                  lo16f(u.z), hi16f(u.z), lo16f(u.w), hi16f(u.w)};
    unsigned int o[4];
    #pragma unroll
    for (int k = 0; k < 4; ++k) {
      float y0 = v[2 * k] * ss[c0 + 2 * k] + ss[CH + c0 + 2 * k];
      float y1 = v[2 * k + 1] * ss[c0 + 2 * k + 1] + ss[CH + c0 + 2 * k + 1];
      y0 = (y0 > 0.f) ? y0 : expm1f(y0);
      y1 = (y1 > 0.f) ? y1 : expm1f(y1);
      o[k] = (unsigned int)f2bf(y0) | ((unsigned int)f2bf(y1) << 16);
    }
    *(uint4*)&out[i * 8] = make_uint4(o[0], o[1], o[2], o[3]);
  }
}

// ---------------- classifier with fused layer-3 BN+ELU ----------------
// reads RAW layer-3 aggregate (pre-BN bf16), applies scale/shift+ELU inline.

__global__ __launch_bounds__(256) void classifier_fused(
    const unsigned short* __restrict__ x, const float* __restrict__ ss,
    const float* __restrict__ Wc1, const float* __restrict__ bc1,
    const float* __restrict__ Wc2, const float* __restrict__ bc2,
    float* __restrict__ outp, int Nn) {
  __shared__ unsigned short sx[256][33];
  __shared__ float sw[32 * 32];
  __shared__ float sb1[32];
  __shared__ float sw2[32];
  __shared__ float ssc[32], ssh[32];
  int t = threadIdx.x;
  int base = blockIdx.x * 256;
  for (int i = t; i < 1024; i += 256) sw[i] = Wc1[i];
  if (t < 32) {
    sb1[t] = bc1[t]; sw2[t] = Wc2[t];
    ssc[t] = ss[t];  ssh[t] = ss[32 + t];
  }
  int cnt = min(256, Nn - base);
  for (int i = t; i < cnt * 32; i += 256) sx[i / 32][i % 32] = x[(size_t)base * 32 + i];
  __syncthreads();
  if (t < cnt) {
    float xa[32];
    #pragma unroll
    for (int c = 0; c < 32; ++c) {
      float y = bf2f(sx[t][c]) * ssc[c] + ssh[c];
      xa[c] = (y > 0.f) ? y : expm1f(y);
    }
    float o = bc2[0];
    #pragma unroll
    for (int j = 0; j < 32; ++j) {
      float v = sb1[j];
      #pragma unroll
      for (int c = 0; c < 32; ++c) v += xa[c] * sw[c * 32 + j];
      v = fmaxf(v, 0.f);
      o += v * sw2[j];
    }
    outp[base + t] = o;
  }
}

// ---------------- host orchestration ----------------

extern "C" void kernel_launch(void* const* d_in, const int* in_sizes, int n_in,
                              void* d_out, int out_size, void* d_ws, size_t ws_size,
                              hipStream_t stream) {
  const float* x   = (const float*)d_in[0];
  const int*   ei  = (const int*)d_in[1];
  const float* W1  = (const float*)d_in[2];
  const float* as1 = (const float*)d_in[3];
  const float* ad1 = (const float*)d_in[4];
  const float* b1  = (const float*)d_in[5];
  const float* g1  = (const float*)d_in[6];
  const float* be1 = (const float*)d_in[7];
  const float* W2  = (const float*)d_in[8];
  const float* as2 = (const float*)d_in[9];
  const float* ad2 = (const float*)d_in[10];
  const float* b2  = (const float*)d_in[11];
  const float* g2  = (const float*)d_in[12];
  const float* be2 = (const float*)d_in[13];
  const float* W3  = (const float*)d_in[14];
  const float* as3 = (const float*)d_in[15];
  const float* ad3 = (const float*)d_in[16];
  const float* b3  = (const float*)d_in[17];
  const float* g3  = (const float*)d_in[18];
  const float* be3 = (const float*)d_in[19];
  const float* Wc1 = (const float*)d_in[20];
  const float* bc1 = (const float*)d_in[21];
  const float* Wc2 = (const float*)d_in[22];
  const float* bc2 = (const float*)d_in[23];
  float* outp = (float*)d_out;

  const int Nn = in_sizes[0] / 128;
  const int Ee = in_sizes[1] / 2;
  const int TotE = Ee + Nn;
  const int* esrc = ei;
  const int* edst = ei + Ee;

  char* w = (char*)d_ws;
  auto carve = [&](size_t bytes) {
    char* p = w;
    w += (bytes + 255) & ~(size_t)255;
    return p;
  };
  unsigned short* hb  = (unsigned short*)carve((size_t)Nn * 256 * 2);
  unsigned short* xb  = (unsigned short*)carve((size_t)Nn * 256 * 2);
  unsigned short* agg = (unsigned short*)carve((size_t)Nn * 256 * 2);
  float* als   = (float*)carve((size_t)Nn * 4 * 4);
  float* ald   = (float*)carve((size_t)Nn * 4 * 4);
  float* pbuf  = (float*)carve((size_t)BN_NB * 512 * 4);
  float* ss    = (float*)carve(512 * 4);
  unsigned short* Wt1 = (unsigned short*)carve(256 * 128 * 2);
  unsigned short* Wt2 = (unsigned short*)carve(256 * 256 * 2);
  unsigned short* Wt3 = (unsigned short*)carve(32 * 256 * 2);
  int* off     = (int*)carve((size_t)(Nn + 1) * 4);
  int* col     = (int*)carve((size_t)TotE * 4);
  int2* ebuf   = (int2*)carve((size_t)TotE * 8);
  int* bhist   = (int*)carve((size_t)MAXBUK * CSR_HB * 4);
  int* btot    = (int*)carve(MAXBUK * 4);
  int* bucketBase = (int*)carve((MAXBUK + 1) * 4);

  // --- operand prep ---
  cast_f32_bf16<<<2048, 256, 0, stream>>>(x, xb, (size_t)Nn * 128 / 4);
  transpose_cast_all<<<(128 * 256 + 256 * 256 + 256 * 32 + 255) / 256, 256, 0, stream>>>(
      W1, W2, W3, Wt1, Wt2, Wt3);

  // --- CSR build: atomic-free bucketed counting sort ---
  const int nbuk = (Nn + 127) >> BUK_SH;
  bucket_hist<<<CSR_HB, 256, 0, stream>>>(edst, Ee, Nn, nbuk, bhist);
  bucket_scan<<<nbuk, 256, 0, stream>>>(bhist, btot);
  bucket_base<<<1, MAXBUK, 0, stream>>>(btot, bucketBase, nbuk);
  bucket_scatter<<<CSR_HB, 256, 0, stream>>>(esrc, edst, Ee, Nn, nbuk, bhist, bucketBase, ebuf);
  fine_fill<<<nbuk, 256, 0, stream>>>(ebuf, bucketBase, Nn, TotE, off, col);

  int waveBlocks = (Nn + 3) / 4;
  int gy = (Nn + 127) / 128;
  float invN = 1.0f / (float)Nn;

  // --- Layer 1: 128 -> 4x64 concat ---
  gemm_mfma_logits<128, 128, 64, 64, 4, 64><<<dim3(2, gy), 256, 0, stream>>>(
      xb, Wt1, hb, as1, ad1, als, ald, Nn, 256, 128);
  gat_aggregate<4, 64><<<waveBlocks, 256, 0, stream>>>(hb, als, ald, off, col, b1, agg, Nn);
  bn_stats_part<256><<<BN_NB, 256, 0, stream>>>(agg, Nn, pbuf);
  bn_reduce_finalize<256><<<256, 256, 0, stream>>>(pbuf, g1, be1, invN, ss);
  bn_apply_elu_b2b<256><<<2048, 256, 0, stream>>>(agg, ss, xb, Nn);

  // --- Layer 2: 256 -> 4x64 concat ---
  gemm_mfma_logits<128, 128, 64, 64, 4, 64><<<dim3(2, gy), 256, 0, stream>>>(
      xb, Wt2, hb, as2, ad2, als, ald, Nn, 256, 256);
  gat_aggregate<4, 64><<<waveBlocks, 256, 0, stream>>>(hb, als, ald, off, col, b2, agg, Nn);
  bn_stats_part<256><<<BN_NB, 256, 0, stream>>>(agg, Nn, pbuf);
  bn_reduce_finalize<256><<<256, 256, 0, stream>>>(pbuf, g2, be2, invN, ss);
  bn_apply_elu_b2b<256><<<2048, 256, 0, stream>>>(agg, ss, xb, Nn);

  // --- Layer 3: 256 -> 1x32, no concat ---
  gemm_mfma_logits<128, 32, 32, 32, 1, 32><<<dim3(1, gy), 256, 0, stream>>>(
      xb, Wt3, hb, as3, ad3, als, ald, Nn, 32, 256);
  gat_aggregate_splitk<32><<<waveBlocks, 256, 0, stream>>>(hb, als, ald, off, col, b3, agg, Nn);
  bn_stats_part<32><<<BN_NB, 256, 0, stream>>>(agg, Nn, pbuf);
  bn_reduce_finalize<32><<<32, 256, 0, stream>>>(pbuf, g3, be3, invN, ss);
  // layer-3 BN-apply+ELU fused into classifier
  classifier_fused<<<(Nn + 255) / 256, 256, 0, stream>>>(agg, ss, Wc1, bc1, Wc2, bc2, outp, Nn);
}